// Round 8
// baseline (667.190 us; speedup 1.0000x reference)
//
#include <hip/hip_runtime.h>
#include <cstdint>

#define VOC   32768
#define DIM   512
#define TOPK  64
#define BATCH 4096

#define KSIG     2.45f
#define EPS_SEL  0.012f
#define CAND_CAP 512
#define RES_CAP  256
#define FCAP     1024

typedef unsigned short u16;
typedef __attribute__((ext_vector_type(8))) short bf16x8;
typedef __attribute__((ext_vector_type(4))) float f32x4;

// ---- bf16 helpers (RNE) ----------------------------------------------------
__device__ __forceinline__ u16 f2bf(float f) {
    unsigned u = __float_as_uint(f);
    unsigned r = (u + 0x7FFFu + ((u >> 16) & 1u)) >> 16;
    return (u16)r;
}
__device__ __forceinline__ float bf2f(u16 h) {
    return __uint_as_float(((unsigned)h) << 16);
}
__device__ __forceinline__ unsigned enc16(u16 h) {
    return (h & 0x8000u) ? (unsigned)((u16)~h) : (unsigned)(h | 0x8000u);
}
__device__ __forceinline__ float dec16(unsigned s16) {
    u16 h = (s16 & 0x8000u) ? (u16)(s16 ^ 0x8000u) : (u16)(~s16);
    return bf2f(h);
}

// ---- async global->LDS 16B -------------------------------------------------
__device__ __forceinline__ void async16(const void* g, void* l) {
    __builtin_amdgcn_global_load_lds(
        (const __attribute__((address_space(1))) void*)g,
        (__attribute__((address_space(3))) void*)l, 16, 0, 0);
}

// ---------------------------------------------------------------------------
// fp32 64x64-tile GEMM + optional per-k-tile fp64 flush. 256 thr, 4x4 micro.
// Retained ONLY for the small precision-critical fold Wqk = Wq @ Wk^T.
// ---------------------------------------------------------------------------
template <bool BT, bool F64ACC>
__global__ __launch_bounds__(256)
void gemm64(const float* __restrict__ A, const float* __restrict__ B,
            const float* __restrict__ bias, float* __restrict__ C,
            int M, int N, int K)
{
    const int KS = 16;
    __shared__ float As[KS][68];
    __shared__ float Bs[KS][64];

    const int tid = threadIdx.x;
    const int m0 = blockIdx.y * 64;
    const int n0 = blockIdx.x * 64;
    const int ty = tid >> 4;
    const int tx = tid & 15;

    float acc[4][4];
    double acc64[4][4];
#pragma unroll
    for (int i = 0; i < 4; i++)
#pragma unroll
        for (int j = 0; j < 4; j++) { acc[i][j] = 0.f; if (F64ACC) acc64[i][j] = 0.0; }

    for (int kt = 0; kt < K; kt += KS) {
        {
            int row = tid >> 2, kq = tid & 3;
            const float4 av = *(const float4*)(A + (size_t)(m0 + row) * K + kt + kq * 4);
            As[kq * 4 + 0][row] = av.x;
            As[kq * 4 + 1][row] = av.y;
            As[kq * 4 + 2][row] = av.z;
            As[kq * 4 + 3][row] = av.w;
        }
        if (!BT) {
            int krow = tid >> 4, nq = tid & 15;
            *(float4*)&Bs[krow][nq * 4] =
                *(const float4*)(B + (size_t)(kt + krow) * N + n0 + nq * 4);
        } else {
            int nrow = tid >> 2, kq = tid & 3;
            const float4 bv = *(const float4*)(B + (size_t)(n0 + nrow) * K + kt + kq * 4);
            Bs[kq * 4 + 0][nrow] = bv.x;
            Bs[kq * 4 + 1][nrow] = bv.y;
            Bs[kq * 4 + 2][nrow] = bv.z;
            Bs[kq * 4 + 3][nrow] = bv.w;
        }
        __syncthreads();

#pragma unroll
        for (int kk = 0; kk < KS; kk++) {
            float4 a = *(const float4*)&As[kk][ty * 4];
            float4 b = *(const float4*)&Bs[kk][tx * 4];
            float av[4] = {a.x, a.y, a.z, a.w};
            float bv[4] = {b.x, b.y, b.z, b.w};
#pragma unroll
            for (int i = 0; i < 4; i++)
#pragma unroll
                for (int j = 0; j < 4; j++)
                    acc[i][j] += av[i] * bv[j];
        }
        __syncthreads();
        if (F64ACC) {
#pragma unroll
            for (int i = 0; i < 4; i++)
#pragma unroll
                for (int j = 0; j < 4; j++) { acc64[i][j] += (double)acc[i][j]; acc[i][j] = 0.f; }
        }
    }

    float4 bb = make_float4(0.f, 0.f, 0.f, 0.f);
    if (bias) bb = *(const float4*)(bias + n0 + tx * 4);
#pragma unroll
    for (int i = 0; i < 4; i++) {
        float4 o;
        o.x = (F64ACC ? (float)acc64[i][0] : acc[i][0]) + bb.x;
        o.y = (F64ACC ? (float)acc64[i][1] : acc[i][1]) + bb.y;
        o.z = (F64ACC ? (float)acc64[i][2] : acc[i][2]) + bb.z;
        o.w = (F64ACC ? (float)acc64[i][3] : acc[i][3]) + bb.w;
        *(float4*)(C + (size_t)(m0 + ty * 4 + i) * N + n0 + tx * 4) = o;
    }
}

__global__ void zero_ws(unsigned* __restrict__ p, int n)
{
    int i = blockIdx.x * 256 + threadIdx.x;
    if (i < n) p[i] = 0u;
}

// ---------------------------------------------------------------------------
// Device bodies for the fused prep kernels (virtual block id passed in).
// ---------------------------------------------------------------------------
__device__ __forceinline__ void pack_rows_dev(int bid, int tid,
        const float* __restrict__ src, u16* __restrict__ hi,
        u16* __restrict__ lo, int R, int log2R)
{
    int idx = bid * 256 + tid;
    int c8  = idx >> log2R;
    int row = idx & (R - 1);
    const float* sp = src + (size_t)row * DIM + c8 * 8;
    float xv[8];
    *(float4*)&xv[0] = *(const float4*)sp;
    *(float4*)&xv[4] = *(const float4*)(sp + 4);
    int ks = c8 >> 2, ch = c8 & 3;
    size_t ob = ((size_t)(ks * 4 + ch) * R + row) * 8;
    u16 h[8], l[8];
#pragma unroll
    for (int j = 0; j < 8; j++) {
        h[j] = f2bf(xv[j]);
        l[j] = f2bf(xv[j] - bf2f(h[j]));
    }
    *(uint4*)(hi + ob) = *(const uint4*)h;
    if (lo) *(uint4*)(lo + ob) = *(const uint4*)l;
}

__device__ __forceinline__ void pack_bT_dev(int bid, int tid,
        const float* __restrict__ W, u16* __restrict__ hi, u16* __restrict__ lo)
{
    int idx = bid * 256 + tid;
    int n  = idx & (DIM - 1);
    int c8 = idx >> 9;
    int ks = c8 >> 2, ch = c8 & 3;
    size_t ob = ((size_t)(ks * 4 + ch) * DIM + n) * 8;
    u16 h[8], l[8];
#pragma unroll
    for (int j = 0; j < 8; j++) {
        float x = W[(size_t)(c8 * 8 + j) * DIM + n];
        h[j] = f2bf(x);
        l[j] = f2bf(x - bf2f(h[j]));
    }
    *(uint4*)(hi + ob) = *(const uint4*)h;
    *(uint4*)(lo + ob) = *(const uint4*)l;
}

__device__ __forceinline__ void cbar_dev(int bid, int tid,
        const float* __restrict__ cb, float* __restrict__ cbarsum)
{
    const int r0 = bid * 128;
    float s0 = 0.f, s1 = 0.f;
    for (int r = 0; r < 128; r++) {
        const float* rp = cb + (size_t)(r0 + r) * DIM;
        s0 += rp[tid];
        s1 += rp[tid + 256];
    }
    atomicAdd(&cbarsum[tid], s0);
    atomicAdd(&cbarsum[tid + 256], s1);
}

__device__ __forceinline__ void bias_fold_dev(int bid, int tid,
        const float* __restrict__ bq, const float* __restrict__ Wk,
        float* __restrict__ bqk)
{
    const int lane = tid & 63, wave = tid >> 6;
    const int j = bid * 4 + wave;
    const float* wr = Wk + (size_t)j * DIM + lane * 8;
    const float* bp = bq + lane * 8;
    double s = 0.0;
#pragma unroll
    for (int t = 0; t < 8; t++) s += (double)bp[t] * (double)wr[t];
#pragma unroll
    for (int off = 32; off > 0; off >>= 1) s += __shfl_down(s, off);
    if (lane == 0) bqk[j] = (float)s;
}

__device__ __forceinline__ void rowstats_dev(int bid, int tid,
        const float* __restrict__ q2, const float* __restrict__ cbarsum,
        float* __restrict__ trow, float* __restrict__ sigrow)
{
    const int lane = tid & 63, wave = tid >> 6;
    const int row = bid * 4 + wave;
    const float* qp = q2 + (size_t)row * DIM + lane * 8;
    float4 a0 = *(const float4*)qp, a1 = *(const float4*)(qp + 4);
    const float* cp = cbarsum + lane * 8;
    float4 c0 = *(const float4*)cp, c1 = *(const float4*)(cp + 4);
    float mu = a0.x*c0.x + a0.y*c0.y + a0.z*c0.z + a0.w*c0.w
             + a1.x*c1.x + a1.y*c1.y + a1.z*c1.z + a1.w*c1.w;
    float nr = a0.x*a0.x + a0.y*a0.y + a0.z*a0.z + a0.w*a0.w
             + a1.x*a1.x + a1.y*a1.y + a1.z*a1.z + a1.w*a1.w;
#pragma unroll
    for (int off = 32; off > 0; off >>= 1) {
        mu += __shfl_down(mu, off);
        nr += __shfl_down(nr, off);
    }
    if (lane == 0) {
        mu *= (1.f / VOC);
        float sig = sqrtf(nr * (1.f / 1536.f));
        trow[row] = mu + KSIG * sig;
        sigrow[row] = sig;
    }
}

// ---------------------------------------------------------------------------
// fused_prep: all pre-dots prep that only depends on {inputs, Wqk, zeroed ws}.
// Block ranges: [0,1024) x-pack hi/lo | [1024,1152) Wqk-bT | [1152,9344)
// cb-pack | [9344,9472) Wv-bT | [9472,9728) cbar_accum | [9728,9856) bias_fold
// ---------------------------------------------------------------------------
__global__ __launch_bounds__(256)
void fused_prep(const float* __restrict__ x, const float* __restrict__ Wqk,
                const float* __restrict__ codebook, const float* __restrict__ Wv,
                const float* __restrict__ bq, const float* __restrict__ Wk,
                u16* __restrict__ xh, u16* __restrict__ xl,
                u16* __restrict__ wqkh, u16* __restrict__ wqkl,
                u16* __restrict__ cbh, u16* __restrict__ wvh,
                u16* __restrict__ wvl, float* __restrict__ cbarsum,
                float* __restrict__ bqk)
{
    const int b = blockIdx.x, tid = threadIdx.x;
    if (b < 1024)       pack_rows_dev(b, tid, x, xh, xl, BATCH, 12);
    else if (b < 1152)  pack_bT_dev(b - 1024, tid, Wqk, wqkh, wqkl);
    else if (b < 9344)  pack_rows_dev(b - 1152, tid, codebook, cbh, nullptr, VOC, 15);
    else if (b < 9472)  pack_bT_dev(b - 9344, tid, Wv, wvh, wvl);
    else if (b < 9728)  cbar_dev(b - 9472, tid, codebook, cbarsum);
    else                bias_fold_dev(b - 9728, tid, bq, Wk, bqk);
}

// fused_q2post: rowstats + q2-pack (both read q2). [0,1024) | [1024,2048)
__global__ __launch_bounds__(256)
void fused_q2post(const float* __restrict__ q2, const float* __restrict__ cbarsum,
                  float* __restrict__ trow, float* __restrict__ sigrow,
                  u16* __restrict__ q2h)
{
    const int b = blockIdx.x, tid = threadIdx.x;
    if (b < 1024) rowstats_dev(b, tid, q2, cbarsum, trow, sigrow);
    else          pack_rows_dev(b - 1024, tid, q2, q2h, nullptr, BATCH, 12);
}

// standalone pack_rows (still used for y)
__global__ __launch_bounds__(256)
void pack_rows(const float* __restrict__ src, u16* __restrict__ hi,
               u16* __restrict__ lo, int R, int log2R)
{
    pack_rows_dev(blockIdx.x, threadIdx.x, src, hi, lo, R, log2R);
}

// ---------------------------------------------------------------------------
// Fused dots GEMM v14: m97-shape. v13's per-step cost was 1116 cyc vs ~600
// pipe-sum; learn_hip m97 (same 128^2 tile, BK=64, SINGLE 32KB buffer,
// 2 barriers/step, 874-912 TF measured on this chip) is the proven shape.
// Change: BK 32->64 => 8 steps (16 barriers total vs 32), 32-MFMA clusters.
// Resources identical to v13 (acc[4][4]=64 AGPR, 32KB LDS, (256,4) -> 16
// waves/CU, one above m97's 12). Exposed staging per step is hidden by the
// other 3 resident blocks' compute (m114 mechanism). K-accumulation order
// per output element unchanged -> dots bit-identical.
// LDS: A [8 planes][128 rows][8] | B [8 planes][128 cols][8], plane =
// global c8 = s*8 + p. Staging: 2048 16B-units / 256 thr = 8 async16/thread;
// 64-lane runs stay in one plane (u=tid+i*256; plane=u>>7 uniform per wave).
// ---------------------------------------------------------------------------
__global__ __launch_bounds__(256, 4)
void mfma_dots(const u16* __restrict__ Ah, const u16* __restrict__ Bh,
               const float* __restrict__ trow, unsigned* __restrict__ candBuf,
               unsigned* __restrict__ counters)
{
    __shared__ u16 lds[16384];         // single stage: A 16KB + B 16KB = 32 KB

    const int tid  = threadIdx.x;
    const int lane = tid & 63;
    const int wave = tid >> 6;
    const int wm = wave >> 1, wn = wave & 1;
    const int lr = lane & 15;
    const int q  = lane >> 4;

    // XCD-affinity: xcd owns a 4-m-tile band; within XCD, m fastest then n.
    const int L   = blockIdx.x;
    const int xcd = L & 7;
    const int j   = L >> 3;                    // 0..1023
    const int m0  = (xcd * 4 + (j & 3)) * 128;
    const int n0  = (j >> 2) * 128;

    // strength-reduced staging pointers: 4 A-units + 4 B-units per thread,
    // advanced by 8 planes per step.
    const size_t stepA = (size_t)8 * BATCH * 8;
    const size_t stepB = (size_t)8 * VOC * 8;
    const u16* gpA[4];
    const u16* gpB[4];
    int ldA[4], ldB[4];
#pragma unroll
    for (int i = 0; i < 4; i++) {
        int u = tid + i * 256;                 // unit 0..1023: plane=u>>7, r/c=u&127
        gpA[i] = Ah + ((size_t)(u >> 7) * BATCH + m0 + (u & 127)) * 8;
        ldA[i] = u * 8;
        gpB[i] = Bh + ((size_t)(u >> 7) * VOC + n0 + (u & 127)) * 8;
        ldB[i] = 8192 + u * 8;
    }

#define ISSUE()                                                               \
    {                                                                         \
        _Pragma("unroll")                                                     \
        for (int i_ = 0; i_ < 4; i_++) { async16(gpA[i_], &lds[ldA[i_]]); gpA[i_] += stepA; } \
        _Pragma("unroll")                                                     \
        for (int i_ = 0; i_ < 4; i_++) { async16(gpB[i_], &lds[ldB[i_]]); gpB[i_] += stepB; } \
    }

    f32x4 acc[4][4] = {};

    ISSUE()                                    // stage step 0

    for (int s = 0; s < 8; s++) {
        __builtin_amdgcn_s_waitcnt(0x0F70);    // vmcnt(0): own 8 loads landed
        __builtin_amdgcn_s_barrier();          // all waves' staging visible

#pragma unroll
        for (int kk = 0; kk < 2; kk++) {       // two K=32 halves, ascending K order
            bf16x8 ah[4];
#pragma unroll
            for (int mt = 0; mt < 4; mt++)
                ah[mt] = *(const bf16x8*)&lds[(kk * 4 + q) * 1024 + (wm * 64 + mt * 16 + lr) * 8];
            __builtin_amdgcn_s_setprio(1);
#pragma unroll
            for (int nt = 0; nt < 4; nt++) {
                bf16x8 bh = *(const bf16x8*)&lds[8192 + (kk * 4 + q) * 1024 + (wn * 64 + nt * 16 + lr) * 8];
#pragma unroll
                for (int mt = 0; mt < 4; mt++)
                    acc[mt][nt] = __builtin_amdgcn_mfma_f32_16x16x32_bf16(
                        ah[mt], bh, acc[mt][nt], 0, 0, 0);
            }
            __builtin_amdgcn_s_setprio(0);
        }

        if (s < 7) {
            __syncthreads();                   // all waves' ds_reads retired
            ISSUE()                            // overwrite with step s+1
        }
    }
#undef ISSUE

    // epilogue: threshold-append candidates
#pragma unroll
    for (int mt = 0; mt < 4; mt++) {
#pragma unroll
        for (int r = 0; r < 4; r++) {
            int rowg = m0 + wm * 64 + mt * 16 + q * 4 + r;
            float tr = trow[rowg];
#pragma unroll
            for (int nt = 0; nt < 4; nt++) {
                float val = acc[mt][nt][r];
                if (val >= tr) {
                    unsigned slot = atomicAdd(&counters[rowg], 1u);
                    if (slot < CAND_CAP) {
                        unsigned s16 = enc16(f2bf(val));
                        candBuf[(size_t)rowg * CAND_CAP + slot] =
                            (s16 << 16) | (unsigned)(n0 + wn * 64 + nt * 16 + lr);
                    }
                }
            }
        }
    }
}

// ---------------------------------------------------------------------------
// out = A @ W + bias in bf16 hi/lo 3-pass MFMA (error ~1e-6). v2 REGRID:
// old grid was 128 blocks (half the GPU idle). Tile 128m x 64n -> grid
// (DIM/64, BATCH/128) = 256 blocks; per-wave 64x32 output acc[4][2]=32 AGPR;
// LDS 2 stages x (Ah 8K|Bh 4K|Al 8K|Bl 4K) = 48 KB -> 3 blocks/CU (was 2).
// Per-element MFMA sequence identical (ks ascending; ah*bh, ah*bl, al*bh)
// -> bit-identical results. Used for q2 = x@Wqk + bqk and out = y@Wv + bv.
// ---------------------------------------------------------------------------
__global__ __launch_bounds__(256, 3)
void mfma_out(const u16* __restrict__ Ah, const u16* __restrict__ Al,
              const u16* __restrict__ Bh, const u16* __restrict__ Bl,
              const float* __restrict__ bias, float* __restrict__ Cout, int Ma)
{
    __shared__ u16 lds[2 * 12288];   // 2 stages x 24 KB

    const int tid  = threadIdx.x;
    const int lane = tid & 63;
    const int wave = tid >> 6;
    const int wm = wave >> 1, wn = wave & 1;
    const int m0 = blockIdx.y * 128, n0 = blockIdx.x * 64;
    const int lr = lane & 15;
    const int q  = lane >> 4;
    const size_t R = (size_t)Ma;

    f32x4 acc[4][2] = {};

    // staging: 6 async16/thread. A-units u=tid+i*256 (512/array): ch=u>>7,
    // row=u&127. B-units u=tid (256/array): ch=u>>6, col=u&63. All runs of 64
    // units stay in one ch => wave-uniform base + lane*16.
#define VISSUE(ks, b)                                                          \
    {                                                                          \
        _Pragma("unroll")                                                      \
        for (int i_ = 0; i_ < 2; i_++) {                                       \
            int u_ = tid + i_ * 256;                                           \
            size_t ai_ = ((size_t)((ks) * 4 + (u_ >> 7)) * R + m0 + (u_ & 127)) * 8; \
            async16(Ah + ai_, &lds[(b) * 12288 + u_ * 8]);                     \
            async16(Al + ai_, &lds[(b) * 12288 + 6144 + u_ * 8]);              \
        }                                                                      \
        {                                                                      \
            int u_ = tid;                                                      \
            size_t bi_ = ((size_t)((ks) * 4 + (u_ >> 6)) * DIM + n0 + (u_ & 63)) * 8; \
            async16(Bh + bi_, &lds[(b) * 12288 + 4096 + u_ * 8]);              \
            async16(Bl + bi_, &lds[(b) * 12288 + 10240 + u_ * 8]);             \
        }                                                                      \
    }

    VISSUE(0, 0)

    for (int ks = 0; ks < 16; ks++) {
        __syncthreads();                       // drains vmcnt(0): stage ks in LDS
        if (ks < 15) VISSUE(ks + 1, (ks + 1) & 1)
        const u16* base = &lds[(ks & 1) * 12288];

        bf16x8 ah[4], al[4];
#pragma unroll
        for (int mt = 0; mt < 4; mt++) {
            int row = wm * 64 + mt * 16 + lr;
            ah[mt] = *(const bf16x8*)&base[q * 1024 + row * 8];
            al[mt] = *(const bf16x8*)&base[6144 + q * 1024 + row * 8];
        }
#pragma unroll
        for (int nt = 0; nt < 2; nt++) {
            int col = wn * 32 + nt * 16 + lr;
            bf16x8 bh = *(const bf16x8*)&base[4096 + q * 512 + col * 8];
            bf16x8 bl = *(const bf16x8*)&base[10240 + q * 512 + col * 8];
#pragma unroll
            for (int mt = 0; mt < 4; mt++) {
                acc[mt][nt] = __builtin_amdgcn_mfma_f32_16x16x32_bf16(ah[mt], bh, acc[mt][nt], 0, 0, 0);
                acc[mt][nt] = __builtin_amdgcn_mfma_f32_16x16x32_bf16(ah[mt], bl, acc[mt][nt], 0, 0, 0);
                acc[mt][nt] = __builtin_amdgcn_mfma_f32_16x16x32_bf16(al[mt], bh, acc[mt][nt], 0, 0, 0);
            }
        }
    }
#undef VISSUE

#pragma unroll
    for (int mt = 0; mt < 4; mt++)
#pragma unroll
        for (int nt = 0; nt < 2; nt++) {
            int col = n0 + wn * 32 + nt * 16 + lr;
            float bb = bias[col];
#pragma unroll
            for (int r = 0; r < 4; r++) {
                int rowg = m0 + wm * 64 + mt * 16 + q * 4 + r;
                Cout[(size_t)rowg * DIM + col] = acc[mt][nt][r] + bb;
            }
        }
}

// ---------------------------------------------------------------------------
// Select v7: histogram selection (2-pass 256-bin over the monotone s16
// encoding; exact 64th-largest incl. duplicates). Unordered band-compaction
// -> fp64 rescue -> exact u64 sort -> softmax -> y_row.
// ---------------------------------------------------------------------------
__global__ __launch_bounds__(256)
void select6(const unsigned* __restrict__ candBuf, const unsigned* __restrict__ counters,
             const float* __restrict__ trow, const float* __restrict__ q2,
             const float* __restrict__ codebook, float* __restrict__ y,
             unsigned* __restrict__ flags)
{
    __shared__ unsigned recs[CAND_CAP];
    __shared__ unsigned list[RES_CAP];
    __shared__ unsigned hist[256];
    __shared__ unsigned long long keys[RES_CAP];
    __shared__ float q2s[DIM];
    __shared__ float wArr[RES_CAP];
    __shared__ float redf[256];
    __shared__ unsigned redu[256];
    __shared__ unsigned s_R;
    __shared__ unsigned s_b1, s_rem, s_thr;

    const int tid  = threadIdx.x;
    const int lane = tid & 63;
    const int wave = tid >> 6;
    const int row  = blockIdx.x;

    const unsigned cnt = counters[row];
    if (cnt < TOPK || cnt > CAND_CAP) {
        if (tid == 0) flags[row] = 1u;
        return;
    }
    for (int i = tid; i < DIM; i += 256) q2s[i] = q2[(size_t)row * DIM + i];
    for (int i = tid; i < CAND_CAP; i += 256)
        recs[i] = (i < (int)cnt) ? candBuf[(size_t)row * CAND_CAP + i] : 0u;
    if (tid == 0) s_R = 0;
    hist[tid] = 0;
    __syncthreads();

    // pass 1: histogram of top byte of s16 (monotone: larger s16 = larger val)
#pragma unroll
    for (int e = 0; e < 2; e++) {
        int i = tid + e * 256;
        if (i < (int)cnt) atomicAdd(&hist[recs[i] >> 24], 1u);
    }
    __syncthreads();
    if (tid == 0) {
        unsigned c = 0; int b = 255;
        for (; b > 0; b--) {
            unsigned h = hist[b];
            if (c + h >= TOPK) break;
            c += h;
        }
        s_b1 = (unsigned)b; s_rem = TOPK - c;
    }
    __syncthreads();
    const unsigned b1 = s_b1, rem = s_rem;
    hist[tid] = 0;
    __syncthreads();

    // pass 2: low byte among records with top byte == b1
#pragma unroll
    for (int e = 0; e < 2; e++) {
        int i = tid + e * 256;
        if (i < (int)cnt && (recs[i] >> 24) == b1)
            atomicAdd(&hist[(recs[i] >> 16) & 0xFFu], 1u);
    }
    __syncthreads();
    if (tid == 0) {
        unsigned c = 0; int b = 255;
        for (; b > 0; b--) {
            unsigned h = hist[b];
            if (c + h >= rem) break;
            c += h;
        }
        s_thr = (b1 << 8) | (unsigned)b;       // s16 of 64th-largest record
    }
    __syncthreads();

    const float a64  = dec16(s_thr);
    const float band = a64 - 2.f * EPS_SEL;
    if (trow[row] > band) {
        if (tid == 0) flags[row] = 1u;
        return;
    }

    // band-compaction (unordered; exact sort later restores determinism)
#pragma unroll
    for (int e = 0; e < 2; e++) {
        int i = tid + e * 256;
        if (i < (int)cnt && dec16(recs[i] >> 16) >= band) {
            unsigned p = atomicAdd(&s_R, 1u);
            if (p < RES_CAP) list[p] = recs[i];
        }
    }
    __syncthreads();
    const int R = (int)s_R;
    if (R > RES_CAP) {
        if (tid == 0) flags[row] = 1u;
        return;
    }

    // fp64 rescue: wave per candidate, coalesced codebook reads
    for (int c = wave; c < R; c += 4) {
        unsigned idx = list[c] & 0xFFFFu;
        const float* cb = codebook + (size_t)idx * DIM + lane * 8;
        float4 c0 = *(const float4*)cb, c1 = *(const float4*)(cb + 4);
        const float* qp = &q2s[lane * 8];
        float4 a0 = *(const float4*)qp, a1 = *(const float4*)(qp + 4);
        double s = (double)a0.x * c0.x + (double)a0.y * c0.y
                 + (double)a0.z * c0.z + (double)a0.w * c0.w
                 + (double)a1.x * c1.x + (double)a1.y * c1.y
                 + (double)a1.z * c1.z + (double)a1.w * c1.w;
#pragma unroll
        for (int off = 32; off > 0; off >>= 1) s += __shfl_down(s, off);
        if (lane == 0) {
            float val = (float)s;
            unsigned b = __float_as_uint(val);
            unsigned sk = (b & 0x80000000u) ? ~b : (b | 0x80000000u);
            keys[c] = ((unsigned long long)(~sk) << 32) | idx;
        }
    }
    if (tid >= R && tid < RES_CAP) keys[tid] = ~0ULL;
    __syncthreads();

    // bitonic sort 256 u64 ascending (= descending by exact value)
    for (int k = 2; k <= RES_CAP; k <<= 1) {
        for (int j = k >> 1; j > 0; j >>= 1) {
            int ixj = tid ^ j;
            if (ixj > tid) {
                unsigned long long a = keys[tid], b2 = keys[ixj];
                if (((tid & k) == 0) ? (a > b2) : (a < b2)) { keys[tid] = b2; keys[ixj] = a; }
            }
            __syncthreads();
        }
    }

    const unsigned threshInv = (unsigned)(keys[TOPK - 1] >> 32);
    unsigned sk0 = ~(unsigned)(keys[0] >> 32);
    const float vmax = __uint_as_float((sk0 & 0x80000000u) ? (sk0 & 0x7FFFFFFFu) : ~sk0);

    unsigned hi = (unsigned)(keys[tid] >> 32);
    bool sel = (hi <= threshInv);
    unsigned sk = ~hi;
    float val = __uint_as_float((sk & 0x80000000u) ? (sk & 0x7FFFFFFFu) : ~sk);
    float w = sel ? expf(val - vmax) : 0.f;
    wArr[tid] = w;
    redf[tid] = w;
    redu[tid] = sel ? 1u : 0u;
    __syncthreads();
    for (int s = 128; s > 0; s >>= 1) {
        if (tid < s) { redf[tid] += redf[tid + s]; redu[tid] += redu[tid + s]; }
        __syncthreads();
    }
    const float invZ = 1.0f / redf[0];
    const int selCount = (int)redu[0];

    // y_row = sum_i w_i * codebook[idx_i, :]
    for (int d = tid; d < DIM; d += 256) {
        float acc = 0.f;
        for (int i = 0; i < selCount; i++) {
            unsigned idx = (unsigned)(keys[i] & 0xFFFFFFFFu);
            acc += wArr[i] * codebook[(size_t)idx * DIM + d];
        }
        y[(size_t)row * DIM + d] = acc * invZ;
    }
}

// ---------------------------------------------------------------------------
// Exact fallback for flagged rows (expected: none). fp64 scan over all VOC.
// ---------------------------------------------------------------------------
__global__ __launch_bounds__(256)
void fallback_row(const unsigned* __restrict__ flags, const float* __restrict__ q2,
                  const float* __restrict__ codebook, const float* __restrict__ trow,
                  const float* __restrict__ sigrow, float* __restrict__ y)
{
    const int row = blockIdx.x;
    if (!flags[row]) return;

    __shared__ float q2s[DIM];
    __shared__ unsigned long long keys[FCAP];
    __shared__ float wArr[FCAP];
    __shared__ float redf[256];
    __shared__ unsigned redu[256];
    __shared__ unsigned s_cnt;

    const int tid = threadIdx.x;
    for (int i = tid; i < DIM; i += 256) q2s[i] = q2[(size_t)row * DIM + i];
    const float sig = sigrow[row];
    float tf = trow[row] - 0.35f * sig;
    unsigned cnt = 0;

    for (int it = 0; it < 16; it++) {
        if (tid == 0) s_cnt = 0;
        __syncthreads();
        for (int i = tid; i < VOC; i += 256) {
            const float* cb = codebook + (size_t)i * DIM;
            double s = 0.0;
            for (int d = 0; d < DIM; d += 4) {
                float4 c4 = *(const float4*)(cb + d);
                s += (double)q2s[d + 0] * (double)c4.x + (double)q2s[d + 1] * (double)c4.y
                   + (double)q2s[d + 2] * (double)c4.z + (double)q2s[d + 3] * (double)c4.w;
            }
            float vv = (float)s;
            if (vv >= tf) {
                unsigned p = atomicAdd(&s_cnt, 1u);
                if (p < FCAP) {
                    unsigned b = __float_as_uint(vv);
                    unsigned sk = (b & 0x80000000u) ? ~b : (b | 0x80000000u);
                    keys[p] = ((unsigned long long)(~sk) << 32) | (unsigned)i;
                }
            }
        }
        __syncthreads();
        cnt = s_cnt;
        if (cnt > FCAP) { tf += 0.15f * sig; continue; }
        if (cnt < TOPK) { tf -= 0.35f * sig; continue; }
        break;
    }
    if (cnt > FCAP) cnt = FCAP;
    for (int i = tid; i < FCAP; i += 256)
        if (i >= (int)cnt) keys[i] = ~0ULL;
    __syncthreads();

    for (int k = 2; k <= FCAP; k <<= 1) {
        for (int j = k >> 1; j > 0; j >>= 1) {
#pragma unroll
            for (int e = 0; e < 4; e++) {
                int i = tid + e * 256;
                int ixj = i ^ j;
                if (ixj > i) {
                    unsigned long long a = keys[i], b = keys[ixj];
                    if (((i & k) == 0) ? (a > b) : (a < b)) { keys[i] = b; keys[ixj] = a; }
                }
            }
            __syncthreads();
        }
    }

    const unsigned threshInv = (unsigned)(keys[TOPK - 1] >> 32);
    unsigned sk0 = ~(unsigned)(keys[0] >> 32);
    const float vmax = __uint_as_float((sk0 & 0x80000000u) ? (sk0 & 0x7FFFFFFFu) : ~sk0);

    float lsum = 0.f; unsigned lcnt = 0;
    for (int i = tid; i < FCAP; i += 256) {
        unsigned hi = (unsigned)(keys[i] >> 32);
        bool sel = (hi <= threshInv);
        unsigned sk = ~hi;
        float vv = __uint_as_float((sk & 0x80000000u) ? (sk & 0x7FFFFFFFu) : ~sk);
        float w = sel ? expf(vv - vmax) : 0.f;
        wArr[i] = w;
        lsum += w; lcnt += sel ? 1u : 0u;
    }
    redf[tid] = lsum; redu[tid] = lcnt;
    __syncthreads();
    for (int s = 128; s > 0; s >>= 1) {
        if (tid < s) { redf[tid] += redf[tid + s]; redu[tid] += redu[tid + s]; }
        __syncthreads();
    }
    const float invZ = 1.f / redf[0];
    const int selCount = (int)redu[0];

    for (int d = tid; d < DIM; d += 256) {
        float acc = 0.f;
        for (int i = 0; i < selCount; i++) {
            unsigned idx = (unsigned)(keys[i] & 0xFFFFFFFFu);
            acc += wArr[i] * codebook[(size_t)idx * DIM + d];
        }
        y[(size_t)row * DIM + d] = acc * invZ;
    }
}

// ---------------------------------------------------------------------------
extern "C" void kernel_launch(void* const* d_in, const int* in_sizes, int n_in,
                              void* d_out, int out_size, void* d_ws, size_t ws_size,
                              hipStream_t stream)
{
    const float* x        = (const float*)d_in[0];
    const float* codebook = (const float*)d_in[1];
    const float* Wq       = (const float*)d_in[2];
    const float* bq       = (const float*)d_in[3];
    const float* Wk       = (const float*)d_in[4];
    // d_in[5] = bk: per-row-constant shift in dots (top-k & softmax invariant)
    const float* Wv       = (const float*)d_in[6];
    const float* bv       = (const float*)d_in[7];
    float* out = (float*)d_out;

    // workspace (~72 MB)
    float* q2   = (float*)d_ws;                       // 4096x512   (8 MB)
    float* Wqk  = q2   + (size_t)BATCH * DIM;         // 512x512    (1 MB)
    float* bqk  = Wqk  + (size_t)DIM * DIM;           // 512 (pad 1024)
    float* y    = bqk  + 1024;                        // 4096x512   (8 MB)
    float* trow = y    + (size_t)BATCH * DIM;         // 4096
    float* sigr = trow + BATCH;                       // 4096
    unsigned* counters = (unsigned*)(sigr + BATCH);   // 4096
    unsigned* flags    = counters + BATCH;            // 4096
    float* cbarsum     = (float*)(flags + BATCH);     // 512
    unsigned* candBuf  = (unsigned*)(cbarsum + 512);  // 4096x512 (8 MB)
    u16* q2h = (u16*)(candBuf + (size_t)BATCH * CAND_CAP);   // 4 MB
    u16* cbh = q2h + (size_t)BATCH * DIM;                    // 32 MB
    u16* yh  = cbh + (size_t)VOC * DIM;                      // 4 MB
    u16* yl  = yh  + (size_t)BATCH * DIM;                    // 4 MB
    u16* wvh = yl  + (size_t)BATCH * DIM;                    // 0.5 MB
    u16* wvl = wvh + (size_t)DIM * DIM;                      // 0.5 MB

    // aliases (no workspace growth):
    //  - x hi/lo pack lives in yh/yl (yh/yl not needed until after select6)
    //  - Wqk hi/lo pack lives in candBuf (candBuf not needed until mfma_dots)
    u16* xh   = yh;
    u16* xl   = yl;
    u16* wqkh = (u16*)candBuf;
    u16* wqkl = wqkh + (size_t)DIM * DIM;

    dim3 blk(256);

    // zero counters+flags+cbarsum first (cbar_accum in fused_prep needs it)
    zero_ws<<<dim3(34), blk, 0, stream>>>(counters, BATCH * 2 + 512);

    // Wqk = Wq @ Wk^T (fp64-flush fold, precision anchor)
    gemm64<true, true><<<dim3(DIM / 64, DIM / 64), blk, 0, stream>>>(
        Wq, Wk, nullptr, Wqk, DIM, DIM, DIM);

    // all independent prep in ONE launch: x-pack | Wqk-pack | cb-pack |
    // Wv-pack | cbar_accum | bias_fold
    fused_prep<<<dim3(9856), blk, 0, stream>>>(
        x, Wqk, codebook, Wv, bq, Wk,
        xh, xl, wqkh, wqkl, cbh, wvh, wvl, cbarsum, bqk);

    // q2 = x @ Wqk + bqk via hi/lo 3-pass MFMA (regridded: 256 blocks)
    mfma_out<<<dim3(DIM / 64, BATCH / 128), blk, 0, stream>>>(
        xh, xl, wqkh, wqkl, bqk, q2, BATCH);

    // rowstats + q2-pack in one launch
    fused_q2post<<<dim3(2048), blk, 0, stream>>>(q2, cbarsum, trow, sigr, q2h);

    // fused dots GEMM (v14: m97-shape, BK=64 single-buffer) + candidate append
    mfma_dots<<<dim3(8192), blk, 0, stream>>>(q2h, cbh, trow, candBuf, counters);

    // exact selection (histogram) + softmax + y = attn @ codebook
    select6<<<dim3(BATCH), blk, 0, stream>>>(
        candBuf, counters, trow, q2, codebook, y, flags);
    fallback_row<<<dim3(BATCH), blk, 0, stream>>>(
        flags, q2, codebook, trow, sigr, y);

    // out = y @ Wv + bv  (hi/lo 3-pass MFMA, regridded: 256 blocks)
    pack_rows<<<dim3(BATCH * 64 / 256), blk, 0, stream>>>(y, yh, yl, BATCH, 12);
    mfma_out<<<dim3(DIM / 64, BATCH / 128), blk, 0, stream>>>(
        yh, yl, wvh, wvl, bv, out, BATCH);
}

// Round 10
// 663.266 us; speedup vs baseline: 1.0059x; 1.0059x over previous
//
#include <hip/hip_runtime.h>
#include <cstdint>

#define VOC   32768
#define DIM   512
#define TOPK  64
#define BATCH 4096

#define KSIG     2.45f
#define EPS_SEL  0.012f
#define CAND_CAP 512
#define RES_CAP  256
#define FCAP     1024

typedef unsigned short u16;
typedef __attribute__((ext_vector_type(8))) short bf16x8;
typedef __attribute__((ext_vector_type(4))) float f32x4;

// ---- bf16 helpers (RNE) ----------------------------------------------------
__device__ __forceinline__ u16 f2bf(float f) {
    unsigned u = __float_as_uint(f);
    unsigned r = (u + 0x7FFFu + ((u >> 16) & 1u)) >> 16;
    return (u16)r;
}
__device__ __forceinline__ float bf2f(u16 h) {
    return __uint_as_float(((unsigned)h) << 16);
}
__device__ __forceinline__ unsigned enc16(u16 h) {
    return (h & 0x8000u) ? (unsigned)((u16)~h) : (unsigned)(h | 0x8000u);
}
__device__ __forceinline__ float dec16(unsigned s16) {
    u16 h = (s16 & 0x8000u) ? (u16)(s16 ^ 0x8000u) : (u16)(~s16);
    return bf2f(h);
}

// ---- async global->LDS 16B -------------------------------------------------
__device__ __forceinline__ void async16(const void* g, void* l) {
    __builtin_amdgcn_global_load_lds(
        (const __attribute__((address_space(1))) void*)g,
        (__attribute__((address_space(3))) void*)l, 16, 0, 0);
}

// ---------------------------------------------------------------------------
// fp32 64x64-tile GEMM + optional per-k-tile fp64 flush. 256 thr, 4x4 micro.
// Retained ONLY for the small precision-critical fold Wqk = Wq @ Wk^T.
// ---------------------------------------------------------------------------
template <bool BT, bool F64ACC>
__global__ __launch_bounds__(256)
void gemm64(const float* __restrict__ A, const float* __restrict__ B,
            const float* __restrict__ bias, float* __restrict__ C,
            int M, int N, int K)
{
    const int KS = 16;
    __shared__ float As[KS][68];
    __shared__ float Bs[KS][64];

    const int tid = threadIdx.x;
    const int m0 = blockIdx.y * 64;
    const int n0 = blockIdx.x * 64;
    const int ty = tid >> 4;
    const int tx = tid & 15;

    float acc[4][4];
    double acc64[4][4];
#pragma unroll
    for (int i = 0; i < 4; i++)
#pragma unroll
        for (int j = 0; j < 4; j++) { acc[i][j] = 0.f; if (F64ACC) acc64[i][j] = 0.0; }

    for (int kt = 0; kt < K; kt += KS) {
        {
            int row = tid >> 2, kq = tid & 3;
            const float4 av = *(const float4*)(A + (size_t)(m0 + row) * K + kt + kq * 4);
            As[kq * 4 + 0][row] = av.x;
            As[kq * 4 + 1][row] = av.y;
            As[kq * 4 + 2][row] = av.z;
            As[kq * 4 + 3][row] = av.w;
        }
        if (!BT) {
            int krow = tid >> 4, nq = tid & 15;
            *(float4*)&Bs[krow][nq * 4] =
                *(const float4*)(B + (size_t)(kt + krow) * N + n0 + nq * 4);
        } else {
            int nrow = tid >> 2, kq = tid & 3;
            const float4 bv = *(const float4*)(B + (size_t)(n0 + nrow) * K + kt + kq * 4);
            Bs[kq * 4 + 0][nrow] = bv.x;
            Bs[kq * 4 + 1][nrow] = bv.y;
            Bs[kq * 4 + 2][nrow] = bv.z;
            Bs[kq * 4 + 3][nrow] = bv.w;
        }
        __syncthreads();

#pragma unroll
        for (int kk = 0; kk < KS; kk++) {
            float4 a = *(const float4*)&As[kk][ty * 4];
            float4 b = *(const float4*)&Bs[kk][tx * 4];
            float av[4] = {a.x, a.y, a.z, a.w};
            float bv[4] = {b.x, b.y, b.z, b.w};
#pragma unroll
            for (int i = 0; i < 4; i++)
#pragma unroll
                for (int j = 0; j < 4; j++)
                    acc[i][j] += av[i] * bv[j];
        }
        __syncthreads();
        if (F64ACC) {
#pragma unroll
            for (int i = 0; i < 4; i++)
#pragma unroll
                for (int j = 0; j < 4; j++) { acc64[i][j] += (double)acc[i][j]; acc[i][j] = 0.f; }
        }
    }

    float4 bb = make_float4(0.f, 0.f, 0.f, 0.f);
    if (bias) bb = *(const float4*)(bias + n0 + tx * 4);
#pragma unroll
    for (int i = 0; i < 4; i++) {
        float4 o;
        o.x = (F64ACC ? (float)acc64[i][0] : acc[i][0]) + bb.x;
        o.y = (F64ACC ? (float)acc64[i][1] : acc[i][1]) + bb.y;
        o.z = (F64ACC ? (float)acc64[i][2] : acc[i][2]) + bb.z;
        o.w = (F64ACC ? (float)acc64[i][3] : acc[i][3]) + bb.w;
        *(float4*)(C + (size_t)(m0 + ty * 4 + i) * N + n0 + tx * 4) = o;
    }
}

__global__ void zero_ws(unsigned* __restrict__ p, int n)
{
    int i = blockIdx.x * 256 + threadIdx.x;
    if (i < n) p[i] = 0u;
}

// ---------------------------------------------------------------------------
// Device bodies for the fused prep kernels (virtual block id passed in).
// ---------------------------------------------------------------------------
__device__ __forceinline__ void pack_rows_dev(int bid, int tid,
        const float* __restrict__ src, u16* __restrict__ hi,
        u16* __restrict__ lo, int R, int log2R)
{
    int idx = bid * 256 + tid;
    int c8  = idx >> log2R;
    int row = idx & (R - 1);
    const float* sp = src + (size_t)row * DIM + c8 * 8;
    float xv[8];
    *(float4*)&xv[0] = *(const float4*)sp;
    *(float4*)&xv[4] = *(const float4*)(sp + 4);
    int ks = c8 >> 2, ch = c8 & 3;
    size_t ob = ((size_t)(ks * 4 + ch) * R + row) * 8;
    u16 h[8], l[8];
#pragma unroll
    for (int j = 0; j < 8; j++) {
        h[j] = f2bf(xv[j]);
        l[j] = f2bf(xv[j] - bf2f(h[j]));
    }
    *(uint4*)(hi + ob) = *(const uint4*)h;
    if (lo) *(uint4*)(lo + ob) = *(const uint4*)l;
}

__device__ __forceinline__ void pack_bT_dev(int bid, int tid,
        const float* __restrict__ W, u16* __restrict__ hi, u16* __restrict__ lo)
{
    int idx = bid * 256 + tid;
    int n  = idx & (DIM - 1);
    int c8 = idx >> 9;
    int ks = c8 >> 2, ch = c8 & 3;
    size_t ob = ((size_t)(ks * 4 + ch) * DIM + n) * 8;
    u16 h[8], l[8];
#pragma unroll
    for (int j = 0; j < 8; j++) {
        float x = W[(size_t)(c8 * 8 + j) * DIM + n];
        h[j] = f2bf(x);
        l[j] = f2bf(x - bf2f(h[j]));
    }
    *(uint4*)(hi + ob) = *(const uint4*)h;
    *(uint4*)(lo + ob) = *(const uint4*)l;
}

__device__ __forceinline__ void cbar_dev(int bid, int tid,
        const float* __restrict__ cb, float* __restrict__ cbarsum)
{
    const int r0 = bid * 128;
    float s0 = 0.f, s1 = 0.f;
    for (int r = 0; r < 128; r++) {
        const float* rp = cb + (size_t)(r0 + r) * DIM;
        s0 += rp[tid];
        s1 += rp[tid + 256];
    }
    atomicAdd(&cbarsum[tid], s0);
    atomicAdd(&cbarsum[tid + 256], s1);
}

__device__ __forceinline__ void bias_fold_dev(int bid, int tid,
        const float* __restrict__ bq, const float* __restrict__ Wk,
        float* __restrict__ bqk)
{
    const int lane = tid & 63, wave = tid >> 6;
    const int j = bid * 4 + wave;
    const float* wr = Wk + (size_t)j * DIM + lane * 8;
    const float* bp = bq + lane * 8;
    double s = 0.0;
#pragma unroll
    for (int t = 0; t < 8; t++) s += (double)bp[t] * (double)wr[t];
#pragma unroll
    for (int off = 32; off > 0; off >>= 1) s += __shfl_down(s, off);
    if (lane == 0) bqk[j] = (float)s;
}

__device__ __forceinline__ void rowstats_dev(int bid, int tid,
        const float* __restrict__ q2, const float* __restrict__ cbarsum,
        float* __restrict__ trow, float* __restrict__ sigrow)
{
    const int lane = tid & 63, wave = tid >> 6;
    const int row = bid * 4 + wave;
    const float* qp = q2 + (size_t)row * DIM + lane * 8;
    float4 a0 = *(const float4*)qp, a1 = *(const float4*)(qp + 4);
    const float* cp = cbarsum + lane * 8;
    float4 c0 = *(const float4*)cp, c1 = *(const float4*)(cp + 4);
    float mu = a0.x*c0.x + a0.y*c0.y + a0.z*c0.z + a0.w*c0.w
             + a1.x*c1.x + a1.y*c1.y + a1.z*c1.z + a1.w*c1.w;
    float nr = a0.x*a0.x + a0.y*a0.y + a0.z*a0.z + a0.w*a0.w
             + a1.x*a1.x + a1.y*a1.y + a1.z*a1.z + a1.w*a1.w;
#pragma unroll
    for (int off = 32; off > 0; off >>= 1) {
        mu += __shfl_down(mu, off);
        nr += __shfl_down(nr, off);
    }
    if (lane == 0) {
        mu *= (1.f / VOC);
        float sig = sqrtf(nr * (1.f / 1536.f));
        trow[row] = mu + KSIG * sig;
        sigrow[row] = sig;
    }
}

// ---------------------------------------------------------------------------
// fused_prep: all pre-dots prep that only depends on {inputs, Wqk, zeroed ws}.
// Block ranges: [0,1024) x-pack hi/lo | [1024,1152) Wqk-bT | [1152,9344)
// cb-pack | [9344,9472) Wv-bT | [9472,9728) cbar_accum | [9728,9856) bias_fold
// ---------------------------------------------------------------------------
__global__ __launch_bounds__(256)
void fused_prep(const float* __restrict__ x, const float* __restrict__ Wqk,
                const float* __restrict__ codebook, const float* __restrict__ Wv,
                const float* __restrict__ bq, const float* __restrict__ Wk,
                u16* __restrict__ xh, u16* __restrict__ xl,
                u16* __restrict__ wqkh, u16* __restrict__ wqkl,
                u16* __restrict__ cbh, u16* __restrict__ wvh,
                u16* __restrict__ wvl, float* __restrict__ cbarsum,
                float* __restrict__ bqk)
{
    const int b = blockIdx.x, tid = threadIdx.x;
    if (b < 1024)       pack_rows_dev(b, tid, x, xh, xl, BATCH, 12);
    else if (b < 1152)  pack_bT_dev(b - 1024, tid, Wqk, wqkh, wqkl);
    else if (b < 9344)  pack_rows_dev(b - 1152, tid, codebook, cbh, nullptr, VOC, 15);
    else if (b < 9472)  pack_bT_dev(b - 9344, tid, Wv, wvh, wvl);
    else if (b < 9728)  cbar_dev(b - 9472, tid, codebook, cbarsum);
    else                bias_fold_dev(b - 9728, tid, bq, Wk, bqk);
}

// fused_q2post: rowstats + q2-pack (both read q2). [0,1024) | [1024,2048)
__global__ __launch_bounds__(256)
void fused_q2post(const float* __restrict__ q2, const float* __restrict__ cbarsum,
                  float* __restrict__ trow, float* __restrict__ sigrow,
                  u16* __restrict__ q2h)
{
    const int b = blockIdx.x, tid = threadIdx.x;
    if (b < 1024) rowstats_dev(b, tid, q2, cbarsum, trow, sigrow);
    else          pack_rows_dev(b - 1024, tid, q2, q2h, nullptr, BATCH, 12);
}

// ---------------------------------------------------------------------------
// Fused dots GEMM v13 (best measured, 238.2us): 128x128, 4 waves, acc[4][4]=
// 64 AGPR, 32KB LDS 2-stage, (256,4) -> 16 waves/CU = register-file roofline
// (v6/v12 proved growing past it spills; v14's BK=64 single-buffer exposed
// staging and regressed +26us). Counted-vmcnt pipeline: per step s:
//   wait vmcnt(4) -> barrier A -> 4 ds_read A + 3x(ds_read B + 4 MFMA) + B3
//   -> lgkmcnt(0) + barrier B -> ISSUE(s+2) into just-freed buffer -> 4 MFMA.
// ---------------------------------------------------------------------------
__global__ __launch_bounds__(256, 4)
void mfma_dots(const u16* __restrict__ Ah, const u16* __restrict__ Bh,
               const float* __restrict__ trow, unsigned* __restrict__ candBuf,
               unsigned* __restrict__ counters)
{
    __shared__ u16 lds[2 * 8192];      // 2 stages x (A 4096 + B 4096) u16 = 32 KB

    const int tid  = threadIdx.x;
    const int lane = tid & 63;
    const int wave = tid >> 6;
    const int wm = wave >> 1, wn = wave & 1;
    const int lr = lane & 15;
    const int q  = lane >> 4;

    // XCD-affinity: xcd owns a 4-m-tile band; within XCD, m fastest then n.
    const int L   = blockIdx.x;
    const int xcd = L & 7;
    const int j   = L >> 3;                    // 0..1023
    const int m0  = (xcd * 4 + (j & 3)) * 128;
    const int n0  = (j >> 2) * 128;

    const int a  = wave >> 1;                  // 0: stage A (q2h), 1: stage B (cbh)
    const u16* src = a ? Bh : Ah;
    const int rb   = a ? n0 : m0;
    const size_t R = a ? (size_t)VOC : (size_t)BATCH;
    const int i0   = (wave & 1) * 4;

    // strength-reduced staging pointers: gpX walks ks=0..15 by const stride
    const size_t gstep = (size_t)4 * R * 8;    // u16 elems per ks-step
    const u16* gp0 = src + ((size_t)(((i0 + 0) >> 1)) * R + rb + ((i0 + 0) & 1) * 64 + lane) * 8;
    const u16* gp1 = src + ((size_t)(((i0 + 1) >> 1)) * R + rb + ((i0 + 1) & 1) * 64 + lane) * 8;
    const u16* gp2 = src + ((size_t)(((i0 + 2) >> 1)) * R + rb + ((i0 + 2) & 1) * 64 + lane) * 8;
    const u16* gp3 = src + ((size_t)(((i0 + 3) >> 1)) * R + rb + ((i0 + 3) & 1) * 64 + lane) * 8;
    const int loff0 = a * 4096 + (i0 + 0) * 512 + lane * 8;
    const int loff1 = a * 4096 + (i0 + 1) * 512 + lane * 8;
    const int loff2 = a * 4096 + (i0 + 2) * 512 + lane * 8;
    const int loff3 = a * 4096 + (i0 + 3) * 512 + lane * 8;

#define ISSUE(b)                                                              \
    {                                                                         \
        async16(gp0, &lds[(b) * 8192 + loff0]); gp0 += gstep;                 \
        async16(gp1, &lds[(b) * 8192 + loff1]); gp1 += gstep;                 \
        async16(gp2, &lds[(b) * 8192 + loff2]); gp2 += gstep;                 \
        async16(gp3, &lds[(b) * 8192 + loff3]); gp3 += gstep;                 \
    }

    f32x4 acc[4][4] = {};

    // prologue: tiles 0 and 1 in flight (8 loads/thread); ptrs now at ks=2
    ISSUE(0)
    ISSUE(1)

    for (int s = 0; s < 16; s++) {
        if (s < 15) __builtin_amdgcn_s_waitcnt(0x0F74);   // vmcnt(4): stage s landed
        else        __builtin_amdgcn_s_waitcnt(0x0F70);   // vmcnt(0): last stage
        __builtin_amdgcn_s_barrier();                     // A: staging published
        const u16* base = &lds[(s & 1) * 8192];

        bf16x8 ah[4];
#pragma unroll
        for (int mt = 0; mt < 4; mt++)
            ah[mt] = *(const bf16x8*)&base[q * 1024 + (wm * 64 + mt * 16 + lr) * 8];

        __builtin_amdgcn_s_setprio(1);
#pragma unroll
        for (int nt = 0; nt < 3; nt++) {
            bf16x8 bh = *(const bf16x8*)&base[4096 + q * 1024 + (wn * 64 + nt * 16 + lr) * 8];
#pragma unroll
            for (int mt = 0; mt < 4; mt++)
                acc[mt][nt] = __builtin_amdgcn_mfma_f32_16x16x32_bf16(ah[mt], bh, acc[mt][nt], 0, 0, 0);
        }
        bf16x8 bh3 = *(const bf16x8*)&base[4096 + q * 1024 + (wn * 64 + 3 * 16 + lr) * 8];
        __builtin_amdgcn_s_setprio(0);

        __builtin_amdgcn_s_waitcnt(0xC07F);    // lgkmcnt(0): this wave's 8 reads done
        __builtin_amdgcn_s_barrier();          // B: ALL waves done reading buf[s&1]
        __builtin_amdgcn_sched_barrier(0);
        if (s < 14) ISSUE(s & 1)               // stage s+2 into just-freed buffer

        __builtin_amdgcn_s_setprio(1);
#pragma unroll
        for (int mt = 0; mt < 4; mt++)
            acc[mt][3] = __builtin_amdgcn_mfma_f32_16x16x32_bf16(ah[mt], bh3, acc[mt][3], 0, 0, 0);
        __builtin_amdgcn_s_setprio(0);
    }
#undef ISSUE

    // epilogue: threshold-append candidates
#pragma unroll
    for (int mt = 0; mt < 4; mt++) {
#pragma unroll
        for (int r = 0; r < 4; r++) {
            int rowg = m0 + wm * 64 + mt * 16 + q * 4 + r;
            float tr = trow[rowg];
#pragma unroll
            for (int nt = 0; nt < 4; nt++) {
                float val = acc[mt][nt][r];
                if (val >= tr) {
                    unsigned slot = atomicAdd(&counters[rowg], 1u);
                    if (slot < CAND_CAP) {
                        unsigned s16 = enc16(f2bf(val));
                        candBuf[(size_t)rowg * CAND_CAP + slot] =
                            (s16 << 16) | (unsigned)(n0 + wn * 64 + nt * 16 + lr);
                    }
                }
            }
        }
    }
}

// ---------------------------------------------------------------------------
// out = A @ W + bias in bf16 hi/lo 3-pass MFMA (error ~1e-6). Regrid (r8,
// bit-identical, kept): tile 128m x 64n, grid 256 blocks, acc[4][2]=32 AGPR,
// LDS 48 KB -> 3 blocks/CU. Used for q2 = x@Wqk + bqk and out = y@Wv + bv.
// ---------------------------------------------------------------------------
__global__ __launch_bounds__(256, 3)
void mfma_out(const u16* __restrict__ Ah, const u16* __restrict__ Al,
              const u16* __restrict__ Bh, const u16* __restrict__ Bl,
              const float* __restrict__ bias, float* __restrict__ Cout, int Ma)
{
    __shared__ u16 lds[2 * 12288];   // 2 stages x 24 KB

    const int tid  = threadIdx.x;
    const int lane = tid & 63;
    const int wave = tid >> 6;
    const int wm = wave >> 1, wn = wave & 1;
    const int m0 = blockIdx.y * 128, n0 = blockIdx.x * 64;
    const int lr = lane & 15;
    const int q  = lane >> 4;
    const size_t R = (size_t)Ma;

    f32x4 acc[4][2] = {};

#define VISSUE(ks, b)                                                          \
    {                                                                          \
        _Pragma("unroll")                                                      \
        for (int i_ = 0; i_ < 2; i_++) {                                       \
            int u_ = tid + i_ * 256;                                           \
            size_t ai_ = ((size_t)((ks) * 4 + (u_ >> 7)) * R + m0 + (u_ & 127)) * 8; \
            async16(Ah + ai_, &lds[(b) * 12288 + u_ * 8]);                     \
            async16(Al + ai_, &lds[(b) * 12288 + 6144 + u_ * 8]);              \
        }                                                                      \
        {                                                                      \
            int u_ = tid;                                                      \
            size_t bi_ = ((size_t)((ks) * 4 + (u_ >> 6)) * DIM + n0 + (u_ & 63)) * 8; \
            async16(Bh + bi_, &lds[(b) * 12288 + 4096 + u_ * 8]);              \
            async16(Bl + bi_, &lds[(b) * 12288 + 10240 + u_ * 8]);             \
        }                                                                      \
    }

    VISSUE(0, 0)

    for (int ks = 0; ks < 16; ks++) {
        __syncthreads();                       // drains vmcnt(0): stage ks in LDS
        if (ks < 15) VISSUE(ks + 1, (ks + 1) & 1)
        const u16* base = &lds[(ks & 1) * 12288];

        bf16x8 ah[4], al[4];
#pragma unroll
        for (int mt = 0; mt < 4; mt++) {
            int row = wm * 64 + mt * 16 + lr;
            ah[mt] = *(const bf16x8*)&base[q * 1024 + row * 8];
            al[mt] = *(const bf16x8*)&base[6144 + q * 1024 + row * 8];
        }
#pragma unroll
        for (int nt = 0; nt < 2; nt++) {
            int col = wn * 32 + nt * 16 + lr;
            bf16x8 bh = *(const bf16x8*)&base[4096 + q * 512 + col * 8];
            bf16x8 bl = *(const bf16x8*)&base[10240 + q * 512 + col * 8];
#pragma unroll
            for (int mt = 0; mt < 4; mt++) {
                acc[mt][nt] = __builtin_amdgcn_mfma_f32_16x16x32_bf16(ah[mt], bh, acc[mt][nt], 0, 0, 0);
                acc[mt][nt] = __builtin_amdgcn_mfma_f32_16x16x32_bf16(ah[mt], bl, acc[mt][nt], 0, 0, 0);
                acc[mt][nt] = __builtin_amdgcn_mfma_f32_16x16x32_bf16(al[mt], bh, acc[mt][nt], 0, 0, 0);
            }
        }
    }
#undef VISSUE

#pragma unroll
    for (int mt = 0; mt < 4; mt++)
#pragma unroll
        for (int nt = 0; nt < 2; nt++) {
            int col = n0 + wn * 32 + nt * 16 + lr;
            float bb = bias[col];
#pragma unroll
            for (int r = 0; r < 4; r++) {
                int rowg = m0 + wm * 64 + mt * 16 + q * 4 + r;
                Cout[(size_t)rowg * DIM + col] = acc[mt][nt][r] + bb;
            }
        }
}

// ---------------------------------------------------------------------------
// Select v8: histogram selection -> band-compaction -> fp64 rescue -> exact
// u64 sort -> softmax -> y_row; PLUS (a) inline exact fallback (was a
// separate 4096-block launch of early-returns) and (b) fused y hi/lo pack via
// a 2KB LDS bounce (was a separate pack_rows launch + 16MB of traffic).
// All branches are block-uniform. Bit-identical to the 3-kernel version.
// ---------------------------------------------------------------------------
__global__ __launch_bounds__(256)
void select8(const unsigned* __restrict__ candBuf, const unsigned* __restrict__ counters,
             const float* __restrict__ trow, const float* __restrict__ sigrow,
             const float* __restrict__ q2, const float* __restrict__ codebook,
             float* __restrict__ y, u16* __restrict__ yh, u16* __restrict__ yl)
{
    __shared__ unsigned recs[CAND_CAP];
    __shared__ unsigned list[RES_CAP];
    __shared__ unsigned hist[256];
    __shared__ unsigned long long keys[FCAP];     // union: select 256 / fallback 1024
    __shared__ float q2s[DIM];
    __shared__ float wArr[FCAP];
    __shared__ float yrow[DIM];
    __shared__ float redf[256];
    __shared__ unsigned redu[256];
    __shared__ unsigned s_R, s_b1, s_rem, s_thr, s_cnt;

    const int tid  = threadIdx.x;
    const int lane = tid & 63;
    const int wave = tid >> 6;
    const int row  = blockIdx.x;

    for (int i = tid; i < DIM; i += 256) q2s[i] = q2[(size_t)row * DIM + i];

    const unsigned cnt = counters[row];
    bool fb = (cnt < TOPK || cnt > CAND_CAP);     // block-uniform
    int selCount = 0;
    float invZ = 1.f;

    if (!fb) {
        for (int i = tid; i < CAND_CAP; i += 256)
            recs[i] = (i < (int)cnt) ? candBuf[(size_t)row * CAND_CAP + i] : 0u;
        if (tid == 0) s_R = 0;
        hist[tid] = 0;
        __syncthreads();

        // pass 1: histogram of top byte of s16
#pragma unroll
        for (int e = 0; e < 2; e++) {
            int i = tid + e * 256;
            if (i < (int)cnt) atomicAdd(&hist[recs[i] >> 24], 1u);
        }
        __syncthreads();
        if (tid == 0) {
            unsigned c = 0; int b = 255;
            for (; b > 0; b--) {
                unsigned h = hist[b];
                if (c + h >= TOPK) break;
                c += h;
            }
            s_b1 = (unsigned)b; s_rem = TOPK - c;
        }
        __syncthreads();
        const unsigned b1 = s_b1, rem = s_rem;
        hist[tid] = 0;
        __syncthreads();

        // pass 2: low byte among records with top byte == b1
#pragma unroll
        for (int e = 0; e < 2; e++) {
            int i = tid + e * 256;
            if (i < (int)cnt && (recs[i] >> 24) == b1)
                atomicAdd(&hist[(recs[i] >> 16) & 0xFFu], 1u);
        }
        __syncthreads();
        if (tid == 0) {
            unsigned c = 0; int b = 255;
            for (; b > 0; b--) {
                unsigned h = hist[b];
                if (c + h >= rem) break;
                c += h;
            }
            s_thr = (b1 << 8) | (unsigned)b;
        }
        __syncthreads();

        const float a64  = dec16(s_thr);
        const float band = a64 - 2.f * EPS_SEL;
        if (trow[row] > band) fb = true;

        if (!fb) {
            // band-compaction (unordered; exact sort restores determinism)
#pragma unroll
            for (int e = 0; e < 2; e++) {
                int i = tid + e * 256;
                if (i < (int)cnt && dec16(recs[i] >> 16) >= band) {
                    unsigned p = atomicAdd(&s_R, 1u);
                    if (p < RES_CAP) list[p] = recs[i];
                }
            }
            __syncthreads();
            const int R = (int)s_R;
            if (R > RES_CAP) fb = true;

            if (!fb) {
                // fp64 rescue: wave per candidate, coalesced codebook reads
                for (int c = wave; c < R; c += 4) {
                    unsigned idx = list[c] & 0xFFFFu;
                    const float* cb = codebook + (size_t)idx * DIM + lane * 8;
                    float4 c0 = *(const float4*)cb, c1 = *(const float4*)(cb + 4);
                    const float* qp = &q2s[lane * 8];
                    float4 a0 = *(const float4*)qp, a1 = *(const float4*)(qp + 4);
                    double s = (double)a0.x * c0.x + (double)a0.y * c0.y
                             + (double)a0.z * c0.z + (double)a0.w * c0.w
                             + (double)a1.x * c1.x + (double)a1.y * c1.y
                             + (double)a1.z * c1.z + (double)a1.w * c1.w;
#pragma unroll
                    for (int off = 32; off > 0; off >>= 1) s += __shfl_down(s, off);
                    if (lane == 0) {
                        float val = (float)s;
                        unsigned b = __float_as_uint(val);
                        unsigned sk = (b & 0x80000000u) ? ~b : (b | 0x80000000u);
                        keys[c] = ((unsigned long long)(~sk) << 32) | idx;
                    }
                }
                if (tid >= R && tid < RES_CAP) keys[tid] = ~0ULL;
                __syncthreads();

                // bitonic sort 256 u64 ascending (= descending by exact value)
                for (int k = 2; k <= RES_CAP; k <<= 1) {
                    for (int j = k >> 1; j > 0; j >>= 1) {
                        int ixj = tid ^ j;
                        if (ixj > tid) {
                            unsigned long long a = keys[tid], b2 = keys[ixj];
                            if (((tid & k) == 0) ? (a > b2) : (a < b2)) { keys[tid] = b2; keys[ixj] = a; }
                        }
                        __syncthreads();
                    }
                }

                const unsigned threshInv = (unsigned)(keys[TOPK - 1] >> 32);
                unsigned sk0 = ~(unsigned)(keys[0] >> 32);
                const float vmax = __uint_as_float((sk0 & 0x80000000u) ? (sk0 & 0x7FFFFFFFu) : ~sk0);

                unsigned hi = (unsigned)(keys[tid] >> 32);
                bool sel = (hi <= threshInv);
                unsigned sk = ~hi;
                float val = __uint_as_float((sk & 0x80000000u) ? (sk & 0x7FFFFFFFu) : ~sk);
                float w = sel ? expf(val - vmax) : 0.f;
                wArr[tid] = w;
                redf[tid] = w;
                redu[tid] = sel ? 1u : 0u;
                __syncthreads();
                for (int s = 128; s > 0; s >>= 1) {
                    if (tid < s) { redf[tid] += redf[tid + s]; redu[tid] += redu[tid + s]; }
                    __syncthreads();
                }
                invZ = 1.0f / redf[0];
                selCount = (int)redu[0];
            }
        }
    }

    if (fb) {
        // ---- inline exact fallback: fp64 scan over all VOC ----
        const float sig = sigrow[row];
        float tf = trow[row] - 0.35f * sig;
        unsigned fcnt = 0;

        for (int it = 0; it < 16; it++) {
            if (tid == 0) s_cnt = 0;
            __syncthreads();
            for (int i = tid; i < VOC; i += 256) {
                const float* cb = codebook + (size_t)i * DIM;
                double s = 0.0;
                for (int d = 0; d < DIM; d += 4) {
                    float4 c4 = *(const float4*)(cb + d);
                    s += (double)q2s[d + 0] * (double)c4.x + (double)q2s[d + 1] * (double)c4.y
                       + (double)q2s[d + 2] * (double)c4.z + (double)q2s[d + 3] * (double)c4.w;
                }
                float vv = (float)s;
                if (vv >= tf) {
                    unsigned p = atomicAdd(&s_cnt, 1u);
                    if (p < FCAP) {
                        unsigned b = __float_as_uint(vv);
                        unsigned sk = (b & 0x80000000u) ? ~b : (b | 0x80000000u);
                        keys[p] = ((unsigned long long)(~sk) << 32) | (unsigned)i;
                    }
                }
            }
            __syncthreads();
            fcnt = s_cnt;
            if (fcnt > FCAP) { tf += 0.15f * sig; continue; }
            if (fcnt < TOPK) { tf -= 0.35f * sig; continue; }
            break;
        }
        if (fcnt > FCAP) fcnt = FCAP;
        for (int i = tid; i < FCAP; i += 256)
            if (i >= (int)fcnt) keys[i] = ~0ULL;
        __syncthreads();

        for (int k = 2; k <= FCAP; k <<= 1) {
            for (int j = k >> 1; j > 0; j >>= 1) {
#pragma unroll
                for (int e = 0; e < 4; e++) {
                    int i = tid + e * 256;
                    int ixj = i ^ j;
                    if (ixj > i) {
                        unsigned long long a = keys[i], b = keys[ixj];
                        if (((i & k) == 0) ? (a > b) : (a < b)) { keys[i] = b; keys[ixj] = a; }
                    }
                }
                __syncthreads();
            }
        }

        const unsigned threshInv = (unsigned)(keys[TOPK - 1] >> 32);
        unsigned sk0 = ~(unsigned)(keys[0] >> 32);
        const float vmax = __uint_as_float((sk0 & 0x80000000u) ? (sk0 & 0x7FFFFFFFu) : ~sk0);

        float lsum = 0.f; unsigned lcnt = 0;
        for (int i = tid; i < FCAP; i += 256) {
            unsigned hi = (unsigned)(keys[i] >> 32);
            bool sel = (hi <= threshInv);
            unsigned sk = ~hi;
            float vv = __uint_as_float((sk & 0x80000000u) ? (sk & 0x7FFFFFFFu) : ~sk);
            float w = sel ? expf(vv - vmax) : 0.f;
            wArr[i] = w;
            lsum += w; lcnt += sel ? 1u : 0u;
        }
        redf[tid] = lsum; redu[tid] = lcnt;
        __syncthreads();
        for (int s = 128; s > 0; s >>= 1) {
            if (tid < s) { redf[tid] += redf[tid + s]; redu[tid] += redu[tid + s]; }
            __syncthreads();
        }
        invZ = 1.f / redf[0];
        selCount = (int)redu[0];
    }

    // ---- common tail: y_row + fused hi/lo pack (LDS bounce) ----
    for (int d = tid; d < DIM; d += 256) {
        float acc = 0.f;
        for (int i = 0; i < selCount; i++) {
            unsigned idx = (unsigned)(keys[i] & 0xFFFFFFFFu);
            acc += wArr[i] * codebook[(size_t)idx * DIM + d];
        }
        float v = acc * invZ;
        y[(size_t)row * DIM + d] = v;
        yrow[d] = v;
    }
    __syncthreads();
    if (tid < 64) {
        const int c8 = tid;                    // plane index ks*4+ch == c8
        u16 h[8], l[8];
#pragma unroll
        for (int j = 0; j < 8; j++) {
            float xv = yrow[c8 * 8 + j];
            h[j] = f2bf(xv);
            l[j] = f2bf(xv - bf2f(h[j]));
        }
        size_t ob = ((size_t)c8 * BATCH + row) * 8;
        *(uint4*)(yh + ob) = *(const uint4*)h;
        *(uint4*)(yl + ob) = *(const uint4*)l;
    }
}

// ---------------------------------------------------------------------------
extern "C" void kernel_launch(void* const* d_in, const int* in_sizes, int n_in,
                              void* d_out, int out_size, void* d_ws, size_t ws_size,
                              hipStream_t stream)
{
    const float* x        = (const float*)d_in[0];
    const float* codebook = (const float*)d_in[1];
    const float* Wq       = (const float*)d_in[2];
    const float* bq       = (const float*)d_in[3];
    const float* Wk       = (const float*)d_in[4];
    // d_in[5] = bk: per-row-constant shift in dots (top-k & softmax invariant)
    const float* Wv       = (const float*)d_in[6];
    const float* bv       = (const float*)d_in[7];
    float* out = (float*)d_out;

    // workspace (~72 MB)
    float* q2   = (float*)d_ws;                       // 4096x512   (8 MB)
    float* Wqk  = q2   + (size_t)BATCH * DIM;         // 512x512    (1 MB)
    float* bqk  = Wqk  + (size_t)DIM * DIM;           // 512 (pad 1024)
    float* y    = bqk  + 1024;                        // 4096x512   (8 MB)
    float* trow = y    + (size_t)BATCH * DIM;         // 4096
    float* sigr = trow + BATCH;                       // 4096
    unsigned* counters = (unsigned*)(sigr + BATCH);   // 4096
    unsigned* flags    = counters + BATCH;            // 4096 (unused; layout kept)
    float* cbarsum     = (float*)(flags + BATCH);     // 512
    unsigned* candBuf  = (unsigned*)(cbarsum + 512);  // 4096x512 (8 MB)
    u16* q2h = (u16*)(candBuf + (size_t)BATCH * CAND_CAP);   // 4 MB
    u16* cbh = q2h + (size_t)BATCH * DIM;                    // 32 MB
    u16* yh  = cbh + (size_t)VOC * DIM;                      // 4 MB
    u16* yl  = yh  + (size_t)BATCH * DIM;                    // 4 MB
    u16* wvh = yl  + (size_t)BATCH * DIM;                    // 0.5 MB
    u16* wvl = wvh + (size_t)DIM * DIM;                      // 0.5 MB

    // aliases (no workspace growth):
    //  - x hi/lo pack lives in yh/yl (dead after mfma_out(q2), before select8)
    //  - Wqk hi/lo pack lives in candBuf (candBuf not needed until mfma_dots)
    u16* xh   = yh;
    u16* xl   = yl;
    u16* wqkh = (u16*)candBuf;
    u16* wqkl = wqkh + (size_t)DIM * DIM;

    dim3 blk(256);

    // zero counters+flags+cbarsum first (cbar_accum in fused_prep needs it)
    zero_ws<<<dim3(34), blk, 0, stream>>>(counters, BATCH * 2 + 512);

    // Wqk = Wq @ Wk^T (fp64-flush fold, precision anchor)
    gemm64<true, true><<<dim3(DIM / 64, DIM / 64), blk, 0, stream>>>(
        Wq, Wk, nullptr, Wqk, DIM, DIM, DIM);

    // all independent prep in ONE launch: x-pack | Wqk-pack | cb-pack |
    // Wv-pack | cbar_accum | bias_fold
    fused_prep<<<dim3(9856), blk, 0, stream>>>(
        x, Wqk, codebook, Wv, bq, Wk,
        xh, xl, wqkh, wqkl, cbh, wvh, wvl, cbarsum, bqk);

    // q2 = x @ Wqk + bqk via hi/lo 3-pass MFMA (256 blocks)
    mfma_out<<<dim3(DIM / 64, BATCH / 128), blk, 0, stream>>>(
        xh, xl, wqkh, wqkl, bqk, q2, BATCH);

    // rowstats + q2-pack in one launch
    fused_q2post<<<dim3(2048), blk, 0, stream>>>(q2, cbarsum, trow, sigr, q2h);

    // fused dots GEMM (v13: 2-stage counted-vmcnt pipeline) + candidate append
    mfma_dots<<<dim3(8192), blk, 0, stream>>>(q2h, cbh, trow, candBuf, counters);

    // selection + softmax + y + inline fallback + fused y-pack (one launch)
    select8<<<dim3(BATCH), blk, 0, stream>>>(
        candBuf, counters, trow, sigr, q2, codebook, y, yh, yl);

    // out = y @ Wv + bv  (hi/lo 3-pass MFMA, 256 blocks)
    mfma_out<<<dim3(DIM / 64, BATCH / 128), blk, 0, stream>>>(
        yh, yl, wvh, wvl, bv, out, BATCH);
}

// Round 11
// 653.896 us; speedup vs baseline: 1.0203x; 1.0143x over previous
//
#include <hip/hip_runtime.h>
#include <cstdint>

#define VOC   32768
#define DIM   512
#define TOPK  64
#define BATCH 4096

#define KSIG     2.45f
#define EPS_SEL  0.012f
#define CAND_CAP 512
#define RES_CAP  256
#define FCAP     1024

typedef unsigned short u16;
typedef __attribute__((ext_vector_type(8))) short bf16x8;
typedef __attribute__((ext_vector_type(4))) float f32x4;

// ---- bf16 helpers (RNE) ----------------------------------------------------
__device__ __forceinline__ u16 f2bf(float f) {
    unsigned u = __float_as_uint(f);
    unsigned r = (u + 0x7FFFu + ((u >> 16) & 1u)) >> 16;
    return (u16)r;
}
__device__ __forceinline__ float bf2f(u16 h) {
    return __uint_as_float(((unsigned)h) << 16);
}
__device__ __forceinline__ unsigned enc16(u16 h) {
    return (h & 0x8000u) ? (unsigned)((u16)~h) : (unsigned)(h | 0x8000u);
}
__device__ __forceinline__ float dec16(unsigned s16) {
    u16 h = (s16 & 0x8000u) ? (u16)(s16 ^ 0x8000u) : (u16)(~s16);
    return bf2f(h);
}

// ---- async global->LDS 16B -------------------------------------------------
__device__ __forceinline__ void async16(const void* g, void* l) {
    __builtin_amdgcn_global_load_lds(
        (const __attribute__((address_space(1))) void*)g,
        (__attribute__((address_space(3))) void*)l, 16, 0, 0);
}

// ---- fused y hi/lo pack tail: yrow (LDS, f32[512]) -> yh/yl planes ---------
// Layout identical to pack_rows: plane c8 = ks*4+ch, ob=(c8*BATCH+row)*8.
__device__ __forceinline__ void pack_y_tail(int tid, int row,
        const float* __restrict__ yrow, u16* __restrict__ yh, u16* __restrict__ yl)
{
    if (tid < 64) {
        const int c8 = tid;
        u16 h[8], l[8];
#pragma unroll
        for (int j = 0; j < 8; j++) {
            float xv = yrow[c8 * 8 + j];
            h[j] = f2bf(xv);
            l[j] = f2bf(xv - bf2f(h[j]));
        }
        size_t ob = ((size_t)c8 * BATCH + row) * 8;
        *(uint4*)(yh + ob) = *(const uint4*)h;
        *(uint4*)(yl + ob) = *(const uint4*)l;
    }
}

// ---------------------------------------------------------------------------
// fp32 64x64-tile GEMM + optional per-k-tile fp64 flush. 256 thr, 4x4 micro.
// Retained ONLY for the small precision-critical fold Wqk = Wq @ Wk^T.
// ---------------------------------------------------------------------------
template <bool BT, bool F64ACC>
__global__ __launch_bounds__(256)
void gemm64(const float* __restrict__ A, const float* __restrict__ B,
            const float* __restrict__ bias, float* __restrict__ C,
            int M, int N, int K)
{
    const int KS = 16;
    __shared__ float As[KS][68];
    __shared__ float Bs[KS][64];

    const int tid = threadIdx.x;
    const int m0 = blockIdx.y * 64;
    const int n0 = blockIdx.x * 64;
    const int ty = tid >> 4;
    const int tx = tid & 15;

    float acc[4][4];
    double acc64[4][4];
#pragma unroll
    for (int i = 0; i < 4; i++)
#pragma unroll
        for (int j = 0; j < 4; j++) { acc[i][j] = 0.f; if (F64ACC) acc64[i][j] = 0.0; }

    for (int kt = 0; kt < K; kt += KS) {
        {
            int row = tid >> 2, kq = tid & 3;
            const float4 av = *(const float4*)(A + (size_t)(m0 + row) * K + kt + kq * 4);
            As[kq * 4 + 0][row] = av.x;
            As[kq * 4 + 1][row] = av.y;
            As[kq * 4 + 2][row] = av.z;
            As[kq * 4 + 3][row] = av.w;
        }
        if (!BT) {
            int krow = tid >> 4, nq = tid & 15;
            *(float4*)&Bs[krow][nq * 4] =
                *(const float4*)(B + (size_t)(kt + krow) * N + n0 + nq * 4);
        } else {
            int nrow = tid >> 2, kq = tid & 3;
            const float4 bv = *(const float4*)(B + (size_t)(n0 + nrow) * K + kt + kq * 4);
            Bs[kq * 4 + 0][nrow] = bv.x;
            Bs[kq * 4 + 1][nrow] = bv.y;
            Bs[kq * 4 + 2][nrow] = bv.z;
            Bs[kq * 4 + 3][nrow] = bv.w;
        }
        __syncthreads();

#pragma unroll
        for (int kk = 0; kk < KS; kk++) {
            float4 a = *(const float4*)&As[kk][ty * 4];
            float4 b = *(const float4*)&Bs[kk][tx * 4];
            float av[4] = {a.x, a.y, a.z, a.w};
            float bv[4] = {b.x, b.y, b.z, b.w};
#pragma unroll
            for (int i = 0; i < 4; i++)
#pragma unroll
                for (int j = 0; j < 4; j++)
                    acc[i][j] += av[i] * bv[j];
        }
        __syncthreads();
        if (F64ACC) {
#pragma unroll
            for (int i = 0; i < 4; i++)
#pragma unroll
                for (int j = 0; j < 4; j++) { acc64[i][j] += (double)acc[i][j]; acc[i][j] = 0.f; }
        }
    }

    float4 bb = make_float4(0.f, 0.f, 0.f, 0.f);
    if (bias) bb = *(const float4*)(bias + n0 + tx * 4);
#pragma unroll
    for (int i = 0; i < 4; i++) {
        float4 o;
        o.x = (F64ACC ? (float)acc64[i][0] : acc[i][0]) + bb.x;
        o.y = (F64ACC ? (float)acc64[i][1] : acc[i][1]) + bb.y;
        o.z = (F64ACC ? (float)acc64[i][2] : acc[i][2]) + bb.z;
        o.w = (F64ACC ? (float)acc64[i][3] : acc[i][3]) + bb.w;
        *(float4*)(C + (size_t)(m0 + ty * 4 + i) * N + n0 + tx * 4) = o;
    }
}

__global__ void zero_ws(unsigned* __restrict__ p, int n)
{
    int i = blockIdx.x * 256 + threadIdx.x;
    if (i < n) p[i] = 0u;
}

// ---------------------------------------------------------------------------
// Device bodies for the fused prep kernels (virtual block id passed in).
// ---------------------------------------------------------------------------
__device__ __forceinline__ void pack_rows_dev(int bid, int tid,
        const float* __restrict__ src, u16* __restrict__ hi,
        u16* __restrict__ lo, int R, int log2R)
{
    int idx = bid * 256 + tid;
    int c8  = idx >> log2R;
    int row = idx & (R - 1);
    const float* sp = src + (size_t)row * DIM + c8 * 8;
    float xv[8];
    *(float4*)&xv[0] = *(const float4*)sp;
    *(float4*)&xv[4] = *(const float4*)(sp + 4);
    int ks = c8 >> 2, ch = c8 & 3;
    size_t ob = ((size_t)(ks * 4 + ch) * R + row) * 8;
    u16 h[8], l[8];
#pragma unroll
    for (int j = 0; j < 8; j++) {
        h[j] = f2bf(xv[j]);
        l[j] = f2bf(xv[j] - bf2f(h[j]));
    }
    *(uint4*)(hi + ob) = *(const uint4*)h;
    if (lo) *(uint4*)(lo + ob) = *(const uint4*)l;
}

__device__ __forceinline__ void pack_bT_dev(int bid, int tid,
        const float* __restrict__ W, u16* __restrict__ hi, u16* __restrict__ lo)
{
    int idx = bid * 256 + tid;
    int n  = idx & (DIM - 1);
    int c8 = idx >> 9;
    int ks = c8 >> 2, ch = c8 & 3;
    size_t ob = ((size_t)(ks * 4 + ch) * DIM + n) * 8;
    u16 h[8], l[8];
#pragma unroll
    for (int j = 0; j < 8; j++) {
        float x = W[(size_t)(c8 * 8 + j) * DIM + n];
        h[j] = f2bf(x);
        l[j] = f2bf(x - bf2f(h[j]));
    }
    *(uint4*)(hi + ob) = *(const uint4*)h;
    *(uint4*)(lo + ob) = *(const uint4*)l;
}

__device__ __forceinline__ void cbar_dev(int bid, int tid,
        const float* __restrict__ cb, float* __restrict__ cbarsum)
{
    const int r0 = bid * 128;
    float s0 = 0.f, s1 = 0.f;
    for (int r = 0; r < 128; r++) {
        const float* rp = cb + (size_t)(r0 + r) * DIM;
        s0 += rp[tid];
        s1 += rp[tid + 256];
    }
    atomicAdd(&cbarsum[tid], s0);
    atomicAdd(&cbarsum[tid + 256], s1);
}

__device__ __forceinline__ void bias_fold_dev(int bid, int tid,
        const float* __restrict__ bq, const float* __restrict__ Wk,
        float* __restrict__ bqk)
{
    const int lane = tid & 63, wave = tid >> 6;
    const int j = bid * 4 + wave;
    const float* wr = Wk + (size_t)j * DIM + lane * 8;
    const float* bp = bq + lane * 8;
    double s = 0.0;
#pragma unroll
    for (int t = 0; t < 8; t++) s += (double)bp[t] * (double)wr[t];
#pragma unroll
    for (int off = 32; off > 0; off >>= 1) s += __shfl_down(s, off);
    if (lane == 0) bqk[j] = (float)s;
}

__device__ __forceinline__ void rowstats_dev(int bid, int tid,
        const float* __restrict__ q2, const float* __restrict__ cbarsum,
        float* __restrict__ trow, float* __restrict__ sigrow)
{
    const int lane = tid & 63, wave = tid >> 6;
    const int row = bid * 4 + wave;
    const float* qp = q2 + (size_t)row * DIM + lane * 8;
    float4 a0 = *(const float4*)qp, a1 = *(const float4*)(qp + 4);
    const float* cp = cbarsum + lane * 8;
    float4 c0 = *(const float4*)cp, c1 = *(const float4*)(cp + 4);
    float mu = a0.x*c0.x + a0.y*c0.y + a0.z*c0.z + a0.w*c0.w
             + a1.x*c1.x + a1.y*c1.y + a1.z*c1.z + a1.w*c1.w;
    float nr = a0.x*a0.x + a0.y*a0.y + a0.z*a0.z + a0.w*a0.w
             + a1.x*a1.x + a1.y*a1.y + a1.z*a1.z + a1.w*a1.w;
#pragma unroll
    for (int off = 32; off > 0; off >>= 1) {
        mu += __shfl_down(mu, off);
        nr += __shfl_down(nr, off);
    }
    if (lane == 0) {
        mu *= (1.f / VOC);
        float sig = sqrtf(nr * (1.f / 1536.f));
        trow[row] = mu + KSIG * sig;
        sigrow[row] = sig;
    }
}

// ---------------------------------------------------------------------------
// fused_prep: all pre-dots prep that only depends on {inputs, Wqk, zeroed ws}.
// Block ranges: [0,1024) x-pack hi/lo | [1024,1152) Wqk-bT | [1152,9344)
// cb-pack | [9344,9472) Wv-bT | [9472,9728) cbar_accum | [9728,9856) bias_fold
// ---------------------------------------------------------------------------
__global__ __launch_bounds__(256)
void fused_prep(const float* __restrict__ x, const float* __restrict__ Wqk,
                const float* __restrict__ codebook, const float* __restrict__ Wv,
                const float* __restrict__ bq, const float* __restrict__ Wk,
                u16* __restrict__ xh, u16* __restrict__ xl,
                u16* __restrict__ wqkh, u16* __restrict__ wqkl,
                u16* __restrict__ cbh, u16* __restrict__ wvh,
                u16* __restrict__ wvl, float* __restrict__ cbarsum,
                float* __restrict__ bqk)
{
    const int b = blockIdx.x, tid = threadIdx.x;
    if (b < 1024)       pack_rows_dev(b, tid, x, xh, xl, BATCH, 12);
    else if (b < 1152)  pack_bT_dev(b - 1024, tid, Wqk, wqkh, wqkl);
    else if (b < 9344)  pack_rows_dev(b - 1152, tid, codebook, cbh, nullptr, VOC, 15);
    else if (b < 9472)  pack_bT_dev(b - 9344, tid, Wv, wvh, wvl);
    else if (b < 9728)  cbar_dev(b - 9472, tid, codebook, cbarsum);
    else                bias_fold_dev(b - 9728, tid, bq, Wk, bqk);
}

// fused_q2post: rowstats + q2-pack (both read q2). [0,1024) | [1024,2048)
__global__ __launch_bounds__(256)
void fused_q2post(const float* __restrict__ q2, const float* __restrict__ cbarsum,
                  float* __restrict__ trow, float* __restrict__ sigrow,
                  u16* __restrict__ q2h)
{
    const int b = blockIdx.x, tid = threadIdx.x;
    if (b < 1024) rowstats_dev(b, tid, q2, cbarsum, trow, sigrow);
    else          pack_rows_dev(b - 1024, tid, q2, q2h, nullptr, BATCH, 12);
}

// ---------------------------------------------------------------------------
// Fused dots GEMM v13 (best measured, 237-238us): 128x128, 4 waves, acc[4][4]
// = 64 AGPR, 32KB LDS 2-stage, (256,4) -> 16 waves/CU = register-file
// roofline. Counted-vmcnt pipeline: per step s:
//   wait vmcnt(4) -> barrier A -> 4 ds_read A + 3x(ds_read B + 4 MFMA) + B3
//   -> lgkmcnt(0) + barrier B -> ISSUE(s+2) into just-freed buffer -> 4 MFMA.
// ---------------------------------------------------------------------------
__global__ __launch_bounds__(256, 4)
void mfma_dots(const u16* __restrict__ Ah, const u16* __restrict__ Bh,
               const float* __restrict__ trow, unsigned* __restrict__ candBuf,
               unsigned* __restrict__ counters)
{
    __shared__ u16 lds[2 * 8192];      // 2 stages x (A 4096 + B 4096) u16 = 32 KB

    const int tid  = threadIdx.x;
    const int lane = tid & 63;
    const int wave = tid >> 6;
    const int wm = wave >> 1, wn = wave & 1;
    const int lr = lane & 15;
    const int q  = lane >> 4;

    // XCD-affinity: xcd owns a 4-m-tile band; within XCD, m fastest then n.
    const int L   = blockIdx.x;
    const int xcd = L & 7;
    const int j   = L >> 3;                    // 0..1023
    const int m0  = (xcd * 4 + (j & 3)) * 128;
    const int n0  = (j >> 2) * 128;

    const int a  = wave >> 1;                  // 0: stage A (q2h), 1: stage B (cbh)
    const u16* src = a ? Bh : Ah;
    const int rb   = a ? n0 : m0;
    const size_t R = a ? (size_t)VOC : (size_t)BATCH;
    const int i0   = (wave & 1) * 4;

    // strength-reduced staging pointers: gpX walks ks=0..15 by const stride
    const size_t gstep = (size_t)4 * R * 8;    // u16 elems per ks-step
    const u16* gp0 = src + ((size_t)(((i0 + 0) >> 1)) * R + rb + ((i0 + 0) & 1) * 64 + lane) * 8;
    const u16* gp1 = src + ((size_t)(((i0 + 1) >> 1)) * R + rb + ((i0 + 1) & 1) * 64 + lane) * 8;
    const u16* gp2 = src + ((size_t)(((i0 + 2) >> 1)) * R + rb + ((i0 + 2) & 1) * 64 + lane) * 8;
    const u16* gp3 = src + ((size_t)(((i0 + 3) >> 1)) * R + rb + ((i0 + 3) & 1) * 64 + lane) * 8;
    const int loff0 = a * 4096 + (i0 + 0) * 512 + lane * 8;
    const int loff1 = a * 4096 + (i0 + 1) * 512 + lane * 8;
    const int loff2 = a * 4096 + (i0 + 2) * 512 + lane * 8;
    const int loff3 = a * 4096 + (i0 + 3) * 512 + lane * 8;

#define ISSUE(b)                                                              \
    {                                                                         \
        async16(gp0, &lds[(b) * 8192 + loff0]); gp0 += gstep;                 \
        async16(gp1, &lds[(b) * 8192 + loff1]); gp1 += gstep;                 \
        async16(gp2, &lds[(b) * 8192 + loff2]); gp2 += gstep;                 \
        async16(gp3, &lds[(b) * 8192 + loff3]); gp3 += gstep;                 \
    }

    f32x4 acc[4][4] = {};

    // prologue: tiles 0 and 1 in flight (8 loads/thread); ptrs now at ks=2
    ISSUE(0)
    ISSUE(1)

    for (int s = 0; s < 16; s++) {
        if (s < 15) __builtin_amdgcn_s_waitcnt(0x0F74);   // vmcnt(4): stage s landed
        else        __builtin_amdgcn_s_waitcnt(0x0F70);   // vmcnt(0): last stage
        __builtin_amdgcn_s_barrier();                     // A: staging published
        const u16* base = &lds[(s & 1) * 8192];

        bf16x8 ah[4];
#pragma unroll
        for (int mt = 0; mt < 4; mt++)
            ah[mt] = *(const bf16x8*)&base[q * 1024 + (wm * 64 + mt * 16 + lr) * 8];

        __builtin_amdgcn_s_setprio(1);
#pragma unroll
        for (int nt = 0; nt < 3; nt++) {
            bf16x8 bh = *(const bf16x8*)&base[4096 + q * 1024 + (wn * 64 + nt * 16 + lr) * 8];
#pragma unroll
            for (int mt = 0; mt < 4; mt++)
                acc[mt][nt] = __builtin_amdgcn_mfma_f32_16x16x32_bf16(ah[mt], bh, acc[mt][nt], 0, 0, 0);
        }
        bf16x8 bh3 = *(const bf16x8*)&base[4096 + q * 1024 + (wn * 64 + 3 * 16 + lr) * 8];
        __builtin_amdgcn_s_setprio(0);

        __builtin_amdgcn_s_waitcnt(0xC07F);    // lgkmcnt(0): this wave's 8 reads done
        __builtin_amdgcn_s_barrier();          // B: ALL waves done reading buf[s&1]
        __builtin_amdgcn_sched_barrier(0);
        if (s < 14) ISSUE(s & 1)               // stage s+2 into just-freed buffer

        __builtin_amdgcn_s_setprio(1);
#pragma unroll
        for (int mt = 0; mt < 4; mt++)
            acc[mt][3] = __builtin_amdgcn_mfma_f32_16x16x32_bf16(ah[mt], bh3, acc[mt][3], 0, 0, 0);
        __builtin_amdgcn_s_setprio(0);
    }
#undef ISSUE

    // epilogue: threshold-append candidates
#pragma unroll
    for (int mt = 0; mt < 4; mt++) {
#pragma unroll
        for (int r = 0; r < 4; r++) {
            int rowg = m0 + wm * 64 + mt * 16 + q * 4 + r;
            float tr = trow[rowg];
#pragma unroll
            for (int nt = 0; nt < 4; nt++) {
                float val = acc[mt][nt][r];
                if (val >= tr) {
                    unsigned slot = atomicAdd(&counters[rowg], 1u);
                    if (slot < CAND_CAP) {
                        unsigned s16 = enc16(f2bf(val));
                        candBuf[(size_t)rowg * CAND_CAP + slot] =
                            (s16 << 16) | (unsigned)(n0 + wn * 64 + nt * 16 + lr);
                    }
                }
            }
        }
    }
}

// ---------------------------------------------------------------------------
// out = A @ W + bias in bf16 hi/lo 3-pass MFMA (error ~1e-6). Regrid (r8,
// bit-identical): tile 128m x 64n, grid 256 blocks, acc[4][2]=32 AGPR,
// LDS 48 KB -> 3 blocks/CU. Used for q2 = x@Wqk + bqk and out = y@Wv + bv.
// ---------------------------------------------------------------------------
__global__ __launch_bounds__(256, 3)
void mfma_out(const u16* __restrict__ Ah, const u16* __restrict__ Al,
              const u16* __restrict__ Bh, const u16* __restrict__ Bl,
              const float* __restrict__ bias, float* __restrict__ Cout, int Ma)
{
    __shared__ u16 lds[2 * 12288];   // 2 stages x 24 KB

    const int tid  = threadIdx.x;
    const int lane = tid & 63;
    const int wave = tid >> 6;
    const int wm = wave >> 1, wn = wave & 1;
    const int m0 = blockIdx.y * 128, n0 = blockIdx.x * 64;
    const int lr = lane & 15;
    const int q  = lane >> 4;
    const size_t R = (size_t)Ma;

    f32x4 acc[4][2] = {};

#define VISSUE(ks, b)                                                          \
    {                                                                          \
        _Pragma("unroll")                                                      \
        for (int i_ = 0; i_ < 2; i_++) {                                       \
            int u_ = tid + i_ * 256;                                           \
            size_t ai_ = ((size_t)((ks) * 4 + (u_ >> 7)) * R + m0 + (u_ & 127)) * 8; \
            async16(Ah + ai_, &lds[(b) * 12288 + u_ * 8]);                     \
            async16(Al + ai_, &lds[(b) * 12288 + 6144 + u_ * 8]);              \
        }                                                                      \
        {                                                                      \
            int u_ = tid;                                                      \
            size_t bi_ = ((size_t)((ks) * 4 + (u_ >> 6)) * DIM + n0 + (u_ & 63)) * 8; \
            async16(Bh + bi_, &lds[(b) * 12288 + 4096 + u_ * 8]);              \
            async16(Bl + bi_, &lds[(b) * 12288 + 10240 + u_ * 8]);             \
        }                                                                      \
    }

    VISSUE(0, 0)

    for (int ks = 0; ks < 16; ks++) {
        __syncthreads();                       // drains vmcnt(0): stage ks in LDS
        if (ks < 15) VISSUE(ks + 1, (ks + 1) & 1)
        const u16* base = &lds[(ks & 1) * 12288];

        bf16x8 ah[4], al[4];
#pragma unroll
        for (int mt = 0; mt < 4; mt++) {
            int row = wm * 64 + mt * 16 + lr;
            ah[mt] = *(const bf16x8*)&base[q * 1024 + row * 8];
            al[mt] = *(const bf16x8*)&base[6144 + q * 1024 + row * 8];
        }
#pragma unroll
        for (int nt = 0; nt < 2; nt++) {
            int col = wn * 32 + nt * 16 + lr;
            bf16x8 bh = *(const bf16x8*)&base[4096 + q * 512 + col * 8];
            bf16x8 bl = *(const bf16x8*)&base[10240 + q * 512 + col * 8];
#pragma unroll
            for (int mt = 0; mt < 4; mt++) {
                acc[mt][nt] = __builtin_amdgcn_mfma_f32_16x16x32_bf16(ah[mt], bh, acc[mt][nt], 0, 0, 0);
                acc[mt][nt] = __builtin_amdgcn_mfma_f32_16x16x32_bf16(ah[mt], bl, acc[mt][nt], 0, 0, 0);
                acc[mt][nt] = __builtin_amdgcn_mfma_f32_16x16x32_bf16(al[mt], bh, acc[mt][nt], 0, 0, 0);
            }
        }
    }
#undef VISSUE

#pragma unroll
    for (int mt = 0; mt < 4; mt++)
#pragma unroll
        for (int nt = 0; nt < 2; nt++) {
            int col = n0 + wn * 32 + nt * 16 + lr;
            float bb = bias[col];
#pragma unroll
            for (int r = 0; r < 4; r++) {
                int rowg = m0 + wm * 64 + mt * 16 + q * 4 + r;
                Cout[(size_t)rowg * DIM + col] = acc[mt][nt][r] + bb;
            }
        }
}

// ---------------------------------------------------------------------------
// Select v9 = r7's select6 (11.3KB LDS, wave-capped 8 blocks/CU) + ONLY the
// y-pack fusion (+2KB yrow -> 13.3KB, still wave-capped: zero occupancy cost)
// deleting the pack_rows(y) launch + 16MB traffic. Fallback rows exit early
// (flags) and are packed by fallback_row's own tail. y global store dropped
// (no consumer). r10 lesson: the FULL merge (inline fallback, keys[1024])
// pushed LDS to 22.5KB -> 7 blocks/CU -> +23us on this latency-bound kernel.
// ---------------------------------------------------------------------------
__global__ __launch_bounds__(256)
void select6(const unsigned* __restrict__ candBuf, const unsigned* __restrict__ counters,
             const float* __restrict__ trow, const float* __restrict__ q2,
             const float* __restrict__ codebook, unsigned* __restrict__ flags,
             u16* __restrict__ yh, u16* __restrict__ yl)
{
    __shared__ unsigned recs[CAND_CAP];
    __shared__ unsigned list[RES_CAP];
    __shared__ unsigned hist[256];
    __shared__ unsigned long long keys[RES_CAP];
    __shared__ float q2s[DIM];
    __shared__ float wArr[RES_CAP];
    __shared__ float yrow[DIM];
    __shared__ float redf[256];
    __shared__ unsigned redu[256];
    __shared__ unsigned s_R;
    __shared__ unsigned s_b1, s_rem, s_thr;

    const int tid  = threadIdx.x;
    const int lane = tid & 63;
    const int wave = tid >> 6;
    const int row  = blockIdx.x;

    const unsigned cnt = counters[row];
    if (cnt < TOPK || cnt > CAND_CAP) {
        if (tid == 0) flags[row] = 1u;
        return;
    }
    for (int i = tid; i < DIM; i += 256) q2s[i] = q2[(size_t)row * DIM + i];
    for (int i = tid; i < CAND_CAP; i += 256)
        recs[i] = (i < (int)cnt) ? candBuf[(size_t)row * CAND_CAP + i] : 0u;
    if (tid == 0) s_R = 0;
    hist[tid] = 0;
    __syncthreads();

    // pass 1: histogram of top byte of s16 (monotone: larger s16 = larger val)
#pragma unroll
    for (int e = 0; e < 2; e++) {
        int i = tid + e * 256;
        if (i < (int)cnt) atomicAdd(&hist[recs[i] >> 24], 1u);
    }
    __syncthreads();
    if (tid == 0) {
        unsigned c = 0; int b = 255;
        for (; b > 0; b--) {
            unsigned h = hist[b];
            if (c + h >= TOPK) break;
            c += h;
        }
        s_b1 = (unsigned)b; s_rem = TOPK - c;
    }
    __syncthreads();
    const unsigned b1 = s_b1, rem = s_rem;
    hist[tid] = 0;
    __syncthreads();

    // pass 2: low byte among records with top byte == b1
#pragma unroll
    for (int e = 0; e < 2; e++) {
        int i = tid + e * 256;
        if (i < (int)cnt && (recs[i] >> 24) == b1)
            atomicAdd(&hist[(recs[i] >> 16) & 0xFFu], 1u);
    }
    __syncthreads();
    if (tid == 0) {
        unsigned c = 0; int b = 255;
        for (; b > 0; b--) {
            unsigned h = hist[b];
            if (c + h >= rem) break;
            c += h;
        }
        s_thr = (b1 << 8) | (unsigned)b;       // s16 of 64th-largest record
    }
    __syncthreads();

    const float a64  = dec16(s_thr);
    const float band = a64 - 2.f * EPS_SEL;
    if (trow[row] > band) {
        if (tid == 0) flags[row] = 1u;
        return;
    }

    // band-compaction (unordered; exact sort later restores determinism)
#pragma unroll
    for (int e = 0; e < 2; e++) {
        int i = tid + e * 256;
        if (i < (int)cnt && dec16(recs[i] >> 16) >= band) {
            unsigned p = atomicAdd(&s_R, 1u);
            if (p < RES_CAP) list[p] = recs[i];
        }
    }
    __syncthreads();
    const int R = (int)s_R;
    if (R > RES_CAP) {
        if (tid == 0) flags[row] = 1u;
        return;
    }

    // fp64 rescue: wave per candidate, coalesced codebook reads
    for (int c = wave; c < R; c += 4) {
        unsigned idx = list[c] & 0xFFFFu;
        const float* cb = codebook + (size_t)idx * DIM + lane * 8;
        float4 c0 = *(const float4*)cb, c1 = *(const float4*)(cb + 4);
        const float* qp = &q2s[lane * 8];
        float4 a0 = *(const float4*)qp, a1 = *(const float4*)(qp + 4);
        double s = (double)a0.x * c0.x + (double)a0.y * c0.y
                 + (double)a0.z * c0.z + (double)a0.w * c0.w
                 + (double)a1.x * c1.x + (double)a1.y * c1.y
                 + (double)a1.z * c1.z + (double)a1.w * c1.w;
#pragma unroll
        for (int off = 32; off > 0; off >>= 1) s += __shfl_down(s, off);
        if (lane == 0) {
            float val = (float)s;
            unsigned b = __float_as_uint(val);
            unsigned sk = (b & 0x80000000u) ? ~b : (b | 0x80000000u);
            keys[c] = ((unsigned long long)(~sk) << 32) | idx;
        }
    }
    if (tid >= R && tid < RES_CAP) keys[tid] = ~0ULL;
    __syncthreads();

    // bitonic sort 256 u64 ascending (= descending by exact value)
    for (int k = 2; k <= RES_CAP; k <<= 1) {
        for (int j = k >> 1; j > 0; j >>= 1) {
            int ixj = tid ^ j;
            if (ixj > tid) {
                unsigned long long a = keys[tid], b2 = keys[ixj];
                if (((tid & k) == 0) ? (a > b2) : (a < b2)) { keys[tid] = b2; keys[ixj] = a; }
            }
            __syncthreads();
        }
    }

    const unsigned threshInv = (unsigned)(keys[TOPK - 1] >> 32);
    unsigned sk0 = ~(unsigned)(keys[0] >> 32);
    const float vmax = __uint_as_float((sk0 & 0x80000000u) ? (sk0 & 0x7FFFFFFFu) : ~sk0);

    unsigned hi = (unsigned)(keys[tid] >> 32);
    bool sel = (hi <= threshInv);
    unsigned sk = ~hi;
    float val = __uint_as_float((sk & 0x80000000u) ? (sk & 0x7FFFFFFFu) : ~sk);
    float w = sel ? expf(val - vmax) : 0.f;
    wArr[tid] = w;
    redf[tid] = w;
    redu[tid] = sel ? 1u : 0u;
    __syncthreads();
    for (int s = 128; s > 0; s >>= 1) {
        if (tid < s) { redf[tid] += redf[tid + s]; redu[tid] += redu[tid + s]; }
        __syncthreads();
    }
    const float invZ = 1.0f / redf[0];
    const int selCount = (int)redu[0];

    // y_row = sum_i w_i * codebook[idx_i, :] -> LDS -> fused hi/lo pack
    for (int d = tid; d < DIM; d += 256) {
        float acc = 0.f;
        for (int i = 0; i < selCount; i++) {
            unsigned idx = (unsigned)(keys[i] & 0xFFFFFFFFu);
            acc += wArr[i] * codebook[(size_t)idx * DIM + d];
        }
        yrow[d] = acc * invZ;
    }
    __syncthreads();
    pack_y_tail(tid, row, yrow, yh, yl);
}

// ---------------------------------------------------------------------------
// Exact fallback for flagged rows (expected: ~none). fp64 scan over all VOC.
// Now also packs its y_row into yh/yl (same tail as select6).
// ---------------------------------------------------------------------------
__global__ __launch_bounds__(256)
void fallback_row(const unsigned* __restrict__ flags, const float* __restrict__ q2,
                  const float* __restrict__ codebook, const float* __restrict__ trow,
                  const float* __restrict__ sigrow, u16* __restrict__ yh,
                  u16* __restrict__ yl)
{
    const int row = blockIdx.x;
    if (!flags[row]) return;

    __shared__ float q2s[DIM];
    __shared__ unsigned long long keys[FCAP];
    __shared__ float wArr[FCAP];
    __shared__ float yrow[DIM];
    __shared__ float redf[256];
    __shared__ unsigned redu[256];
    __shared__ unsigned s_cnt;

    const int tid = threadIdx.x;
    for (int i = tid; i < DIM; i += 256) q2s[i] = q2[(size_t)row * DIM + i];
    const float sig = sigrow[row];
    float tf = trow[row] - 0.35f * sig;
    unsigned cnt = 0;

    for (int it = 0; it < 16; it++) {
        if (tid == 0) s_cnt = 0;
        __syncthreads();
        for (int i = tid; i < VOC; i += 256) {
            const float* cb = codebook + (size_t)i * DIM;
            double s = 0.0;
            for (int d = 0; d < DIM; d += 4) {
                float4 c4 = *(const float4*)(cb + d);
                s += (double)q2s[d + 0] * (double)c4.x + (double)q2s[d + 1] * (double)c4.y
                   + (double)q2s[d + 2] * (double)c4.z + (double)q2s[d + 3] * (double)c4.w;
            }
            float vv = (float)s;
            if (vv >= tf) {
                unsigned p = atomicAdd(&s_cnt, 1u);
                if (p < FCAP) {
                    unsigned b = __float_as_uint(vv);
                    unsigned sk = (b & 0x80000000u) ? ~b : (b | 0x80000000u);
                    keys[p] = ((unsigned long long)(~sk) << 32) | (unsigned)i;
                }
            }
        }
        __syncthreads();
        cnt = s_cnt;
        if (cnt > FCAP) { tf += 0.15f * sig; continue; }
        if (cnt < TOPK) { tf -= 0.35f * sig; continue; }
        break;
    }
    if (cnt > FCAP) cnt = FCAP;
    for (int i = tid; i < FCAP; i += 256)
        if (i >= (int)cnt) keys[i] = ~0ULL;
    __syncthreads();

    for (int k = 2; k <= FCAP; k <<= 1) {
        for (int j = k >> 1; j > 0; j >>= 1) {
#pragma unroll
            for (int e = 0; e < 4; e++) {
                int i = tid + e * 256;
                int ixj = i ^ j;
                if (ixj > i) {
                    unsigned long long a = keys[i], b = keys[ixj];
                    if (((i & k) == 0) ? (a > b) : (a < b)) { keys[i] = b; keys[ixj] = a; }
                }
            }
            __syncthreads();
        }
    }

    const unsigned threshInv = (unsigned)(keys[TOPK - 1] >> 32);
    unsigned sk0 = ~(unsigned)(keys[0] >> 32);
    const float vmax = __uint_as_float((sk0 & 0x80000000u) ? (sk0 & 0x7FFFFFFFu) : ~sk0);

    float lsum = 0.f; unsigned lcnt = 0;
    for (int i = tid; i < FCAP; i += 256) {
        unsigned hi = (unsigned)(keys[i] >> 32);
        bool sel = (hi <= threshInv);
        unsigned sk = ~hi;
        float vv = __uint_as_float((sk & 0x80000000u) ? (sk & 0x7FFFFFFFu) : ~sk);
        float w = sel ? expf(vv - vmax) : 0.f;
        wArr[i] = w;
        lsum += w; lcnt += sel ? 1u : 0u;
    }
    redf[tid] = lsum; redu[tid] = lcnt;
    __syncthreads();
    for (int s = 128; s > 0; s >>= 1) {
        if (tid < s) { redf[tid] += redf[tid + s]; redu[tid] += redu[tid + s]; }
        __syncthreads();
    }
    const float invZ = 1.f / redf[0];
    const int selCount = (int)redu[0];

    for (int d = tid; d < DIM; d += 256) {
        float acc = 0.f;
        for (int i = 0; i < selCount; i++) {
            unsigned idx = (unsigned)(keys[i] & 0xFFFFFFFFu);
            acc += wArr[i] * codebook[(size_t)idx * DIM + d];
        }
        yrow[d] = acc * invZ;
    }
    __syncthreads();
    pack_y_tail(tid, row, yrow, yh, yl);
}

// ---------------------------------------------------------------------------
extern "C" void kernel_launch(void* const* d_in, const int* in_sizes, int n_in,
                              void* d_out, int out_size, void* d_ws, size_t ws_size,
                              hipStream_t stream)
{
    const float* x        = (const float*)d_in[0];
    const float* codebook = (const float*)d_in[1];
    const float* Wq       = (const float*)d_in[2];
    const float* bq       = (const float*)d_in[3];
    const float* Wk       = (const float*)d_in[4];
    // d_in[5] = bk: per-row-constant shift in dots (top-k & softmax invariant)
    const float* Wv       = (const float*)d_in[6];
    const float* bv       = (const float*)d_in[7];
    float* out = (float*)d_out;

    // workspace (~72 MB; y slot retained in layout but no longer written)
    float* q2   = (float*)d_ws;                       // 4096x512   (8 MB)
    float* Wqk  = q2   + (size_t)BATCH * DIM;         // 512x512    (1 MB)
    float* bqk  = Wqk  + (size_t)DIM * DIM;           // 512 (pad 1024)
    float* y    = bqk  + 1024;                        // 4096x512   (8 MB, unused)
    float* trow = y    + (size_t)BATCH * DIM;         // 4096
    float* sigr = trow + BATCH;                       // 4096
    unsigned* counters = (unsigned*)(sigr + BATCH);   // 4096
    unsigned* flags    = counters + BATCH;            // 4096
    float* cbarsum     = (float*)(flags + BATCH);     // 512
    unsigned* candBuf  = (unsigned*)(cbarsum + 512);  // 4096x512 (8 MB)
    u16* q2h = (u16*)(candBuf + (size_t)BATCH * CAND_CAP);   // 4 MB
    u16* cbh = q2h + (size_t)BATCH * DIM;                    // 32 MB
    u16* yh  = cbh + (size_t)VOC * DIM;                      // 4 MB
    u16* yl  = yh  + (size_t)BATCH * DIM;                    // 4 MB
    u16* wvh = yl  + (size_t)BATCH * DIM;                    // 0.5 MB
    u16* wvl = wvh + (size_t)DIM * DIM;                      // 0.5 MB

    // aliases (no workspace growth):
    //  - x hi/lo pack lives in yh/yl (dead after mfma_out(q2); rewritten by
    //    select6/fallback_row before mfma_out(out))
    //  - Wqk hi/lo pack lives in candBuf (candBuf not needed until mfma_dots)
    u16* xh   = yh;
    u16* xl   = yl;
    u16* wqkh = (u16*)candBuf;
    u16* wqkl = wqkh + (size_t)DIM * DIM;

    dim3 blk(256);

    // zero counters+flags+cbarsum first (cbar_accum in fused_prep needs it)
    zero_ws<<<dim3(34), blk, 0, stream>>>(counters, BATCH * 2 + 512);

    // Wqk = Wq @ Wk^T (fp64-flush fold, precision anchor)
    gemm64<true, true><<<dim3(DIM / 64, DIM / 64), blk, 0, stream>>>(
        Wq, Wk, nullptr, Wqk, DIM, DIM, DIM);

    // all independent prep in ONE launch: x-pack | Wqk-pack | cb-pack |
    // Wv-pack | cbar_accum | bias_fold
    fused_prep<<<dim3(9856), blk, 0, stream>>>(
        x, Wqk, codebook, Wv, bq, Wk,
        xh, xl, wqkh, wqkl, cbh, wvh, wvl, cbarsum, bqk);

    // q2 = x @ Wqk + bqk via hi/lo 3-pass MFMA (256 blocks)
    mfma_out<<<dim3(DIM / 64, BATCH / 128), blk, 0, stream>>>(
        xh, xl, wqkh, wqkl, bqk, q2, BATCH);

    // rowstats + q2-pack in one launch
    fused_q2post<<<dim3(2048), blk, 0, stream>>>(q2, cbarsum, trow, sigr, q2h);

    // fused dots GEMM (v13: 2-stage counted-vmcnt pipeline) + candidate append
    mfma_dots<<<dim3(8192), blk, 0, stream>>>(q2h, cbh, trow, candBuf, counters);

    // selection + softmax + y_row (+ fused hi/lo pack directly to yh/yl)
    select6<<<dim3(BATCH), blk, 0, stream>>>(
        candBuf, counters, trow, q2, codebook, flags, yh, yl);
    fallback_row<<<dim3(BATCH), blk, 0, stream>>>(
        flags, q2, codebook, trow, sigr, yh, yl);

    // out = y @ Wv + bv  (hi/lo 3-pass MFMA, 256 blocks)
    mfma_out<<<dim3(DIM / 64, BATCH / 128), blk, 0, stream>>>(
        yh, yl, wvh, wvl, bv, out, BATCH);
}

// Round 12
// 641.964 us; speedup vs baseline: 1.0393x; 1.0186x over previous
//
#include <hip/hip_runtime.h>
#include <cstdint>

#define VOC   32768
#define DIM   512
#define TOPK  64
#define BATCH 4096

#define KSIG     2.45f
#define EPS_SEL  0.012f
#define CAND_CAP 512
#define RES_CAP  256
#define FCAP     1024

typedef unsigned short u16;
typedef __attribute__((ext_vector_type(8))) short bf16x8;
typedef __attribute__((ext_vector_type(4))) float f32x4;

// ---- bf16 helpers (RNE) ----------------------------------------------------
__device__ __forceinline__ u16 f2bf(float f) {
    unsigned u = __float_as_uint(f);
    unsigned r = (u + 0x7FFFu + ((u >> 16) & 1u)) >> 16;
    return (u16)r;
}
__device__ __forceinline__ float bf2f(u16 h) {
    return __uint_as_float(((unsigned)h) << 16);
}
__device__ __forceinline__ unsigned enc16(u16 h) {
    return (h & 0x8000u) ? (unsigned)((u16)~h) : (unsigned)(h | 0x8000u);
}
__device__ __forceinline__ float dec16(unsigned s16) {
    u16 h = (s16 & 0x8000u) ? (u16)(s16 ^ 0x8000u) : (u16)(~s16);
    return bf2f(h);
}

// ---- async global->LDS 16B -------------------------------------------------
__device__ __forceinline__ void async16(const void* g, void* l) {
    __builtin_amdgcn_global_load_lds(
        (const __attribute__((address_space(1))) void*)g,
        (__attribute__((address_space(3))) void*)l, 16, 0, 0);
}

// ---------------------------------------------------------------------------
// fp32 64x64-tile GEMM + optional per-k-tile fp64 flush. 256 thr, 4x4 micro.
// Retained ONLY for the precision-critical fold Wqk = Wq @ Wk^T. Prologue
// also zeroes the counters/flags/cbarsum words (fold of the old zero_ws
// launch: 64 blocks x 256 thr >= 8704 words; disjoint memory, stream-ordered
// before all consumers).
// ---------------------------------------------------------------------------
template <bool BT, bool F64ACC>
__global__ __launch_bounds__(256)
void gemm64(const float* __restrict__ A, const float* __restrict__ B,
            const float* __restrict__ bias, float* __restrict__ C,
            int M, int N, int K, unsigned* __restrict__ zeroP, int zeroN)
{
    const int KS = 16;
    __shared__ float As[KS][68];
    __shared__ float Bs[KS][64];

    const int tid = threadIdx.x;
    if (zeroP) {
        int zi = (blockIdx.y * gridDim.x + blockIdx.x) * 256 + tid;
        if (zi < zeroN) zeroP[zi] = 0u;
    }

    const int m0 = blockIdx.y * 64;
    const int n0 = blockIdx.x * 64;
    const int ty = tid >> 4;
    const int tx = tid & 15;

    float acc[4][4];
    double acc64[4][4];
#pragma unroll
    for (int i = 0; i < 4; i++)
#pragma unroll
        for (int j = 0; j < 4; j++) { acc[i][j] = 0.f; if (F64ACC) acc64[i][j] = 0.0; }

    for (int kt = 0; kt < K; kt += KS) {
        {
            int row = tid >> 2, kq = tid & 3;
            const float4 av = *(const float4*)(A + (size_t)(m0 + row) * K + kt + kq * 4);
            As[kq * 4 + 0][row] = av.x;
            As[kq * 4 + 1][row] = av.y;
            As[kq * 4 + 2][row] = av.z;
            As[kq * 4 + 3][row] = av.w;
        }
        if (!BT) {
            int krow = tid >> 4, nq = tid & 15;
            *(float4*)&Bs[krow][nq * 4] =
                *(const float4*)(B + (size_t)(kt + krow) * N + n0 + nq * 4);
        } else {
            int nrow = tid >> 2, kq = tid & 3;
            const float4 bv = *(const float4*)(B + (size_t)(n0 + nrow) * K + kt + kq * 4);
            Bs[kq * 4 + 0][nrow] = bv.x;
            Bs[kq * 4 + 1][nrow] = bv.y;
            Bs[kq * 4 + 2][nrow] = bv.z;
            Bs[kq * 4 + 3][nrow] = bv.w;
        }
        __syncthreads();

#pragma unroll
        for (int kk = 0; kk < KS; kk++) {
            float4 a = *(const float4*)&As[kk][ty * 4];
            float4 b = *(const float4*)&Bs[kk][tx * 4];
            float av[4] = {a.x, a.y, a.z, a.w};
            float bv[4] = {b.x, b.y, b.z, b.w};
#pragma unroll
            for (int i = 0; i < 4; i++)
#pragma unroll
                for (int j = 0; j < 4; j++)
                    acc[i][j] += av[i] * bv[j];
        }
        __syncthreads();
        if (F64ACC) {
#pragma unroll
            for (int i = 0; i < 4; i++)
#pragma unroll
                for (int j = 0; j < 4; j++) { acc64[i][j] += (double)acc[i][j]; acc[i][j] = 0.f; }
        }
    }

    float4 bb = make_float4(0.f, 0.f, 0.f, 0.f);
    if (bias) bb = *(const float4*)(bias + n0 + tx * 4);
#pragma unroll
    for (int i = 0; i < 4; i++) {
        float4 o;
        o.x = (F64ACC ? (float)acc64[i][0] : acc[i][0]) + bb.x;
        o.y = (F64ACC ? (float)acc64[i][1] : acc[i][1]) + bb.y;
        o.z = (F64ACC ? (float)acc64[i][2] : acc[i][2]) + bb.z;
        o.w = (F64ACC ? (float)acc64[i][3] : acc[i][3]) + bb.w;
        *(float4*)(C + (size_t)(m0 + ty * 4 + i) * N + n0 + tx * 4) = o;
    }
}

// ---------------------------------------------------------------------------
// Device bodies for the fused prep kernels (virtual block id passed in).
// ---------------------------------------------------------------------------
__device__ __forceinline__ void pack_rows_dev(int bid, int tid,
        const float* __restrict__ src, u16* __restrict__ hi,
        u16* __restrict__ lo, int R, int log2R)
{
    int idx = bid * 256 + tid;
    int c8  = idx >> log2R;
    int row = idx & (R - 1);
    const float* sp = src + (size_t)row * DIM + c8 * 8;
    float xv[8];
    *(float4*)&xv[0] = *(const float4*)sp;
    *(float4*)&xv[4] = *(const float4*)(sp + 4);
    int ks = c8 >> 2, ch = c8 & 3;
    size_t ob = ((size_t)(ks * 4 + ch) * R + row) * 8;
    u16 h[8], l[8];
#pragma unroll
    for (int j = 0; j < 8; j++) {
        h[j] = f2bf(xv[j]);
        l[j] = f2bf(xv[j] - bf2f(h[j]));
    }
    *(uint4*)(hi + ob) = *(const uint4*)h;
    if (lo) *(uint4*)(lo + ob) = *(const uint4*)l;
}

__device__ __forceinline__ void pack_bT_dev(int bid, int tid,
        const float* __restrict__ W, u16* __restrict__ hi, u16* __restrict__ lo)
{
    int idx = bid * 256 + tid;
    int n  = idx & (DIM - 1);
    int c8 = idx >> 9;
    int ks = c8 >> 2, ch = c8 & 3;
    size_t ob = ((size_t)(ks * 4 + ch) * DIM + n) * 8;
    u16 h[8], l[8];
#pragma unroll
    for (int j = 0; j < 8; j++) {
        float x = W[(size_t)(c8 * 8 + j) * DIM + n];
        h[j] = f2bf(x);
        l[j] = f2bf(x - bf2f(h[j]));
    }
    *(uint4*)(hi + ob) = *(const uint4*)h;
    *(uint4*)(lo + ob) = *(const uint4*)l;
}

__device__ __forceinline__ void cbar_dev(int bid, int tid,
        const float* __restrict__ cb, float* __restrict__ cbarsum)
{
    const int r0 = bid * 128;
    float s0 = 0.f, s1 = 0.f;
    for (int r = 0; r < 128; r++) {
        const float* rp = cb + (size_t)(r0 + r) * DIM;
        s0 += rp[tid];
        s1 += rp[tid + 256];
    }
    atomicAdd(&cbarsum[tid], s0);
    atomicAdd(&cbarsum[tid + 256], s1);
}

__device__ __forceinline__ void bias_fold_dev(int bid, int tid,
        const float* __restrict__ bq, const float* __restrict__ Wk,
        float* __restrict__ bqk)
{
    const int lane = tid & 63, wave = tid >> 6;
    const int j = bid * 4 + wave;
    const float* wr = Wk + (size_t)j * DIM + lane * 8;
    const float* bp = bq + lane * 8;
    double s = 0.0;
#pragma unroll
    for (int t = 0; t < 8; t++) s += (double)bp[t] * (double)wr[t];
#pragma unroll
    for (int off = 32; off > 0; off >>= 1) s += __shfl_down(s, off);
    if (lane == 0) bqk[j] = (float)s;
}

__device__ __forceinline__ void rowstats_dev(int bid, int tid,
        const float* __restrict__ q2, const float* __restrict__ cbarsum,
        float* __restrict__ trow, float* __restrict__ sigrow)
{
    const int lane = tid & 63, wave = tid >> 6;
    const int row = bid * 4 + wave;
    const float* qp = q2 + (size_t)row * DIM + lane * 8;
    float4 a0 = *(const float4*)qp, a1 = *(const float4*)(qp + 4);
    const float* cp = cbarsum + lane * 8;
    float4 c0 = *(const float4*)cp, c1 = *(const float4*)(cp + 4);
    float mu = a0.x*c0.x + a0.y*c0.y + a0.z*c0.z + a0.w*c0.w
             + a1.x*c1.x + a1.y*c1.y + a1.z*c1.z + a1.w*c1.w;
    float nr = a0.x*a0.x + a0.y*a0.y + a0.z*a0.z + a0.w*a0.w
             + a1.x*a1.x + a1.y*a1.y + a1.z*a1.z + a1.w*a1.w;
#pragma unroll
    for (int off = 32; off > 0; off >>= 1) {
        mu += __shfl_down(mu, off);
        nr += __shfl_down(nr, off);
    }
    if (lane == 0) {
        mu *= (1.f / VOC);
        float sig = sqrtf(nr * (1.f / 1536.f));
        trow[row] = mu + KSIG * sig;
        sigrow[row] = sig;
    }
}

// ---------------------------------------------------------------------------
// fused_prep: all pre-dots prep that only depends on {inputs, Wqk, zeroed ws}.
// Block ranges: [0,1024) x-pack hi/lo | [1024,1152) Wqk-bT | [1152,9344)
// cb-pack | [9344,9472) Wv-bT | [9472,9728) cbar_accum | [9728,9856) bias_fold
// ---------------------------------------------------------------------------
__global__ __launch_bounds__(256)
void fused_prep(const float* __restrict__ x, const float* __restrict__ Wqk,
                const float* __restrict__ codebook, const float* __restrict__ Wv,
                const float* __restrict__ bq, const float* __restrict__ Wk,
                u16* __restrict__ xh, u16* __restrict__ xl,
                u16* __restrict__ wqkh, u16* __restrict__ wqkl,
                u16* __restrict__ cbh, u16* __restrict__ wvh,
                u16* __restrict__ wvl, float* __restrict__ cbarsum,
                float* __restrict__ bqk)
{
    const int b = blockIdx.x, tid = threadIdx.x;
    if (b < 1024)       pack_rows_dev(b, tid, x, xh, xl, BATCH, 12);
    else if (b < 1152)  pack_bT_dev(b - 1024, tid, Wqk, wqkh, wqkl);
    else if (b < 9344)  pack_rows_dev(b - 1152, tid, codebook, cbh, nullptr, VOC, 15);
    else if (b < 9472)  pack_bT_dev(b - 9344, tid, Wv, wvh, wvl);
    else if (b < 9728)  cbar_dev(b - 9472, tid, codebook, cbarsum);
    else                bias_fold_dev(b - 9728, tid, bq, Wk, bqk);
}

// fused_q2post: rowstats + q2-pack (both read q2). [0,1024) | [1024,2048)
__global__ __launch_bounds__(256)
void fused_q2post(const float* __restrict__ q2, const float* __restrict__ cbarsum,
                  float* __restrict__ trow, float* __restrict__ sigrow,
                  u16* __restrict__ q2h)
{
    const int b = blockIdx.x, tid = threadIdx.x;
    if (b < 1024) rowstats_dev(b, tid, q2, cbarsum, trow, sigrow);
    else          pack_rows_dev(b - 1024, tid, q2, q2h, nullptr, BATCH, 12);
}

// standalone pack_rows: used for y AFTER select/fallback. Coalesced by
// construction (block per c8-range, consecutive rows) — r11 lesson: fusing
// this into select6 transposes the access to 64KB-strided 16B scatters
// (+15us). The separate pass IS the transpose.
__global__ __launch_bounds__(256)
void pack_rows(const float* __restrict__ src, u16* __restrict__ hi,
               u16* __restrict__ lo, int R, int log2R)
{
    pack_rows_dev(blockIdx.x, threadIdx.x, src, hi, lo, R, log2R);
}

// ---------------------------------------------------------------------------
// Fused dots GEMM v13 (best measured, 235-238us): 128x128, 4 waves, acc[4][4]
// = 64 AGPR, 32KB LDS 2-stage, (256,4) -> 16 waves/CU = register-file
// roofline. Counted-vmcnt pipeline: per step s:
//   wait vmcnt(4) -> barrier A -> 4 ds_read A + 3x(ds_read B + 4 MFMA) + B3
//   -> lgkmcnt(0) + barrier B -> ISSUE(s+2) into just-freed buffer -> 4 MFMA.
// ---------------------------------------------------------------------------
__global__ __launch_bounds__(256, 4)
void mfma_dots(const u16* __restrict__ Ah, const u16* __restrict__ Bh,
               const float* __restrict__ trow, unsigned* __restrict__ candBuf,
               unsigned* __restrict__ counters)
{
    __shared__ u16 lds[2 * 8192];      // 2 stages x (A 4096 + B 4096) u16 = 32 KB

    const int tid  = threadIdx.x;
    const int lane = tid & 63;
    const int wave = tid >> 6;
    const int wm = wave >> 1, wn = wave & 1;
    const int lr = lane & 15;
    const int q  = lane >> 4;

    // XCD-affinity: xcd owns a 4-m-tile band; within XCD, m fastest then n.
    const int L   = blockIdx.x;
    const int xcd = L & 7;
    const int j   = L >> 3;                    // 0..1023
    const int m0  = (xcd * 4 + (j & 3)) * 128;
    const int n0  = (j >> 2) * 128;

    const int a  = wave >> 1;                  // 0: stage A (q2h), 1: stage B (cbh)
    const u16* src = a ? Bh : Ah;
    const int rb   = a ? n0 : m0;
    const size_t R = a ? (size_t)VOC : (size_t)BATCH;
    const int i0   = (wave & 1) * 4;

    // strength-reduced staging pointers: gpX walks ks=0..15 by const stride
    const size_t gstep = (size_t)4 * R * 8;    // u16 elems per ks-step
    const u16* gp0 = src + ((size_t)(((i0 + 0) >> 1)) * R + rb + ((i0 + 0) & 1) * 64 + lane) * 8;
    const u16* gp1 = src + ((size_t)(((i0 + 1) >> 1)) * R + rb + ((i0 + 1) & 1) * 64 + lane) * 8;
    const u16* gp2 = src + ((size_t)(((i0 + 2) >> 1)) * R + rb + ((i0 + 2) & 1) * 64 + lane) * 8;
    const u16* gp3 = src + ((size_t)(((i0 + 3) >> 1)) * R + rb + ((i0 + 3) & 1) * 64 + lane) * 8;
    const int loff0 = a * 4096 + (i0 + 0) * 512 + lane * 8;
    const int loff1 = a * 4096 + (i0 + 1) * 512 + lane * 8;
    const int loff2 = a * 4096 + (i0 + 2) * 512 + lane * 8;
    const int loff3 = a * 4096 + (i0 + 3) * 512 + lane * 8;

#define ISSUE(b)                                                              \
    {                                                                         \
        async16(gp0, &lds[(b) * 8192 + loff0]); gp0 += gstep;                 \
        async16(gp1, &lds[(b) * 8192 + loff1]); gp1 += gstep;                 \
        async16(gp2, &lds[(b) * 8192 + loff2]); gp2 += gstep;                 \
        async16(gp3, &lds[(b) * 8192 + loff3]); gp3 += gstep;                 \
    }

    f32x4 acc[4][4] = {};

    // prologue: tiles 0 and 1 in flight (8 loads/thread); ptrs now at ks=2
    ISSUE(0)
    ISSUE(1)

    for (int s = 0; s < 16; s++) {
        if (s < 15) __builtin_amdgcn_s_waitcnt(0x0F74);   // vmcnt(4): stage s landed
        else        __builtin_amdgcn_s_waitcnt(0x0F70);   // vmcnt(0): last stage
        __builtin_amdgcn_s_barrier();                     // A: staging published
        const u16* base = &lds[(s & 1) * 8192];

        bf16x8 ah[4];
#pragma unroll
        for (int mt = 0; mt < 4; mt++)
            ah[mt] = *(const bf16x8*)&base[q * 1024 + (wm * 64 + mt * 16 + lr) * 8];

        __builtin_amdgcn_s_setprio(1);
#pragma unroll
        for (int nt = 0; nt < 3; nt++) {
            bf16x8 bh = *(const bf16x8*)&base[4096 + q * 1024 + (wn * 64 + nt * 16 + lr) * 8];
#pragma unroll
            for (int mt = 0; mt < 4; mt++)
                acc[mt][nt] = __builtin_amdgcn_mfma_f32_16x16x32_bf16(ah[mt], bh, acc[mt][nt], 0, 0, 0);
        }
        bf16x8 bh3 = *(const bf16x8*)&base[4096 + q * 1024 + (wn * 64 + 3 * 16 + lr) * 8];
        __builtin_amdgcn_s_setprio(0);

        __builtin_amdgcn_s_waitcnt(0xC07F);    // lgkmcnt(0): this wave's 8 reads done
        __builtin_amdgcn_s_barrier();          // B: ALL waves done reading buf[s&1]
        __builtin_amdgcn_sched_barrier(0);
        if (s < 14) ISSUE(s & 1)               // stage s+2 into just-freed buffer

        __builtin_amdgcn_s_setprio(1);
#pragma unroll
        for (int mt = 0; mt < 4; mt++)
            acc[mt][3] = __builtin_amdgcn_mfma_f32_16x16x32_bf16(ah[mt], bh3, acc[mt][3], 0, 0, 0);
        __builtin_amdgcn_s_setprio(0);
    }
#undef ISSUE

    // epilogue: threshold-append candidates
#pragma unroll
    for (int mt = 0; mt < 4; mt++) {
#pragma unroll
        for (int r = 0; r < 4; r++) {
            int rowg = m0 + wm * 64 + mt * 16 + q * 4 + r;
            float tr = trow[rowg];
#pragma unroll
            for (int nt = 0; nt < 4; nt++) {
                float val = acc[mt][nt][r];
                if (val >= tr) {
                    unsigned slot = atomicAdd(&counters[rowg], 1u);
                    if (slot < CAND_CAP) {
                        unsigned s16 = enc16(f2bf(val));
                        candBuf[(size_t)rowg * CAND_CAP + slot] =
                            (s16 << 16) | (unsigned)(n0 + wn * 64 + nt * 16 + lr);
                    }
                }
            }
        }
    }
}

// ---------------------------------------------------------------------------
// out = A @ W + bias in bf16 hi/lo 3-pass MFMA (error ~1e-6). Regrid (r8,
// bit-identical): tile 128m x 64n, grid 256 blocks, acc[4][2]=32 AGPR,
// LDS 48 KB -> 3 blocks/CU. Used for q2 = x@Wqk + bqk and out = y@Wv + bv.
// ---------------------------------------------------------------------------
__global__ __launch_bounds__(256, 3)
void mfma_out(const u16* __restrict__ Ah, const u16* __restrict__ Al,
              const u16* __restrict__ Bh, const u16* __restrict__ Bl,
              const float* __restrict__ bias, float* __restrict__ Cout, int Ma)
{
    __shared__ u16 lds[2 * 12288];   // 2 stages x 24 KB

    const int tid  = threadIdx.x;
    const int lane = tid & 63;
    const int wave = tid >> 6;
    const int wm = wave >> 1, wn = wave & 1;
    const int m0 = blockIdx.y * 128, n0 = blockIdx.x * 64;
    const int lr = lane & 15;
    const int q  = lane >> 4;
    const size_t R = (size_t)Ma;

    f32x4 acc[4][2] = {};

#define VISSUE(ks, b)                                                          \
    {                                                                          \
        _Pragma("unroll")                                                      \
        for (int i_ = 0; i_ < 2; i_++) {                                       \
            int u_ = tid + i_ * 256;                                           \
            size_t ai_ = ((size_t)((ks) * 4 + (u_ >> 7)) * R + m0 + (u_ & 127)) * 8; \
            async16(Ah + ai_, &lds[(b) * 12288 + u_ * 8]);                     \
            async16(Al + ai_, &lds[(b) * 12288 + 6144 + u_ * 8]);              \
        }                                                                      \
        {                                                                      \
            int u_ = tid;                                                      \
            size_t bi_ = ((size_t)((ks) * 4 + (u_ >> 6)) * DIM + n0 + (u_ & 63)) * 8; \
            async16(Bh + bi_, &lds[(b) * 12288 + 4096 + u_ * 8]);              \
            async16(Bl + bi_, &lds[(b) * 12288 + 10240 + u_ * 8]);             \
        }                                                                      \
    }

    VISSUE(0, 0)

    for (int ks = 0; ks < 16; ks++) {
        __syncthreads();                       // drains vmcnt(0): stage ks in LDS
        if (ks < 15) VISSUE(ks + 1, (ks + 1) & 1)
        const u16* base = &lds[(ks & 1) * 12288];

        bf16x8 ah[4], al[4];
#pragma unroll
        for (int mt = 0; mt < 4; mt++) {
            int row = wm * 64 + mt * 16 + lr;
            ah[mt] = *(const bf16x8*)&base[q * 1024 + row * 8];
            al[mt] = *(const bf16x8*)&base[6144 + q * 1024 + row * 8];
        }
#pragma unroll
        for (int nt = 0; nt < 2; nt++) {
            int col = wn * 32 + nt * 16 + lr;
            bf16x8 bh = *(const bf16x8*)&base[4096 + q * 512 + col * 8];
            bf16x8 bl = *(const bf16x8*)&base[10240 + q * 512 + col * 8];
#pragma unroll
            for (int mt = 0; mt < 4; mt++) {
                acc[mt][nt] = __builtin_amdgcn_mfma_f32_16x16x32_bf16(ah[mt], bh, acc[mt][nt], 0, 0, 0);
                acc[mt][nt] = __builtin_amdgcn_mfma_f32_16x16x32_bf16(ah[mt], bl, acc[mt][nt], 0, 0, 0);
                acc[mt][nt] = __builtin_amdgcn_mfma_f32_16x16x32_bf16(al[mt], bh, acc[mt][nt], 0, 0, 0);
            }
        }
    }
#undef VISSUE

#pragma unroll
    for (int mt = 0; mt < 4; mt++)
#pragma unroll
        for (int nt = 0; nt < 2; nt++) {
            int col = n0 + wn * 32 + nt * 16 + lr;
            float bb = bias[col];
#pragma unroll
            for (int r = 0; r < 4; r++) {
                int rowg = m0 + wm * 64 + mt * 16 + q * 4 + r;
                Cout[(size_t)rowg * DIM + col] = acc[mt][nt][r] + bb;
            }
        }
}

// ---------------------------------------------------------------------------
// Select v7 (r7 form, best measured): histogram selection -> band-compaction
// -> fp64 rescue -> exact u64 sort -> softmax -> y_row store. Separate
// coalesced pack_rows(y) follows fallback_row.
// ---------------------------------------------------------------------------
__global__ __launch_bounds__(256)
void select6(const unsigned* __restrict__ candBuf, const unsigned* __restrict__ counters,
             const float* __restrict__ trow, const float* __restrict__ q2,
             const float* __restrict__ codebook, float* __restrict__ y,
             unsigned* __restrict__ flags)
{
    __shared__ unsigned recs[CAND_CAP];
    __shared__ unsigned list[RES_CAP];
    __shared__ unsigned hist[256];
    __shared__ unsigned long long keys[RES_CAP];
    __shared__ float q2s[DIM];
    __shared__ float wArr[RES_CAP];
    __shared__ float redf[256];
    __shared__ unsigned redu[256];
    __shared__ unsigned s_R;
    __shared__ unsigned s_b1, s_rem, s_thr;

    const int tid  = threadIdx.x;
    const int lane = tid & 63;
    const int wave = tid >> 6;
    const int row  = blockIdx.x;

    const unsigned cnt = counters[row];
    if (cnt < TOPK || cnt > CAND_CAP) {
        if (tid == 0) flags[row] = 1u;
        return;
    }
    for (int i = tid; i < DIM; i += 256) q2s[i] = q2[(size_t)row * DIM + i];
    for (int i = tid; i < CAND_CAP; i += 256)
        recs[i] = (i < (int)cnt) ? candBuf[(size_t)row * CAND_CAP + i] : 0u;
    if (tid == 0) s_R = 0;
    hist[tid] = 0;
    __syncthreads();

    // pass 1: histogram of top byte of s16 (monotone: larger s16 = larger val)
#pragma unroll
    for (int e = 0; e < 2; e++) {
        int i = tid + e * 256;
        if (i < (int)cnt) atomicAdd(&hist[recs[i] >> 24], 1u);
    }
    __syncthreads();
    if (tid == 0) {
        unsigned c = 0; int b = 255;
        for (; b > 0; b--) {
            unsigned h = hist[b];
            if (c + h >= TOPK) break;
            c += h;
        }
        s_b1 = (unsigned)b; s_rem = TOPK - c;
    }
    __syncthreads();
    const unsigned b1 = s_b1, rem = s_rem;
    hist[tid] = 0;
    __syncthreads();

    // pass 2: low byte among records with top byte == b1
#pragma unroll
    for (int e = 0; e < 2; e++) {
        int i = tid + e * 256;
        if (i < (int)cnt && (recs[i] >> 24) == b1)
            atomicAdd(&hist[(recs[i] >> 16) & 0xFFu], 1u);
    }
    __syncthreads();
    if (tid == 0) {
        unsigned c = 0; int b = 255;
        for (; b > 0; b--) {
            unsigned h = hist[b];
            if (c + h >= rem) break;
            c += h;
        }
        s_thr = (b1 << 8) | (unsigned)b;       // s16 of 64th-largest record
    }
    __syncthreads();

    const float a64  = dec16(s_thr);
    const float band = a64 - 2.f * EPS_SEL;
    if (trow[row] > band) {
        if (tid == 0) flags[row] = 1u;
        return;
    }

    // band-compaction (unordered; exact sort later restores determinism)
#pragma unroll
    for (int e = 0; e < 2; e++) {
        int i = tid + e * 256;
        if (i < (int)cnt && dec16(recs[i] >> 16) >= band) {
            unsigned p = atomicAdd(&s_R, 1u);
            if (p < RES_CAP) list[p] = recs[i];
        }
    }
    __syncthreads();
    const int R = (int)s_R;
    if (R > RES_CAP) {
        if (tid == 0) flags[row] = 1u;
        return;
    }

    // fp64 rescue: wave per candidate, coalesced codebook reads
    for (int c = wave; c < R; c += 4) {
        unsigned idx = list[c] & 0xFFFFu;
        const float* cb = codebook + (size_t)idx * DIM + lane * 8;
        float4 c0 = *(const float4*)cb, c1 = *(const float4*)(cb + 4);
        const float* qp = &q2s[lane * 8];
        float4 a0 = *(const float4*)qp, a1 = *(const float4*)(qp + 4);
        double s = (double)a0.x * c0.x + (double)a0.y * c0.y
                 + (double)a0.z * c0.z + (double)a0.w * c0.w
                 + (double)a1.x * c1.x + (double)a1.y * c1.y
                 + (double)a1.z * c1.z + (double)a1.w * c1.w;
#pragma unroll
        for (int off = 32; off > 0; off >>= 1) s += __shfl_down(s, off);
        if (lane == 0) {
            float val = (float)s;
            unsigned b = __float_as_uint(val);
            unsigned sk = (b & 0x80000000u) ? ~b : (b | 0x80000000u);
            keys[c] = ((unsigned long long)(~sk) << 32) | idx;
        }
    }
    if (tid >= R && tid < RES_CAP) keys[tid] = ~0ULL;
    __syncthreads();

    // bitonic sort 256 u64 ascending (= descending by exact value)
    for (int k = 2; k <= RES_CAP; k <<= 1) {
        for (int j = k >> 1; j > 0; j >>= 1) {
            int ixj = tid ^ j;
            if (ixj > tid) {
                unsigned long long a = keys[tid], b2 = keys[ixj];
                if (((tid & k) == 0) ? (a > b2) : (a < b2)) { keys[tid] = b2; keys[ixj] = a; }
            }
            __syncthreads();
        }
    }

    const unsigned threshInv = (unsigned)(keys[TOPK - 1] >> 32);
    unsigned sk0 = ~(unsigned)(keys[0] >> 32);
    const float vmax = __uint_as_float((sk0 & 0x80000000u) ? (sk0 & 0x7FFFFFFFu) : ~sk0);

    unsigned hi = (unsigned)(keys[tid] >> 32);
    bool sel = (hi <= threshInv);
    unsigned sk = ~hi;
    float val = __uint_as_float((sk & 0x80000000u) ? (sk & 0x7FFFFFFFu) : ~sk);
    float w = sel ? expf(val - vmax) : 0.f;
    wArr[tid] = w;
    redf[tid] = w;
    redu[tid] = sel ? 1u : 0u;
    __syncthreads();
    for (int s = 128; s > 0; s >>= 1) {
        if (tid < s) { redf[tid] += redf[tid + s]; redu[tid] += redu[tid + s]; }
        __syncthreads();
    }
    const float invZ = 1.0f / redf[0];
    const int selCount = (int)redu[0];

    // y_row = sum_i w_i * codebook[idx_i, :]
    for (int d = tid; d < DIM; d += 256) {
        float acc = 0.f;
        for (int i = 0; i < selCount; i++) {
            unsigned idx = (unsigned)(keys[i] & 0xFFFFFFFFu);
            acc += wArr[i] * codebook[(size_t)idx * DIM + d];
        }
        y[(size_t)row * DIM + d] = acc * invZ;
    }
}

// ---------------------------------------------------------------------------
// Exact fallback for flagged rows (expected: ~none). fp64 scan over all VOC.
// ---------------------------------------------------------------------------
__global__ __launch_bounds__(256)
void fallback_row(const unsigned* __restrict__ flags, const float* __restrict__ q2,
                  const float* __restrict__ codebook, const float* __restrict__ trow,
                  const float* __restrict__ sigrow, float* __restrict__ y)
{
    const int row = blockIdx.x;
    if (!flags[row]) return;

    __shared__ float q2s[DIM];
    __shared__ unsigned long long keys[FCAP];
    __shared__ float wArr[FCAP];
    __shared__ float redf[256];
    __shared__ unsigned redu[256];
    __shared__ unsigned s_cnt;

    const int tid = threadIdx.x;
    for (int i = tid; i < DIM; i += 256) q2s[i] = q2[(size_t)row * DIM + i];
    const float sig = sigrow[row];
    float tf = trow[row] - 0.35f * sig;
    unsigned cnt = 0;

    for (int it = 0; it < 16; it++) {
        if (tid == 0) s_cnt = 0;
        __syncthreads();
        for (int i = tid; i < VOC; i += 256) {
            const float* cb = codebook + (size_t)i * DIM;
            double s = 0.0;
            for (int d = 0; d < DIM; d += 4) {
                float4 c4 = *(const float4*)(cb + d);
                s += (double)q2s[d + 0] * (double)c4.x + (double)q2s[d + 1] * (double)c4.y
                   + (double)q2s[d + 2] * (double)c4.z + (double)q2s[d + 3] * (double)c4.w;
            }
            float vv = (float)s;
            if (vv >= tf) {
                unsigned p = atomicAdd(&s_cnt, 1u);
                if (p < FCAP) {
                    unsigned b = __float_as_uint(vv);
                    unsigned sk = (b & 0x80000000u) ? ~b : (b | 0x80000000u);
                    keys[p] = ((unsigned long long)(~sk) << 32) | (unsigned)i;
                }
            }
        }
        __syncthreads();
        cnt = s_cnt;
        if (cnt > FCAP) { tf += 0.15f * sig; continue; }
        if (cnt < TOPK) { tf -= 0.35f * sig; continue; }
        break;
    }
    if (cnt > FCAP) cnt = FCAP;
    for (int i = tid; i < FCAP; i += 256)
        if (i >= (int)cnt) keys[i] = ~0ULL;
    __syncthreads();

    for (int k = 2; k <= FCAP; k <<= 1) {
        for (int j = k >> 1; j > 0; j >>= 1) {
#pragma unroll
            for (int e = 0; e < 4; e++) {
                int i = tid + e * 256;
                int ixj = i ^ j;
                if (ixj > i) {
                    unsigned long long a = keys[i], b = keys[ixj];
                    if (((i & k) == 0) ? (a > b) : (a < b)) { keys[i] = b; keys[ixj] = a; }
                }
            }
            __syncthreads();
        }
    }

    const unsigned threshInv = (unsigned)(keys[TOPK - 1] >> 32);
    unsigned sk0 = ~(unsigned)(keys[0] >> 32);
    const float vmax = __uint_as_float((sk0 & 0x80000000u) ? (sk0 & 0x7FFFFFFFu) : ~sk0);

    float lsum = 0.f; unsigned lcnt = 0;
    for (int i = tid; i < FCAP; i += 256) {
        unsigned hi = (unsigned)(keys[i] >> 32);
        bool sel = (hi <= threshInv);
        unsigned sk = ~hi;
        float vv = __uint_as_float((sk & 0x80000000u) ? (sk & 0x7FFFFFFFu) : ~sk);
        float w = sel ? expf(vv - vmax) : 0.f;
        wArr[i] = w;
        lsum += w; lcnt += sel ? 1u : 0u;
    }
    redf[tid] = lsum; redu[tid] = lcnt;
    __syncthreads();
    for (int s = 128; s > 0; s >>= 1) {
        if (tid < s) { redf[tid] += redf[tid + s]; redu[tid] += redu[tid + s]; }
        __syncthreads();
    }
    const float invZ = 1.f / redf[0];
    const int selCount = (int)redu[0];

    for (int d = tid; d < DIM; d += 256) {
        float acc = 0.f;
        for (int i = 0; i < selCount; i++) {
            unsigned idx = (unsigned)(keys[i] & 0xFFFFFFFFu);
            acc += wArr[i] * codebook[(size_t)idx * DIM + d];
        }
        y[(size_t)row * DIM + d] = acc * invZ;
    }
}

// ---------------------------------------------------------------------------
extern "C" void kernel_launch(void* const* d_in, const int* in_sizes, int n_in,
                              void* d_out, int out_size, void* d_ws, size_t ws_size,
                              hipStream_t stream)
{
    const float* x        = (const float*)d_in[0];
    const float* codebook = (const float*)d_in[1];
    const float* Wq       = (const float*)d_in[2];
    const float* bq       = (const float*)d_in[3];
    const float* Wk       = (const float*)d_in[4];
    // d_in[5] = bk: per-row-constant shift in dots (top-k & softmax invariant)
    const float* Wv       = (const float*)d_in[6];
    const float* bv       = (const float*)d_in[7];
    float* out = (float*)d_out;

    // workspace (~72 MB)
    float* q2   = (float*)d_ws;                       // 4096x512   (8 MB)
    float* Wqk  = q2   + (size_t)BATCH * DIM;         // 512x512    (1 MB)
    float* bqk  = Wqk  + (size_t)DIM * DIM;           // 512 (pad 1024)
    float* y    = bqk  + 1024;                        // 4096x512   (8 MB)
    float* trow = y    + (size_t)BATCH * DIM;         // 4096
    float* sigr = trow + BATCH;                       // 4096
    unsigned* counters = (unsigned*)(sigr + BATCH);   // 4096
    unsigned* flags    = counters + BATCH;            // 4096
    float* cbarsum     = (float*)(flags + BATCH);     // 512
    unsigned* candBuf  = (unsigned*)(cbarsum + 512);  // 4096x512 (8 MB)
    u16* q2h = (u16*)(candBuf + (size_t)BATCH * CAND_CAP);   // 4 MB
    u16* cbh = q2h + (size_t)BATCH * DIM;                    // 32 MB
    u16* yh  = cbh + (size_t)VOC * DIM;                      // 4 MB
    u16* yl  = yh  + (size_t)BATCH * DIM;                    // 4 MB
    u16* wvh = yl  + (size_t)BATCH * DIM;                    // 0.5 MB
    u16* wvl = wvh + (size_t)DIM * DIM;                      // 0.5 MB

    // aliases (no workspace growth):
    //  - x hi/lo pack lives in yh/yl (dead after mfma_out(q2); rewritten by
    //    pack_rows(y) before mfma_out(out))
    //  - Wqk hi/lo pack lives in candBuf (candBuf not needed until mfma_dots)
    u16* xh   = yh;
    u16* xl   = yl;
    u16* wqkh = (u16*)candBuf;
    u16* wqkl = wqkh + (size_t)DIM * DIM;

    dim3 blk(256);

    // Wqk = Wq @ Wk^T (fp64-flush fold); prologue zeroes counters/flags/cbarsum
    gemm64<true, true><<<dim3(DIM / 64, DIM / 64), blk, 0, stream>>>(
        Wq, Wk, nullptr, Wqk, DIM, DIM, DIM, counters, BATCH * 2 + 512);

    // all independent prep in ONE launch: x-pack | Wqk-pack | cb-pack |
    // Wv-pack | cbar_accum | bias_fold
    fused_prep<<<dim3(9856), blk, 0, stream>>>(
        x, Wqk, codebook, Wv, bq, Wk,
        xh, xl, wqkh, wqkl, cbh, wvh, wvl, cbarsum, bqk);

    // q2 = x @ Wqk + bqk via hi/lo 3-pass MFMA (256 blocks)
    mfma_out<<<dim3(DIM / 64, BATCH / 128), blk, 0, stream>>>(
        xh, xl, wqkh, wqkl, bqk, q2, BATCH);

    // rowstats + q2-pack in one launch
    fused_q2post<<<dim3(2048), blk, 0, stream>>>(q2, cbarsum, trow, sigr, q2h);

    // fused dots GEMM (v13: 2-stage counted-vmcnt pipeline) + candidate append
    mfma_dots<<<dim3(8192), blk, 0, stream>>>(q2h, cbh, trow, candBuf, counters);

    // exact selection + softmax + y = attn @ codebook
    select6<<<dim3(BATCH), blk, 0, stream>>>(
        candBuf, counters, trow, q2, codebook, y, flags);
    fallback_row<<<dim3(BATCH), blk, 0, stream>>>(
        flags, q2, codebook, trow, sigr, y);

    // out = y @ Wv + bv  (hi/lo 3-pass MFMA, 256 blocks)
    pack_rows<<<dim3(BATCH * 64 / 256), blk, 0, stream>>>(y, yh, yl, BATCH, 12);
    mfma_out<<<dim3(DIM / 64, BATCH / 128), blk, 0, stream>>>(
        yh, yl, wvh, wvl, bv, out, BATCH);
}

// Round 13
// 638.083 us; speedup vs baseline: 1.0456x; 1.0061x over previous
//
#include <hip/hip_runtime.h>
#include <cstdint>

#define VOC   32768
#define DIM   512
#define TOPK  64
#define BATCH 4096

#define KSIG     2.45f
#define EPS_SEL  0.012f
#define CAND_CAP 512
#define RES_CAP  256
#define FCAP     1024

typedef unsigned short u16;
typedef __attribute__((ext_vector_type(8))) short bf16x8;
typedef __attribute__((ext_vector_type(4))) float f32x4;

// ---- bf16 helpers (RNE) ----------------------------------------------------
__device__ __forceinline__ u16 f2bf(float f) {
    unsigned u = __float_as_uint(f);
    unsigned r = (u + 0x7FFFu + ((u >> 16) & 1u)) >> 16;
    return (u16)r;
}
__device__ __forceinline__ float bf2f(u16 h) {
    return __uint_as_float(((unsigned)h) << 16);
}
__device__ __forceinline__ unsigned enc16(u16 h) {
    return (h & 0x8000u) ? (unsigned)((u16)~h) : (unsigned)(h | 0x8000u);
}
__device__ __forceinline__ float dec16(unsigned s16) {
    u16 h = (s16 & 0x8000u) ? (u16)(s16 ^ 0x8000u) : (u16)(~s16);
    return bf2f(h);
}

// ---- async global->LDS 16B -------------------------------------------------
__device__ __forceinline__ void async16(const void* g, void* l) {
    __builtin_amdgcn_global_load_lds(
        (const __attribute__((address_space(1))) void*)g,
        (__attribute__((address_space(3))) void*)l, 16, 0, 0);
}

// ---------------------------------------------------------------------------
// fp32 64x64-tile GEMM + optional per-k-tile fp64 flush. 256 thr, 4x4 micro.
// Retained ONLY for the precision-critical fold Wqk = Wq @ Wk^T. Prologue
// also zeroes the counters/flags/cbarsum words (fold of the old zero_ws
// launch: 64 blocks x 256 thr >= 8704 words; disjoint memory, stream-ordered
// before all consumers).
// ---------------------------------------------------------------------------
template <bool BT, bool F64ACC>
__global__ __launch_bounds__(256)
void gemm64(const float* __restrict__ A, const float* __restrict__ B,
            const float* __restrict__ bias, float* __restrict__ C,
            int M, int N, int K, unsigned* __restrict__ zeroP, int zeroN)
{
    const int KS = 16;
    __shared__ float As[KS][68];
    __shared__ float Bs[KS][64];

    const int tid = threadIdx.x;
    if (zeroP) {
        int zi = (blockIdx.y * gridDim.x + blockIdx.x) * 256 + tid;
        if (zi < zeroN) zeroP[zi] = 0u;
    }

    const int m0 = blockIdx.y * 64;
    const int n0 = blockIdx.x * 64;
    const int ty = tid >> 4;
    const int tx = tid & 15;

    float acc[4][4];
    double acc64[4][4];
#pragma unroll
    for (int i = 0; i < 4; i++)
#pragma unroll
        for (int j = 0; j < 4; j++) { acc[i][j] = 0.f; if (F64ACC) acc64[i][j] = 0.0; }

    for (int kt = 0; kt < K; kt += KS) {
        {
            int row = tid >> 2, kq = tid & 3;
            const float4 av = *(const float4*)(A + (size_t)(m0 + row) * K + kt + kq * 4);
            As[kq * 4 + 0][row] = av.x;
            As[kq * 4 + 1][row] = av.y;
            As[kq * 4 + 2][row] = av.z;
            As[kq * 4 + 3][row] = av.w;
        }
        if (!BT) {
            int krow = tid >> 4, nq = tid & 15;
            *(float4*)&Bs[krow][nq * 4] =
                *(const float4*)(B + (size_t)(kt + krow) * N + n0 + nq * 4);
        } else {
            int nrow = tid >> 2, kq = tid & 3;
            const float4 bv = *(const float4*)(B + (size_t)(n0 + nrow) * K + kt + kq * 4);
            Bs[kq * 4 + 0][nrow] = bv.x;
            Bs[kq * 4 + 1][nrow] = bv.y;
            Bs[kq * 4 + 2][nrow] = bv.z;
            Bs[kq * 4 + 3][nrow] = bv.w;
        }
        __syncthreads();

#pragma unroll
        for (int kk = 0; kk < KS; kk++) {
            float4 a = *(const float4*)&As[kk][ty * 4];
            float4 b = *(const float4*)&Bs[kk][tx * 4];
            float av[4] = {a.x, a.y, a.z, a.w};
            float bv[4] = {b.x, b.y, b.z, b.w};
#pragma unroll
            for (int i = 0; i < 4; i++)
#pragma unroll
                for (int j = 0; j < 4; j++)
                    acc[i][j] += av[i] * bv[j];
        }
        __syncthreads();
        if (F64ACC) {
#pragma unroll
            for (int i = 0; i < 4; i++)
#pragma unroll
                for (int j = 0; j < 4; j++) { acc64[i][j] += (double)acc[i][j]; acc[i][j] = 0.f; }
        }
    }

    float4 bb = make_float4(0.f, 0.f, 0.f, 0.f);
    if (bias) bb = *(const float4*)(bias + n0 + tx * 4);
#pragma unroll
    for (int i = 0; i < 4; i++) {
        float4 o;
        o.x = (F64ACC ? (float)acc64[i][0] : acc[i][0]) + bb.x;
        o.y = (F64ACC ? (float)acc64[i][1] : acc[i][1]) + bb.y;
        o.z = (F64ACC ? (float)acc64[i][2] : acc[i][2]) + bb.z;
        o.w = (F64ACC ? (float)acc64[i][3] : acc[i][3]) + bb.w;
        *(float4*)(C + (size_t)(m0 + ty * 4 + i) * N + n0 + tx * 4) = o;
    }
}

// ---------------------------------------------------------------------------
// Device bodies for the fused prep kernels (virtual block id passed in).
// ---------------------------------------------------------------------------
__device__ __forceinline__ void pack_rows_dev(int bid, int tid,
        const float* __restrict__ src, u16* __restrict__ hi,
        u16* __restrict__ lo, int R, int log2R)
{
    int idx = bid * 256 + tid;
    int c8  = idx >> log2R;
    int row = idx & (R - 1);
    const float* sp = src + (size_t)row * DIM + c8 * 8;
    float xv[8];
    *(float4*)&xv[0] = *(const float4*)sp;
    *(float4*)&xv[4] = *(const float4*)(sp + 4);
    int ks = c8 >> 2, ch = c8 & 3;
    size_t ob = ((size_t)(ks * 4 + ch) * R + row) * 8;
    u16 h[8], l[8];
#pragma unroll
    for (int j = 0; j < 8; j++) {
        h[j] = f2bf(xv[j]);
        l[j] = f2bf(xv[j] - bf2f(h[j]));
    }
    *(uint4*)(hi + ob) = *(const uint4*)h;
    if (lo) *(uint4*)(lo + ob) = *(const uint4*)l;
}

__device__ __forceinline__ void pack_bT_dev(int bid, int tid,
        const float* __restrict__ W, u16* __restrict__ hi, u16* __restrict__ lo)
{
    int idx = bid * 256 + tid;
    int n  = idx & (DIM - 1);
    int c8 = idx >> 9;
    int ks = c8 >> 2, ch = c8 & 3;
    size_t ob = ((size_t)(ks * 4 + ch) * DIM + n) * 8;
    u16 h[8], l[8];
#pragma unroll
    for (int j = 0; j < 8; j++) {
        float x = W[(size_t)(c8 * 8 + j) * DIM + n];
        h[j] = f2bf(x);
        l[j] = f2bf(x - bf2f(h[j]));
    }
    *(uint4*)(hi + ob) = *(const uint4*)h;
    *(uint4*)(lo + ob) = *(const uint4*)l;
}

__device__ __forceinline__ void cbar_dev(int bid, int tid,
        const float* __restrict__ cb, float* __restrict__ cbarsum)
{
    const int r0 = bid * 128;
    float s0 = 0.f, s1 = 0.f;
    for (int r = 0; r < 128; r++) {
        const float* rp = cb + (size_t)(r0 + r) * DIM;
        s0 += rp[tid];
        s1 += rp[tid + 256];
    }
    atomicAdd(&cbarsum[tid], s0);
    atomicAdd(&cbarsum[tid + 256], s1);
}

__device__ __forceinline__ void bias_fold_dev(int bid, int tid,
        const float* __restrict__ bq, const float* __restrict__ Wk,
        float* __restrict__ bqk)
{
    const int lane = tid & 63, wave = tid >> 6;
    const int j = bid * 4 + wave;
    const float* wr = Wk + (size_t)j * DIM + lane * 8;
    const float* bp = bq + lane * 8;
    double s = 0.0;
#pragma unroll
    for (int t = 0; t < 8; t++) s += (double)bp[t] * (double)wr[t];
#pragma unroll
    for (int off = 32; off > 0; off >>= 1) s += __shfl_down(s, off);
    if (lane == 0) bqk[j] = (float)s;
}

__device__ __forceinline__ void rowstats_dev(int bid, int tid,
        const float* __restrict__ q2, const float* __restrict__ cbarsum,
        float* __restrict__ trow, float* __restrict__ sigrow)
{
    const int lane = tid & 63, wave = tid >> 6;
    const int row = bid * 4 + wave;
    const float* qp = q2 + (size_t)row * DIM + lane * 8;
    float4 a0 = *(const float4*)qp, a1 = *(const float4*)(qp + 4);
    const float* cp = cbarsum + lane * 8;
    float4 c0 = *(const float4*)cp, c1 = *(const float4*)(cp + 4);
    float mu = a0.x*c0.x + a0.y*c0.y + a0.z*c0.z + a0.w*c0.w
             + a1.x*c1.x + a1.y*c1.y + a1.z*c1.z + a1.w*c1.w;
    float nr = a0.x*a0.x + a0.y*a0.y + a0.z*a0.z + a0.w*a0.w
             + a1.x*a1.x + a1.y*a1.y + a1.z*a1.z + a1.w*a1.w;
#pragma unroll
    for (int off = 32; off > 0; off >>= 1) {
        mu += __shfl_down(mu, off);
        nr += __shfl_down(nr, off);
    }
    if (lane == 0) {
        mu *= (1.f / VOC);
        float sig = sqrtf(nr * (1.f / 1536.f));
        trow[row] = mu + KSIG * sig;
        sigrow[row] = sig;
    }
}

// ---------------------------------------------------------------------------
// fused_prep: all pre-dots prep that only depends on {inputs, Wqk, zeroed ws}.
// Block ranges: [0,1024) x-pack hi/lo | [1024,1152) Wqk-bT | [1152,9344)
// cb-pack | [9344,9472) Wv-bT | [9472,9728) cbar_accum | [9728,9856) bias_fold
// ---------------------------------------------------------------------------
__global__ __launch_bounds__(256)
void fused_prep(const float* __restrict__ x, const float* __restrict__ Wqk,
                const float* __restrict__ codebook, const float* __restrict__ Wv,
                const float* __restrict__ bq, const float* __restrict__ Wk,
                u16* __restrict__ xh, u16* __restrict__ xl,
                u16* __restrict__ wqkh, u16* __restrict__ wqkl,
                u16* __restrict__ cbh, u16* __restrict__ wvh,
                u16* __restrict__ wvl, float* __restrict__ cbarsum,
                float* __restrict__ bqk)
{
    const int b = blockIdx.x, tid = threadIdx.x;
    if (b < 1024)       pack_rows_dev(b, tid, x, xh, xl, BATCH, 12);
    else if (b < 1152)  pack_bT_dev(b - 1024, tid, Wqk, wqkh, wqkl);
    else if (b < 9344)  pack_rows_dev(b - 1152, tid, codebook, cbh, nullptr, VOC, 15);
    else if (b < 9472)  pack_bT_dev(b - 9344, tid, Wv, wvh, wvl);
    else if (b < 9728)  cbar_dev(b - 9472, tid, codebook, cbarsum);
    else                bias_fold_dev(b - 9728, tid, bq, Wk, bqk);
}

// fused_q2post: rowstats + q2-pack (both read q2). [0,1024) | [1024,2048)
__global__ __launch_bounds__(256)
void fused_q2post(const float* __restrict__ q2, const float* __restrict__ cbarsum,
                  float* __restrict__ trow, float* __restrict__ sigrow,
                  u16* __restrict__ q2h)
{
    const int b = blockIdx.x, tid = threadIdx.x;
    if (b < 1024) rowstats_dev(b, tid, q2, cbarsum, trow, sigrow);
    else          pack_rows_dev(b - 1024, tid, q2, q2h, nullptr, BATCH, 12);
}

// standalone pack_rows: used for y AFTER select/fallback. Coalesced by
// construction (block per c8-range, consecutive rows) — r11 lesson: fusing
// this into select6 transposes the access to 64KB-strided 16B scatters
// (+15us). The separate pass IS the transpose.
__global__ __launch_bounds__(256)
void pack_rows(const float* __restrict__ src, u16* __restrict__ hi,
               u16* __restrict__ lo, int R, int log2R)
{
    pack_rows_dev(blockIdx.x, threadIdx.x, src, hi, lo, R, log2R);
}

// ---------------------------------------------------------------------------
// Fused dots GEMM v13 (best measured, 235-240us): 128x128, 4 waves, acc[4][4]
// = 64 AGPR, 32KB LDS 2-stage, (256,4) -> 16 waves/CU = register-file
// roofline. Counted-vmcnt pipeline: per step s:
//   wait vmcnt(4) -> barrier A -> 4 ds_read A + 3x(ds_read B + 4 MFMA) + B3
//   -> lgkmcnt(0) + barrier B -> ISSUE(s+2) into just-freed buffer -> 4 MFMA.
// ---------------------------------------------------------------------------
__global__ __launch_bounds__(256, 4)
void mfma_dots(const u16* __restrict__ Ah, const u16* __restrict__ Bh,
               const float* __restrict__ trow, unsigned* __restrict__ candBuf,
               unsigned* __restrict__ counters)
{
    __shared__ u16 lds[2 * 8192];      // 2 stages x (A 4096 + B 4096) u16 = 32 KB

    const int tid  = threadIdx.x;
    const int lane = tid & 63;
    const int wave = tid >> 6;
    const int wm = wave >> 1, wn = wave & 1;
    const int lr = lane & 15;
    const int q  = lane >> 4;

    // XCD-affinity: xcd owns a 4-m-tile band; within XCD, m fastest then n.
    const int L   = blockIdx.x;
    const int xcd = L & 7;
    const int j   = L >> 3;                    // 0..1023
    const int m0  = (xcd * 4 + (j & 3)) * 128;
    const int n0  = (j >> 2) * 128;

    const int a  = wave >> 1;                  // 0: stage A (q2h), 1: stage B (cbh)
    const u16* src = a ? Bh : Ah;
    const int rb   = a ? n0 : m0;
    const size_t R = a ? (size_t)VOC : (size_t)BATCH;
    const int i0   = (wave & 1) * 4;

    // strength-reduced staging pointers: gpX walks ks=0..15 by const stride
    const size_t gstep = (size_t)4 * R * 8;    // u16 elems per ks-step
    const u16* gp0 = src + ((size_t)(((i0 + 0) >> 1)) * R + rb + ((i0 + 0) & 1) * 64 + lane) * 8;
    const u16* gp1 = src + ((size_t)(((i0 + 1) >> 1)) * R + rb + ((i0 + 1) & 1) * 64 + lane) * 8;
    const u16* gp2 = src + ((size_t)(((i0 + 2) >> 1)) * R + rb + ((i0 + 2) & 1) * 64 + lane) * 8;
    const u16* gp3 = src + ((size_t)(((i0 + 3) >> 1)) * R + rb + ((i0 + 3) & 1) * 64 + lane) * 8;
    const int loff0 = a * 4096 + (i0 + 0) * 512 + lane * 8;
    const int loff1 = a * 4096 + (i0 + 1) * 512 + lane * 8;
    const int loff2 = a * 4096 + (i0 + 2) * 512 + lane * 8;
    const int loff3 = a * 4096 + (i0 + 3) * 512 + lane * 8;

#define ISSUE(b)                                                              \
    {                                                                         \
        async16(gp0, &lds[(b) * 8192 + loff0]); gp0 += gstep;                 \
        async16(gp1, &lds[(b) * 8192 + loff1]); gp1 += gstep;                 \
        async16(gp2, &lds[(b) * 8192 + loff2]); gp2 += gstep;                 \
        async16(gp3, &lds[(b) * 8192 + loff3]); gp3 += gstep;                 \
    }

    f32x4 acc[4][4] = {};

    // prologue: tiles 0 and 1 in flight (8 loads/thread); ptrs now at ks=2
    ISSUE(0)
    ISSUE(1)

    for (int s = 0; s < 16; s++) {
        if (s < 15) __builtin_amdgcn_s_waitcnt(0x0F74);   // vmcnt(4): stage s landed
        else        __builtin_amdgcn_s_waitcnt(0x0F70);   // vmcnt(0): last stage
        __builtin_amdgcn_s_barrier();                     // A: staging published
        const u16* base = &lds[(s & 1) * 8192];

        bf16x8 ah[4];
#pragma unroll
        for (int mt = 0; mt < 4; mt++)
            ah[mt] = *(const bf16x8*)&base[q * 1024 + (wm * 64 + mt * 16 + lr) * 8];

        __builtin_amdgcn_s_setprio(1);
#pragma unroll
        for (int nt = 0; nt < 3; nt++) {
            bf16x8 bh = *(const bf16x8*)&base[4096 + q * 1024 + (wn * 64 + nt * 16 + lr) * 8];
#pragma unroll
            for (int mt = 0; mt < 4; mt++)
                acc[mt][nt] = __builtin_amdgcn_mfma_f32_16x16x32_bf16(ah[mt], bh, acc[mt][nt], 0, 0, 0);
        }
        bf16x8 bh3 = *(const bf16x8*)&base[4096 + q * 1024 + (wn * 64 + 3 * 16 + lr) * 8];
        __builtin_amdgcn_s_setprio(0);

        __builtin_amdgcn_s_waitcnt(0xC07F);    // lgkmcnt(0): this wave's 8 reads done
        __builtin_amdgcn_s_barrier();          // B: ALL waves done reading buf[s&1]
        __builtin_amdgcn_sched_barrier(0);
        if (s < 14) ISSUE(s & 1)               // stage s+2 into just-freed buffer

        __builtin_amdgcn_s_setprio(1);
#pragma unroll
        for (int mt = 0; mt < 4; mt++)
            acc[mt][3] = __builtin_amdgcn_mfma_f32_16x16x32_bf16(ah[mt], bh3, acc[mt][3], 0, 0, 0);
        __builtin_amdgcn_s_setprio(0);
    }
#undef ISSUE

    // epilogue: threshold-append candidates
#pragma unroll
    for (int mt = 0; mt < 4; mt++) {
#pragma unroll
        for (int r = 0; r < 4; r++) {
            int rowg = m0 + wm * 64 + mt * 16 + q * 4 + r;
            float tr = trow[rowg];
#pragma unroll
            for (int nt = 0; nt < 4; nt++) {
                float val = acc[mt][nt][r];
                if (val >= tr) {
                    unsigned slot = atomicAdd(&counters[rowg], 1u);
                    if (slot < CAND_CAP) {
                        unsigned s16 = enc16(f2bf(val));
                        candBuf[(size_t)rowg * CAND_CAP + slot] =
                            (s16 << 16) | (unsigned)(n0 + wn * 64 + nt * 16 + lr);
                    }
                }
            }
        }
    }
}

// ---------------------------------------------------------------------------
// out = A @ W + bias in bf16 hi/lo 3-pass MFMA (error ~1e-6). Regrid (r8,
// bit-identical): tile 128m x 64n, grid 256 blocks, acc[4][2]=32 AGPR,
// LDS 48 KB -> 3 blocks/CU. Used for q2 = x@Wqk + bqk and out = y@Wv + bv.
// ---------------------------------------------------------------------------
__global__ __launch_bounds__(256, 3)
void mfma_out(const u16* __restrict__ Ah, const u16* __restrict__ Al,
              const u16* __restrict__ Bh, const u16* __restrict__ Bl,
              const float* __restrict__ bias, float* __restrict__ Cout, int Ma)
{
    __shared__ u16 lds[2 * 12288];   // 2 stages x 24 KB

    const int tid  = threadIdx.x;
    const int lane = tid & 63;
    const int wave = tid >> 6;
    const int wm = wave >> 1, wn = wave & 1;
    const int m0 = blockIdx.y * 128, n0 = blockIdx.x * 64;
    const int lr = lane & 15;
    const int q  = lane >> 4;
    const size_t R = (size_t)Ma;

    f32x4 acc[4][2] = {};

#define VISSUE(ks, b)                                                          \
    {                                                                          \
        _Pragma("unroll")                                                      \
        for (int i_ = 0; i_ < 2; i_++) {                                       \
            int u_ = tid + i_ * 256;                                           \
            size_t ai_ = ((size_t)((ks) * 4 + (u_ >> 7)) * R + m0 + (u_ & 127)) * 8; \
            async16(Ah + ai_, &lds[(b) * 12288 + u_ * 8]);                     \
            async16(Al + ai_, &lds[(b) * 12288 + 6144 + u_ * 8]);              \
        }                                                                      \
        {                                                                      \
            int u_ = tid;                                                      \
            size_t bi_ = ((size_t)((ks) * 4 + (u_ >> 6)) * DIM + n0 + (u_ & 63)) * 8; \
            async16(Bh + bi_, &lds[(b) * 12288 + 4096 + u_ * 8]);              \
            async16(Bl + bi_, &lds[(b) * 12288 + 10240 + u_ * 8]);             \
        }                                                                      \
    }

    VISSUE(0, 0)

    for (int ks = 0; ks < 16; ks++) {
        __syncthreads();                       // drains vmcnt(0): stage ks in LDS
        if (ks < 15) VISSUE(ks + 1, (ks + 1) & 1)
        const u16* base = &lds[(ks & 1) * 12288];

        bf16x8 ah[4], al[4];
#pragma unroll
        for (int mt = 0; mt < 4; mt++) {
            int row = wm * 64 + mt * 16 + lr;
            ah[mt] = *(const bf16x8*)&base[q * 1024 + row * 8];
            al[mt] = *(const bf16x8*)&base[6144 + q * 1024 + row * 8];
        }
#pragma unroll
        for (int nt = 0; nt < 2; nt++) {
            int col = wn * 32 + nt * 16 + lr;
            bf16x8 bh = *(const bf16x8*)&base[4096 + q * 512 + col * 8];
            bf16x8 bl = *(const bf16x8*)&base[10240 + q * 512 + col * 8];
#pragma unroll
            for (int mt = 0; mt < 4; mt++) {
                acc[mt][nt] = __builtin_amdgcn_mfma_f32_16x16x32_bf16(ah[mt], bh, acc[mt][nt], 0, 0, 0);
                acc[mt][nt] = __builtin_amdgcn_mfma_f32_16x16x32_bf16(ah[mt], bl, acc[mt][nt], 0, 0, 0);
                acc[mt][nt] = __builtin_amdgcn_mfma_f32_16x16x32_bf16(al[mt], bh, acc[mt][nt], 0, 0, 0);
            }
        }
    }
#undef VISSUE

#pragma unroll
    for (int mt = 0; mt < 4; mt++)
#pragma unroll
        for (int nt = 0; nt < 2; nt++) {
            int col = n0 + wn * 32 + nt * 16 + lr;
            float bb = bias[col];
#pragma unroll
            for (int r = 0; r < 4; r++) {
                int rowg = m0 + wm * 64 + mt * 16 + q * 4 + r;
                Cout[(size_t)rowg * DIM + col] = acc[mt][nt][r] + bb;
            }
        }
}

// ---------------------------------------------------------------------------
// Select v10 = r12's select6 with two latency fixes (bit-identical results):
//  (a) fp64 rescue 2-deep prefetch: candidate c+4's codebook row loads are
//      issued BEFORE computing candidate c -> one full iteration (~200+ cyc
//      of fp64 FMA + 6-shuffle chain) hides the ~600-900 cyc L3 latency that
//      was previously exposed per candidate. Per-candidate sum order
//      unchanged. Cost ~16 VGPR (depth-2 chosen over 4-deep batching to
//      avoid an occupancy cliff; kernel is wave-capped at 8 blocks/CU).
//  (b) y_row single-pass dual-accumulator: one walk over keys/wArr computes
//      d=tid and d=tid+256 together (same per-d order -> bit-identical),
//      doubling independent loads in flight and halving LDS re-reads.
// ---------------------------------------------------------------------------
__global__ __launch_bounds__(256)
void select6(const unsigned* __restrict__ candBuf, const unsigned* __restrict__ counters,
             const float* __restrict__ trow, const float* __restrict__ q2,
             const float* __restrict__ codebook, float* __restrict__ y,
             unsigned* __restrict__ flags)
{
    __shared__ unsigned recs[CAND_CAP];
    __shared__ unsigned list[RES_CAP];
    __shared__ unsigned hist[256];
    __shared__ unsigned long long keys[RES_CAP];
    __shared__ float q2s[DIM];
    __shared__ float wArr[RES_CAP];
    __shared__ float redf[256];
    __shared__ unsigned redu[256];
    __shared__ unsigned s_R;
    __shared__ unsigned s_b1, s_rem, s_thr;

    const int tid  = threadIdx.x;
    const int lane = tid & 63;
    const int wave = tid >> 6;
    const int row  = blockIdx.x;

    const unsigned cnt = counters[row];
    if (cnt < TOPK || cnt > CAND_CAP) {
        if (tid == 0) flags[row] = 1u;
        return;
    }
    for (int i = tid; i < DIM; i += 256) q2s[i] = q2[(size_t)row * DIM + i];
    for (int i = tid; i < CAND_CAP; i += 256)
        recs[i] = (i < (int)cnt) ? candBuf[(size_t)row * CAND_CAP + i] : 0u;
    if (tid == 0) s_R = 0;
    hist[tid] = 0;
    __syncthreads();

    // pass 1: histogram of top byte of s16 (monotone: larger s16 = larger val)
#pragma unroll
    for (int e = 0; e < 2; e++) {
        int i = tid + e * 256;
        if (i < (int)cnt) atomicAdd(&hist[recs[i] >> 24], 1u);
    }
    __syncthreads();
    if (tid == 0) {
        unsigned c = 0; int b = 255;
        for (; b > 0; b--) {
            unsigned h = hist[b];
            if (c + h >= TOPK) break;
            c += h;
        }
        s_b1 = (unsigned)b; s_rem = TOPK - c;
    }
    __syncthreads();
    const unsigned b1 = s_b1, rem = s_rem;
    hist[tid] = 0;
    __syncthreads();

    // pass 2: low byte among records with top byte == b1
#pragma unroll
    for (int e = 0; e < 2; e++) {
        int i = tid + e * 256;
        if (i < (int)cnt && (recs[i] >> 24) == b1)
            atomicAdd(&hist[(recs[i] >> 16) & 0xFFu], 1u);
    }
    __syncthreads();
    if (tid == 0) {
        unsigned c = 0; int b = 255;
        for (; b > 0; b--) {
            unsigned h = hist[b];
            if (c + h >= rem) break;
            c += h;
        }
        s_thr = (b1 << 8) | (unsigned)b;       // s16 of 64th-largest record
    }
    __syncthreads();

    const float a64  = dec16(s_thr);
    const float band = a64 - 2.f * EPS_SEL;
    if (trow[row] > band) {
        if (tid == 0) flags[row] = 1u;
        return;
    }

    // band-compaction (unordered; exact sort later restores determinism)
#pragma unroll
    for (int e = 0; e < 2; e++) {
        int i = tid + e * 256;
        if (i < (int)cnt && dec16(recs[i] >> 16) >= band) {
            unsigned p = atomicAdd(&s_R, 1u);
            if (p < RES_CAP) list[p] = recs[i];
        }
    }
    __syncthreads();
    const int R = (int)s_R;
    if (R > RES_CAP) {
        if (tid == 0) flags[row] = 1u;
        return;
    }

    // fp64 rescue: wave per candidate, 2-deep prefetch (see header comment)
    {
        const float* qp = &q2s[lane * 8];
        float4 a0 = *(const float4*)qp, a1 = *(const float4*)(qp + 4);
        unsigned nIdx = 0;
        float4 p0 = make_float4(0.f, 0.f, 0.f, 0.f), p1 = p0;
        if (wave < R) {
            nIdx = list[wave] & 0xFFFFu;
            const float* cb = codebook + (size_t)nIdx * DIM + lane * 8;
            p0 = *(const float4*)cb; p1 = *(const float4*)(cb + 4);
        }
        for (int c = wave; c < R; c += 4) {
            const unsigned uIdx = nIdx;
            const float4 u0 = p0, u1 = p1;
            if (c + 4 < R) {
                nIdx = list[c + 4] & 0xFFFFu;
                const float* cb = codebook + (size_t)nIdx * DIM + lane * 8;
                p0 = *(const float4*)cb; p1 = *(const float4*)(cb + 4);
            }
            double s = (double)a0.x * u0.x + (double)a0.y * u0.y
                     + (double)a0.z * u0.z + (double)a0.w * u0.w
                     + (double)a1.x * u1.x + (double)a1.y * u1.y
                     + (double)a1.z * u1.z + (double)a1.w * u1.w;
#pragma unroll
            for (int off = 32; off > 0; off >>= 1) s += __shfl_down(s, off);
            if (lane == 0) {
                float val = (float)s;
                unsigned b = __float_as_uint(val);
                unsigned sk = (b & 0x80000000u) ? ~b : (b | 0x80000000u);
                keys[c] = ((unsigned long long)(~sk) << 32) | uIdx;
            }
        }
    }
    if (tid >= R && tid < RES_CAP) keys[tid] = ~0ULL;
    __syncthreads();

    // bitonic sort 256 u64 ascending (= descending by exact value)
    for (int k = 2; k <= RES_CAP; k <<= 1) {
        for (int j = k >> 1; j > 0; j >>= 1) {
            int ixj = tid ^ j;
            if (ixj > tid) {
                unsigned long long a = keys[tid], b2 = keys[ixj];
                if (((tid & k) == 0) ? (a > b2) : (a < b2)) { keys[tid] = b2; keys[ixj] = a; }
            }
            __syncthreads();
        }
    }

    const unsigned threshInv = (unsigned)(keys[TOPK - 1] >> 32);
    unsigned sk0 = ~(unsigned)(keys[0] >> 32);
    const float vmax = __uint_as_float((sk0 & 0x80000000u) ? (sk0 & 0x7FFFFFFFu) : ~sk0);

    unsigned hi = (unsigned)(keys[tid] >> 32);
    bool sel = (hi <= threshInv);
    unsigned sk = ~hi;
    float val = __uint_as_float((sk & 0x80000000u) ? (sk & 0x7FFFFFFFu) : ~sk);
    float w = sel ? expf(val - vmax) : 0.f;
    wArr[tid] = w;
    redf[tid] = w;
    redu[tid] = sel ? 1u : 0u;
    __syncthreads();
    for (int s = 128; s > 0; s >>= 1) {
        if (tid < s) { redf[tid] += redf[tid + s]; redu[tid] += redu[tid + s]; }
        __syncthreads();
    }
    const float invZ = 1.0f / redf[0];
    const int selCount = (int)redu[0];

    // y_row: single pass, dual accumulators (d=tid and d=tid+256)
    {
        float acc0 = 0.f, acc1 = 0.f;
        const int d0 = tid, d1 = tid + 256;
        for (int i = 0; i < selCount; i++) {
            unsigned idx = (unsigned)(keys[i] & 0xFFFFFFFFu);
            float w2 = wArr[i];
            const float* cb = codebook + (size_t)idx * DIM;
            acc0 += w2 * cb[d0];
            acc1 += w2 * cb[d1];
        }
        y[(size_t)row * DIM + d0] = acc0 * invZ;
        y[(size_t)row * DIM + d1] = acc1 * invZ;
    }
}

// ---------------------------------------------------------------------------
// Exact fallback for flagged rows (expected: ~none). fp64 scan over all VOC.
// ---------------------------------------------------------------------------
__global__ __launch_bounds__(256)
void fallback_row(const unsigned* __restrict__ flags, const float* __restrict__ q2,
                  const float* __restrict__ codebook, const float* __restrict__ trow,
                  const float* __restrict__ sigrow, float* __restrict__ y)
{
    const int row = blockIdx.x;
    if (!flags[row]) return;

    __shared__ float q2s[DIM];
    __shared__ unsigned long long keys[FCAP];
    __shared__ float wArr[FCAP];
    __shared__ float redf[256];
    __shared__ unsigned redu[256];
    __shared__ unsigned s_cnt;

    const int tid = threadIdx.x;
    for (int i = tid; i < DIM; i += 256) q2s[i] = q2[(size_t)row * DIM + i];
    const float sig = sigrow[row];
    float tf = trow[row] - 0.35f * sig;
    unsigned cnt = 0;

    for (int it = 0; it < 16; it++) {
        if (tid == 0) s_cnt = 0;
        __syncthreads();
        for (int i = tid; i < VOC; i += 256) {
            const float* cb = codebook + (size_t)i * DIM;
            double s = 0.0;
            for (int d = 0; d < DIM; d += 4) {
                float4 c4 = *(const float4*)(cb + d);
                s += (double)q2s[d + 0] * (double)c4.x + (double)q2s[d + 1] * (double)c4.y
                   + (double)q2s[d + 2] * (double)c4.z + (double)q2s[d + 3] * (double)c4.w;
            }
            float vv = (float)s;
            if (vv >= tf) {
                unsigned p = atomicAdd(&s_cnt, 1u);
                if (p < FCAP) {
                    unsigned b = __float_as_uint(vv);
                    unsigned sk = (b & 0x80000000u) ? ~b : (b | 0x80000000u);
                    keys[p] = ((unsigned long long)(~sk) << 32) | (unsigned)i;
                }
            }
        }
        __syncthreads();
        cnt = s_cnt;
        if (cnt > FCAP) { tf += 0.15f * sig; continue; }
        if (cnt < TOPK) { tf -= 0.35f * sig; continue; }
        break;
    }
    if (cnt > FCAP) cnt = FCAP;
    for (int i = tid; i < FCAP; i += 256)
        if (i >= (int)cnt) keys[i] = ~0ULL;
    __syncthreads();

    for (int k = 2; k <= FCAP; k <<= 1) {
        for (int j = k >> 1; j > 0; j >>= 1) {
#pragma unroll
            for (int e = 0; e < 4; e++) {
                int i = tid + e * 256;
                int ixj = i ^ j;
                if (ixj > i) {
                    unsigned long long a = keys[i], b = keys[ixj];
                    if (((i & k) == 0) ? (a > b) : (a < b)) { keys[i] = b; keys[ixj] = a; }
                }
            }
            __syncthreads();
        }
    }

    const unsigned threshInv = (unsigned)(keys[TOPK - 1] >> 32);
    unsigned sk0 = ~(unsigned)(keys[0] >> 32);
    const float vmax = __uint_as_float((sk0 & 0x80000000u) ? (sk0 & 0x7FFFFFFFu) : ~sk0);

    float lsum = 0.f; unsigned lcnt = 0;
    for (int i = tid; i < FCAP; i += 256) {
        unsigned hi = (unsigned)(keys[i] >> 32);
        bool sel = (hi <= threshInv);
        unsigned sk = ~hi;
        float vv = __uint_as_float((sk & 0x80000000u) ? (sk & 0x7FFFFFFFu) : ~sk);
        float w = sel ? expf(vv - vmax) : 0.f;
        wArr[i] = w;
        lsum += w; lcnt += sel ? 1u : 0u;
    }
    redf[tid] = lsum; redu[tid] = lcnt;
    __syncthreads();
    for (int s = 128; s > 0; s >>= 1) {
        if (tid < s) { redf[tid] += redf[tid + s]; redu[tid] += redu[tid + s]; }
        __syncthreads();
    }
    const float invZ = 1.f / redf[0];
    const int selCount = (int)redu[0];

    for (int d = tid; d < DIM; d += 256) {
        float acc = 0.f;
        for (int i = 0; i < selCount; i++) {
            unsigned idx = (unsigned)(keys[i] & 0xFFFFFFFFu);
            acc += wArr[i] * codebook[(size_t)idx * DIM + d];
        }
        y[(size_t)row * DIM + d] = acc * invZ;
    }
}

// ---------------------------------------------------------------------------
extern "C" void kernel_launch(void* const* d_in, const int* in_sizes, int n_in,
                              void* d_out, int out_size, void* d_ws, size_t ws_size,
                              hipStream_t stream)
{
    const float* x        = (const float*)d_in[0];
    const float* codebook = (const float*)d_in[1];
    const float* Wq       = (const float*)d_in[2];
    const float* bq       = (const float*)d_in[3];
    const float* Wk       = (const float*)d_in[4];
    // d_in[5] = bk: per-row-constant shift in dots (top-k & softmax invariant)
    const float* Wv       = (const float*)d_in[6];
    const float* bv       = (const float*)d_in[7];
    float* out = (float*)d_out;

    // workspace (~72 MB)
    float* q2   = (float*)d_ws;                       // 4096x512   (8 MB)
    float* Wqk  = q2   + (size_t)BATCH * DIM;         // 512x512    (1 MB)
    float* bqk  = Wqk  + (size_t)DIM * DIM;           // 512 (pad 1024)
    float* y    = bqk  + 1024;                        // 4096x512   (8 MB)
    float* trow = y    + (size_t)BATCH * DIM;         // 4096
    float* sigr = trow + BATCH;                       // 4096
    unsigned* counters = (unsigned*)(sigr + BATCH);   // 4096
    unsigned* flags    = counters + BATCH;            // 4096
    float* cbarsum     = (float*)(flags + BATCH);     // 512
    unsigned* candBuf  = (unsigned*)(cbarsum + 512);  // 4096x512 (8 MB)
    u16* q2h = (u16*)(candBuf + (size_t)BATCH * CAND_CAP);   // 4 MB
    u16* cbh = q2h + (size_t)BATCH * DIM;                    // 32 MB
    u16* yh  = cbh + (size_t)VOC * DIM;                      // 4 MB
    u16* yl  = yh  + (size_t)BATCH * DIM;                    // 4 MB
    u16* wvh = yl  + (size_t)BATCH * DIM;                    // 0.5 MB
    u16* wvl = wvh + (size_t)DIM * DIM;                      // 0.5 MB

    // aliases (no workspace growth):
    //  - x hi/lo pack lives in yh/yl (dead after mfma_out(q2); rewritten by
    //    pack_rows(y) before mfma_out(out))
    //  - Wqk hi/lo pack lives in candBuf (candBuf not needed until mfma_dots)
    u16* xh   = yh;
    u16* xl   = yl;
    u16* wqkh = (u16*)candBuf;
    u16* wqkl = wqkh + (size_t)DIM * DIM;

    dim3 blk(256);

    // Wqk = Wq @ Wk^T (fp64-flush fold); prologue zeroes counters/flags/cbarsum
    gemm64<true, true><<<dim3(DIM / 64, DIM / 64), blk, 0, stream>>>(
        Wq, Wk, nullptr, Wqk, DIM, DIM, DIM, counters, BATCH * 2 + 512);

    // all independent prep in ONE launch: x-pack | Wqk-pack | cb-pack |
    // Wv-pack | cbar_accum | bias_fold
    fused_prep<<<dim3(9856), blk, 0, stream>>>(
        x, Wqk, codebook, Wv, bq, Wk,
        xh, xl, wqkh, wqkl, cbh, wvh, wvl, cbarsum, bqk);

    // q2 = x @ Wqk + bqk via hi/lo 3-pass MFMA (256 blocks)
    mfma_out<<<dim3(DIM / 64, BATCH / 128), blk, 0, stream>>>(
        xh, xl, wqkh, wqkl, bqk, q2, BATCH);

    // rowstats + q2-pack in one launch
    fused_q2post<<<dim3(2048), blk, 0, stream>>>(q2, cbarsum, trow, sigr, q2h);

    // fused dots GEMM (v13: 2-stage counted-vmcnt pipeline) + candidate append
    mfma_dots<<<dim3(8192), blk, 0, stream>>>(q2h, cbh, trow, candBuf, counters);

    // exact selection + softmax + y = attn @ codebook (prefetched rescue)
    select6<<<dim3(BATCH), blk, 0, stream>>>(
        candBuf, counters, trow, q2, codebook, y, flags);
    fallback_row<<<dim3(BATCH), blk, 0, stream>>>(
        flags, q2, codebook, trow, sigr, y);

    // out = y @ Wv + bv  (hi/lo 3-pass MFMA, 256 blocks)
    pack_rows<<<dim3(BATCH * 64 / 256), blk, 0, stream>>>(y, yh, yl, BATCH, 12);
    mfma_out<<<dim3(DIM / 64, BATCH / 128), blk, 0, stream>>>(
        yh, yl, wvh, wvl, bv, out, BATCH);
}

// Round 14
// 629.409 us; speedup vs baseline: 1.0600x; 1.0138x over previous
//
#include <hip/hip_runtime.h>
#include <cstdint>

#define VOC   32768
#define DIM   512
#define TOPK  64
#define BATCH 4096

#define KSIG     2.45f
#define EPS_SEL  0.012f
#define CAND_CAP 512
#define RES_CAP  256
#define FCAP     1024

typedef unsigned short u16;
typedef __attribute__((ext_vector_type(8))) short bf16x8;
typedef __attribute__((ext_vector_type(4))) float f32x4;

// ---- bf16 helpers (RNE) ----------------------------------------------------
__device__ __forceinline__ u16 f2bf(float f) {
    unsigned u = __float_as_uint(f);
    unsigned r = (u + 0x7FFFu + ((u >> 16) & 1u)) >> 16;
    return (u16)r;
}
__device__ __forceinline__ float bf2f(u16 h) {
    return __uint_as_float(((unsigned)h) << 16);
}
__device__ __forceinline__ unsigned enc16(u16 h) {
    return (h & 0x8000u) ? (unsigned)((u16)~h) : (unsigned)(h | 0x8000u);
}
__device__ __forceinline__ float dec16(unsigned s16) {
    u16 h = (s16 & 0x8000u) ? (u16)(s16 ^ 0x8000u) : (u16)(~s16);
    return bf2f(h);
}

// ---- async global->LDS 16B -------------------------------------------------
__device__ __forceinline__ void async16(const void* g, void* l) {
    __builtin_amdgcn_global_load_lds(
        (const __attribute__((address_space(1))) void*)g,
        (__attribute__((address_space(3))) void*)l, 16, 0, 0);
}

// ---------------------------------------------------------------------------
// fp32 64x64-tile GEMM + optional per-k-tile fp64 flush. 256 thr, 4x4 micro.
// Retained ONLY for the precision-critical fold Wqk = Wq @ Wk^T. Prologue
// also zeroes the counters/flags/cbarsum words (fold of the old zero_ws
// launch).
// ---------------------------------------------------------------------------
template <bool BT, bool F64ACC>
__global__ __launch_bounds__(256)
void gemm64(const float* __restrict__ A, const float* __restrict__ B,
            const float* __restrict__ bias, float* __restrict__ C,
            int M, int N, int K, unsigned* __restrict__ zeroP, int zeroN)
{
    const int KS = 16;
    __shared__ float As[KS][68];
    __shared__ float Bs[KS][64];

    const int tid = threadIdx.x;
    if (zeroP) {
        int zi = (blockIdx.y * gridDim.x + blockIdx.x) * 256 + tid;
        if (zi < zeroN) zeroP[zi] = 0u;
    }

    const int m0 = blockIdx.y * 64;
    const int n0 = blockIdx.x * 64;
    const int ty = tid >> 4;
    const int tx = tid & 15;

    float acc[4][4];
    double acc64[4][4];
#pragma unroll
    for (int i = 0; i < 4; i++)
#pragma unroll
        for (int j = 0; j < 4; j++) { acc[i][j] = 0.f; if (F64ACC) acc64[i][j] = 0.0; }

    for (int kt = 0; kt < K; kt += KS) {
        {
            int row = tid >> 2, kq = tid & 3;
            const float4 av = *(const float4*)(A + (size_t)(m0 + row) * K + kt + kq * 4);
            As[kq * 4 + 0][row] = av.x;
            As[kq * 4 + 1][row] = av.y;
            As[kq * 4 + 2][row] = av.z;
            As[kq * 4 + 3][row] = av.w;
        }
        if (!BT) {
            int krow = tid >> 4, nq = tid & 15;
            *(float4*)&Bs[krow][nq * 4] =
                *(const float4*)(B + (size_t)(kt + krow) * N + n0 + nq * 4);
        } else {
            int nrow = tid >> 2, kq = tid & 3;
            const float4 bv = *(const float4*)(B + (size_t)(n0 + nrow) * K + kt + kq * 4);
            Bs[kq * 4 + 0][nrow] = bv.x;
            Bs[kq * 4 + 1][nrow] = bv.y;
            Bs[kq * 4 + 2][nrow] = bv.z;
            Bs[kq * 4 + 3][nrow] = bv.w;
        }
        __syncthreads();

#pragma unroll
        for (int kk = 0; kk < KS; kk++) {
            float4 a = *(const float4*)&As[kk][ty * 4];
            float4 b = *(const float4*)&Bs[kk][tx * 4];
            float av[4] = {a.x, a.y, a.z, a.w};
            float bv[4] = {b.x, b.y, b.z, b.w};
#pragma unroll
            for (int i = 0; i < 4; i++)
#pragma unroll
                for (int j = 0; j < 4; j++)
                    acc[i][j] += av[i] * bv[j];
        }
        __syncthreads();
        if (F64ACC) {
#pragma unroll
            for (int i = 0; i < 4; i++)
#pragma unroll
                for (int j = 0; j < 4; j++) { acc64[i][j] += (double)acc[i][j]; acc[i][j] = 0.f; }
        }
    }

    float4 bb = make_float4(0.f, 0.f, 0.f, 0.f);
    if (bias) bb = *(const float4*)(bias + n0 + tx * 4);
#pragma unroll
    for (int i = 0; i < 4; i++) {
        float4 o;
        o.x = (F64ACC ? (float)acc64[i][0] : acc[i][0]) + bb.x;
        o.y = (F64ACC ? (float)acc64[i][1] : acc[i][1]) + bb.y;
        o.z = (F64ACC ? (float)acc64[i][2] : acc[i][2]) + bb.z;
        o.w = (F64ACC ? (float)acc64[i][3] : acc[i][3]) + bb.w;
        *(float4*)(C + (size_t)(m0 + ty * 4 + i) * N + n0 + tx * 4) = o;
    }
}

// ---------------------------------------------------------------------------
// Device bodies for the fused prep kernels (virtual block id passed in).
// ---------------------------------------------------------------------------
__device__ __forceinline__ void pack_rows_dev(int bid, int tid,
        const float* __restrict__ src, u16* __restrict__ hi,
        u16* __restrict__ lo, int R, int log2R)
{
    int idx = bid * 256 + tid;
    int c8  = idx >> log2R;
    int row = idx & (R - 1);
    const float* sp = src + (size_t)row * DIM + c8 * 8;
    float xv[8];
    *(float4*)&xv[0] = *(const float4*)sp;
    *(float4*)&xv[4] = *(const float4*)(sp + 4);
    int ks = c8 >> 2, ch = c8 & 3;
    size_t ob = ((size_t)(ks * 4 + ch) * R + row) * 8;
    u16 h[8], l[8];
#pragma unroll
    for (int j = 0; j < 8; j++) {
        h[j] = f2bf(xv[j]);
        l[j] = f2bf(xv[j] - bf2f(h[j]));
    }
    *(uint4*)(hi + ob) = *(const uint4*)h;
    if (lo) *(uint4*)(lo + ob) = *(const uint4*)l;
}

// Coalesced codebook pack via LDS transpose (r13 analysis: the old per-c8
// scheme read 32B/lane at 2KB stride -> 64MB codebook fetched as ~128MB of
// half-used lines, no cross-block line reuse. Here: block owns 16 rows x
// 512 cols = 32KB CONTIGUOUS; phase 1 reads perfectly coalesced float4s,
// converts, stages bf16 in 16KB LDS; phase 2 writes the identical
// [c8][row][8] planes in 64B-contiguous chunks. Per-element conversion and
// output layout unchanged -> bit-identical. 16KB LDS keeps fused_prep
// wave-capped (10 >= 8 blocks/CU): zero occupancy cost.
__device__ __forceinline__ void cbpack_dev(int bid, int tid,
        const float* __restrict__ cb, u16* __restrict__ hi, u16* sld)
{
    const int r0 = bid * 16;
    const float* base = cb + (size_t)r0 * DIM;
    // phase 1: 2048 float4s linear over the 16x512 tile, coalesced
#pragma unroll
    for (int it = 0; it < 8; it++) {
        int f = it * 256 + tid;                // float4 index
        float4 v = *(const float4*)(base + (size_t)f * 4);
        int e = f * 4;                         // element index
        u16* d = &sld[e];                      // sld is [16][512] row-major
        d[0] = f2bf(v.x); d[1] = f2bf(v.y); d[2] = f2bf(v.z); d[3] = f2bf(v.w);
    }
    __syncthreads();
    // phase 2: thread t -> plane c8 = t>>2, rows (t&3)*4 + k (k=0..3)
    const int c8 = tid >> 2;
    const int rb = (tid & 3) * 4;
#pragma unroll
    for (int k = 0; k < 4; k++) {
        int r = rb + k;
        uint4 w = *(const uint4*)&sld[r * DIM + c8 * 8];
        *(uint4*)(hi + ((size_t)c8 * VOC + r0 + r) * 8) = w;
    }
}

__device__ __forceinline__ void pack_bT_dev(int bid, int tid,
        const float* __restrict__ W, u16* __restrict__ hi, u16* __restrict__ lo)
{
    int idx = bid * 256 + tid;
    int n  = idx & (DIM - 1);
    int c8 = idx >> 9;
    int ks = c8 >> 2, ch = c8 & 3;
    size_t ob = ((size_t)(ks * 4 + ch) * DIM + n) * 8;
    u16 h[8], l[8];
#pragma unroll
    for (int j = 0; j < 8; j++) {
        float x = W[(size_t)(c8 * 8 + j) * DIM + n];
        h[j] = f2bf(x);
        l[j] = f2bf(x - bf2f(h[j]));
    }
    *(uint4*)(hi + ob) = *(const uint4*)h;
    *(uint4*)(lo + ob) = *(const uint4*)l;
}

__device__ __forceinline__ void cbar_dev(int bid, int tid,
        const float* __restrict__ cb, float* __restrict__ cbarsum)
{
    const int r0 = bid * 128;
    float s0 = 0.f, s1 = 0.f;
    for (int r = 0; r < 128; r++) {
        const float* rp = cb + (size_t)(r0 + r) * DIM;
        s0 += rp[tid];
        s1 += rp[tid + 256];
    }
    atomicAdd(&cbarsum[tid], s0);
    atomicAdd(&cbarsum[tid + 256], s1);
}

__device__ __forceinline__ void bias_fold_dev(int bid, int tid,
        const float* __restrict__ bq, const float* __restrict__ Wk,
        float* __restrict__ bqk)
{
    const int lane = tid & 63, wave = tid >> 6;
    const int j = bid * 4 + wave;
    const float* wr = Wk + (size_t)j * DIM + lane * 8;
    const float* bp = bq + lane * 8;
    double s = 0.0;
#pragma unroll
    for (int t = 0; t < 8; t++) s += (double)bp[t] * (double)wr[t];
#pragma unroll
    for (int off = 32; off > 0; off >>= 1) s += __shfl_down(s, off);
    if (lane == 0) bqk[j] = (float)s;
}

__device__ __forceinline__ void rowstats_dev(int bid, int tid,
        const float* __restrict__ q2, const float* __restrict__ cbarsum,
        float* __restrict__ trow, float* __restrict__ sigrow)
{
    const int lane = tid & 63, wave = tid >> 6;
    const int row = bid * 4 + wave;
    const float* qp = q2 + (size_t)row * DIM + lane * 8;
    float4 a0 = *(const float4*)qp, a1 = *(const float4*)(qp + 4);
    const float* cp = cbarsum + lane * 8;
    float4 c0 = *(const float4*)cp, c1 = *(const float4*)(cp + 4);
    float mu = a0.x*c0.x + a0.y*c0.y + a0.z*c0.z + a0.w*c0.w
             + a1.x*c1.x + a1.y*c1.y + a1.z*c1.z + a1.w*c1.w;
    float nr = a0.x*a0.x + a0.y*a0.y + a0.z*a0.z + a0.w*a0.w
             + a1.x*a1.x + a1.y*a1.y + a1.z*a1.z + a1.w*a1.w;
#pragma unroll
    for (int off = 32; off > 0; off >>= 1) {
        mu += __shfl_down(mu, off);
        nr += __shfl_down(nr, off);
    }
    if (lane == 0) {
        mu *= (1.f / VOC);
        float sig = sqrtf(nr * (1.f / 1536.f));
        trow[row] = mu + KSIG * sig;
        sigrow[row] = sig;
    }
}

// ---------------------------------------------------------------------------
// fused_prep: all pre-dots prep that only depends on {inputs, Wqk, zeroed ws}.
// Block ranges: [0,1024) x-pack hi/lo | [1024,1152) Wqk-bT | [1152,3200)
// cb-pack-coalesced (2048 blk x 16 rows) | [3200,3328) Wv-bT | [3328,3584)
// cbar_accum | [3584,3712) bias_fold
// ---------------------------------------------------------------------------
__global__ __launch_bounds__(256)
void fused_prep(const float* __restrict__ x, const float* __restrict__ Wqk,
                const float* __restrict__ codebook, const float* __restrict__ Wv,
                const float* __restrict__ bq, const float* __restrict__ Wk,
                u16* __restrict__ xh, u16* __restrict__ xl,
                u16* __restrict__ wqkh, u16* __restrict__ wqkl,
                u16* __restrict__ cbh, u16* __restrict__ wvh,
                u16* __restrict__ wvl, float* __restrict__ cbarsum,
                float* __restrict__ bqk)
{
    __shared__ u16 sld[16 * DIM];   // 16 KB (cb-pack transpose staging)
    const int b = blockIdx.x, tid = threadIdx.x;
    if (b < 1024)       pack_rows_dev(b, tid, x, xh, xl, BATCH, 12);
    else if (b < 1152)  pack_bT_dev(b - 1024, tid, Wqk, wqkh, wqkl);
    else if (b < 3200)  cbpack_dev(b - 1152, tid, codebook, cbh, sld);
    else if (b < 3328)  pack_bT_dev(b - 3200, tid, Wv, wvh, wvl);
    else if (b < 3584)  cbar_dev(b - 3328, tid, codebook, cbarsum);
    else                bias_fold_dev(b - 3584, tid, bq, Wk, bqk);
}

// fused_q2post: rowstats + q2-pack (both read q2). [0,1024) | [1024,2048)
__global__ __launch_bounds__(256)
void fused_q2post(const float* __restrict__ q2, const float* __restrict__ cbarsum,
                  float* __restrict__ trow, float* __restrict__ sigrow,
                  u16* __restrict__ q2h)
{
    const int b = blockIdx.x, tid = threadIdx.x;
    if (b < 1024) rowstats_dev(b, tid, q2, cbarsum, trow, sigrow);
    else          pack_rows_dev(b - 1024, tid, q2, q2h, nullptr, BATCH, 12);
}

// standalone pack_rows: used for y AFTER select/fallback. Coalesced enough
// (r11 lesson: do NOT fuse into select6 -> 64KB-strided scatters, +15us).
__global__ __launch_bounds__(256)
void pack_rows(const float* __restrict__ src, u16* __restrict__ hi,
               u16* __restrict__ lo, int R, int log2R)
{
    pack_rows_dev(blockIdx.x, threadIdx.x, src, hi, lo, R, log2R);
}

// ---------------------------------------------------------------------------
// Fused dots GEMM v13 (best measured, 233-240us): 128x128, 4 waves, acc[4][4]
// = 64 AGPR, 32KB LDS 2-stage, (256,4) -> 16 waves/CU = register-file
// roofline. Counted-vmcnt pipeline: per step s:
//   wait vmcnt(4) -> barrier A -> 4 ds_read A + 3x(ds_read B + 4 MFMA) + B3
//   -> lgkmcnt(0) + barrier B -> ISSUE(s+2) into just-freed buffer -> 4 MFMA.
// ---------------------------------------------------------------------------
__global__ __launch_bounds__(256, 4)
void mfma_dots(const u16* __restrict__ Ah, const u16* __restrict__ Bh,
               const float* __restrict__ trow, unsigned* __restrict__ candBuf,
               unsigned* __restrict__ counters)
{
    __shared__ u16 lds[2 * 8192];      // 2 stages x (A 4096 + B 4096) u16 = 32 KB

    const int tid  = threadIdx.x;
    const int lane = tid & 63;
    const int wave = tid >> 6;
    const int wm = wave >> 1, wn = wave & 1;
    const int lr = lane & 15;
    const int q  = lane >> 4;

    // XCD-affinity: xcd owns a 4-m-tile band; within XCD, m fastest then n.
    const int L   = blockIdx.x;
    const int xcd = L & 7;
    const int j   = L >> 3;                    // 0..1023
    const int m0  = (xcd * 4 + (j & 3)) * 128;
    const int n0  = (j >> 2) * 128;

    const int a  = wave >> 1;                  // 0: stage A (q2h), 1: stage B (cbh)
    const u16* src = a ? Bh : Ah;
    const int rb   = a ? n0 : m0;
    const size_t R = a ? (size_t)VOC : (size_t)BATCH;
    const int i0   = (wave & 1) * 4;

    // strength-reduced staging pointers: gpX walks ks=0..15 by const stride
    const size_t gstep = (size_t)4 * R * 8;    // u16 elems per ks-step
    const u16* gp0 = src + ((size_t)(((i0 + 0) >> 1)) * R + rb + ((i0 + 0) & 1) * 64 + lane) * 8;
    const u16* gp1 = src + ((size_t)(((i0 + 1) >> 1)) * R + rb + ((i0 + 1) & 1) * 64 + lane) * 8;
    const u16* gp2 = src + ((size_t)(((i0 + 2) >> 1)) * R + rb + ((i0 + 2) & 1) * 64 + lane) * 8;
    const u16* gp3 = src + ((size_t)(((i0 + 3) >> 1)) * R + rb + ((i0 + 3) & 1) * 64 + lane) * 8;
    const int loff0 = a * 4096 + (i0 + 0) * 512 + lane * 8;
    const int loff1 = a * 4096 + (i0 + 1) * 512 + lane * 8;
    const int loff2 = a * 4096 + (i0 + 2) * 512 + lane * 8;
    const int loff3 = a * 4096 + (i0 + 3) * 512 + lane * 8;

#define ISSUE(b)                                                              \
    {                                                                         \
        async16(gp0, &lds[(b) * 8192 + loff0]); gp0 += gstep;                 \
        async16(gp1, &lds[(b) * 8192 + loff1]); gp1 += gstep;                 \
        async16(gp2, &lds[(b) * 8192 + loff2]); gp2 += gstep;                 \
        async16(gp3, &lds[(b) * 8192 + loff3]); gp3 += gstep;                 \
    }

    f32x4 acc[4][4] = {};

    // prologue: tiles 0 and 1 in flight (8 loads/thread); ptrs now at ks=2
    ISSUE(0)
    ISSUE(1)

    for (int s = 0; s < 16; s++) {
        if (s < 15) __builtin_amdgcn_s_waitcnt(0x0F74);   // vmcnt(4): stage s landed
        else        __builtin_amdgcn_s_waitcnt(0x0F70);   // vmcnt(0): last stage
        __builtin_amdgcn_s_barrier();                     // A: staging published
        const u16* base = &lds[(s & 1) * 8192];

        bf16x8 ah[4];
#pragma unroll
        for (int mt = 0; mt < 4; mt++)
            ah[mt] = *(const bf16x8*)&base[q * 1024 + (wm * 64 + mt * 16 + lr) * 8];

        __builtin_amdgcn_s_setprio(1);
#pragma unroll
        for (int nt = 0; nt < 3; nt++) {
            bf16x8 bh = *(const bf16x8*)&base[4096 + q * 1024 + (wn * 64 + nt * 16 + lr) * 8];
#pragma unroll
            for (int mt = 0; mt < 4; mt++)
                acc[mt][nt] = __builtin_amdgcn_mfma_f32_16x16x32_bf16(ah[mt], bh, acc[mt][nt], 0, 0, 0);
        }
        bf16x8 bh3 = *(const bf16x8*)&base[4096 + q * 1024 + (wn * 64 + 3 * 16 + lr) * 8];
        __builtin_amdgcn_s_setprio(0);

        __builtin_amdgcn_s_waitcnt(0xC07F);    // lgkmcnt(0): this wave's 8 reads done
        __builtin_amdgcn_s_barrier();          // B: ALL waves done reading buf[s&1]
        __builtin_amdgcn_sched_barrier(0);
        if (s < 14) ISSUE(s & 1)               // stage s+2 into just-freed buffer

        __builtin_amdgcn_s_setprio(1);
#pragma unroll
        for (int mt = 0; mt < 4; mt++)
            acc[mt][3] = __builtin_amdgcn_mfma_f32_16x16x32_bf16(ah[mt], bh3, acc[mt][3], 0, 0, 0);
        __builtin_amdgcn_s_setprio(0);
    }
#undef ISSUE

    // epilogue: threshold-append candidates
#pragma unroll
    for (int mt = 0; mt < 4; mt++) {
#pragma unroll
        for (int r = 0; r < 4; r++) {
            int rowg = m0 + wm * 64 + mt * 16 + q * 4 + r;
            float tr = trow[rowg];
#pragma unroll
            for (int nt = 0; nt < 4; nt++) {
                float val = acc[mt][nt][r];
                if (val >= tr) {
                    unsigned slot = atomicAdd(&counters[rowg], 1u);
                    if (slot < CAND_CAP) {
                        unsigned s16 = enc16(f2bf(val));
                        candBuf[(size_t)rowg * CAND_CAP + slot] =
                            (s16 << 16) | (unsigned)(n0 + wn * 64 + nt * 16 + lr);
                    }
                }
            }
        }
    }
}

// ---------------------------------------------------------------------------
// out = A @ W + bias in bf16 hi/lo 3-pass MFMA (error ~1e-6). Regrid (r8,
// bit-identical): tile 128m x 64n, grid 256 blocks, acc[4][2]=32 AGPR,
// LDS 48 KB -> 3 blocks/CU. Used for q2 = x@Wqk + bqk and out = y@Wv + bv.
// ---------------------------------------------------------------------------
__global__ __launch_bounds__(256, 3)
void mfma_out(const u16* __restrict__ Ah, const u16* __restrict__ Al,
              const u16* __restrict__ Bh, const u16* __restrict__ Bl,
              const float* __restrict__ bias, float* __restrict__ Cout, int Ma)
{
    __shared__ u16 lds[2 * 12288];   // 2 stages x 24 KB

    const int tid  = threadIdx.x;
    const int lane = tid & 63;
    const int wave = tid >> 6;
    const int wm = wave >> 1, wn = wave & 1;
    const int m0 = blockIdx.y * 128, n0 = blockIdx.x * 64;
    const int lr = lane & 15;
    const int q  = lane >> 4;
    const size_t R = (size_t)Ma;

    f32x4 acc[4][2] = {};

#define VISSUE(ks, b)                                                          \
    {                                                                          \
        _Pragma("unroll")                                                      \
        for (int i_ = 0; i_ < 2; i_++) {                                       \
            int u_ = tid + i_ * 256;                                           \
            size_t ai_ = ((size_t)((ks) * 4 + (u_ >> 7)) * R + m0 + (u_ & 127)) * 8; \
            async16(Ah + ai_, &lds[(b) * 12288 + u_ * 8]);                     \
            async16(Al + ai_, &lds[(b) * 12288 + 6144 + u_ * 8]);              \
        }                                                                      \
        {                                                                      \
            int u_ = tid;                                                      \
            size_t bi_ = ((size_t)((ks) * 4 + (u_ >> 6)) * DIM + n0 + (u_ & 63)) * 8; \
            async16(Bh + bi_, &lds[(b) * 12288 + 4096 + u_ * 8]);              \
            async16(Bl + bi_, &lds[(b) * 12288 + 10240 + u_ * 8]);             \
        }                                                                      \
    }

    VISSUE(0, 0)

    for (int ks = 0; ks < 16; ks++) {
        __syncthreads();                       // drains vmcnt(0): stage ks in LDS
        if (ks < 15) VISSUE(ks + 1, (ks + 1) & 1)
        const u16* base = &lds[(ks & 1) * 12288];

        bf16x8 ah[4], al[4];
#pragma unroll
        for (int mt = 0; mt < 4; mt++) {
            int row = wm * 64 + mt * 16 + lr;
            ah[mt] = *(const bf16x8*)&base[q * 1024 + row * 8];
            al[mt] = *(const bf16x8*)&base[6144 + q * 1024 + row * 8];
        }
#pragma unroll
        for (int nt = 0; nt < 2; nt++) {
            int col = wn * 32 + nt * 16 + lr;
            bf16x8 bh = *(const bf16x8*)&base[4096 + q * 512 + col * 8];
            bf16x8 bl = *(const bf16x8*)&base[10240 + q * 512 + col * 8];
#pragma unroll
            for (int mt = 0; mt < 4; mt++) {
                acc[mt][nt] = __builtin_amdgcn_mfma_f32_16x16x32_bf16(ah[mt], bh, acc[mt][nt], 0, 0, 0);
                acc[mt][nt] = __builtin_amdgcn_mfma_f32_16x16x32_bf16(ah[mt], bl, acc[mt][nt], 0, 0, 0);
                acc[mt][nt] = __builtin_amdgcn_mfma_f32_16x16x32_bf16(al[mt], bh, acc[mt][nt], 0, 0, 0);
            }
        }
    }
#undef VISSUE

#pragma unroll
    for (int mt = 0; mt < 4; mt++)
#pragma unroll
        for (int nt = 0; nt < 2; nt++) {
            int col = n0 + wn * 32 + nt * 16 + lr;
            float bb = bias[col];
#pragma unroll
            for (int r = 0; r < 4; r++) {
                int rowg = m0 + wm * 64 + mt * 16 + q * 4 + r;
                Cout[(size_t)rowg * DIM + col] = acc[mt][nt][r] + bb;
            }
        }
}

// ---------------------------------------------------------------------------
// Select v10 (r13 form): histogram selection -> band-compaction -> fp64
// rescue with 2-deep prefetch -> exact u64 sort -> softmax -> y_row
// (single-pass dual accumulators).
// ---------------------------------------------------------------------------
__global__ __launch_bounds__(256)
void select6(const unsigned* __restrict__ candBuf, const unsigned* __restrict__ counters,
             const float* __restrict__ trow, const float* __restrict__ q2,
             const float* __restrict__ codebook, float* __restrict__ y,
             unsigned* __restrict__ flags)
{
    __shared__ unsigned recs[CAND_CAP];
    __shared__ unsigned list[RES_CAP];
    __shared__ unsigned hist[256];
    __shared__ unsigned long long keys[RES_CAP];
    __shared__ float q2s[DIM];
    __shared__ float wArr[RES_CAP];
    __shared__ float redf[256];
    __shared__ unsigned redu[256];
    __shared__ unsigned s_R;
    __shared__ unsigned s_b1, s_rem, s_thr;

    const int tid  = threadIdx.x;
    const int lane = tid & 63;
    const int wave = tid >> 6;
    const int row  = blockIdx.x;

    const unsigned cnt = counters[row];
    if (cnt < TOPK || cnt > CAND_CAP) {
        if (tid == 0) flags[row] = 1u;
        return;
    }
    for (int i = tid; i < DIM; i += 256) q2s[i] = q2[(size_t)row * DIM + i];
    for (int i = tid; i < CAND_CAP; i += 256)
        recs[i] = (i < (int)cnt) ? candBuf[(size_t)row * CAND_CAP + i] : 0u;
    if (tid == 0) s_R = 0;
    hist[tid] = 0;
    __syncthreads();

    // pass 1: histogram of top byte of s16 (monotone: larger s16 = larger val)
#pragma unroll
    for (int e = 0; e < 2; e++) {
        int i = tid + e * 256;
        if (i < (int)cnt) atomicAdd(&hist[recs[i] >> 24], 1u);
    }
    __syncthreads();
    if (tid == 0) {
        unsigned c = 0; int b = 255;
        for (; b > 0; b--) {
            unsigned h = hist[b];
            if (c + h >= TOPK) break;
            c += h;
        }
        s_b1 = (unsigned)b; s_rem = TOPK - c;
    }
    __syncthreads();
    const unsigned b1 = s_b1, rem = s_rem;
    hist[tid] = 0;
    __syncthreads();

    // pass 2: low byte among records with top byte == b1
#pragma unroll
    for (int e = 0; e < 2; e++) {
        int i = tid + e * 256;
        if (i < (int)cnt && (recs[i] >> 24) == b1)
            atomicAdd(&hist[(recs[i] >> 16) & 0xFFu], 1u);
    }
    __syncthreads();
    if (tid == 0) {
        unsigned c = 0; int b = 255;
        for (; b > 0; b--) {
            unsigned h = hist[b];
            if (c + h >= rem) break;
            c += h;
        }
        s_thr = (b1 << 8) | (unsigned)b;       // s16 of 64th-largest record
    }
    __syncthreads();

    const float a64  = dec16(s_thr);
    const float band = a64 - 2.f * EPS_SEL;
    if (trow[row] > band) {
        if (tid == 0) flags[row] = 1u;
        return;
    }

    // band-compaction (unordered; exact sort later restores determinism)
#pragma unroll
    for (int e = 0; e < 2; e++) {
        int i = tid + e * 256;
        if (i < (int)cnt && dec16(recs[i] >> 16) >= band) {
            unsigned p = atomicAdd(&s_R, 1u);
            if (p < RES_CAP) list[p] = recs[i];
        }
    }
    __syncthreads();
    const int R = (int)s_R;
    if (R > RES_CAP) {
        if (tid == 0) flags[row] = 1u;
        return;
    }

    // fp64 rescue: wave per candidate, 2-deep prefetch
    {
        const float* qp = &q2s[lane * 8];
        float4 a0 = *(const float4*)qp, a1 = *(const float4*)(qp + 4);
        unsigned nIdx = 0;
        float4 p0 = make_float4(0.f, 0.f, 0.f, 0.f), p1 = p0;
        if (wave < R) {
            nIdx = list[wave] & 0xFFFFu;
            const float* cb = codebook + (size_t)nIdx * DIM + lane * 8;
            p0 = *(const float4*)cb; p1 = *(const float4*)(cb + 4);
        }
        for (int c = wave; c < R; c += 4) {
            const unsigned uIdx = nIdx;
            const float4 u0 = p0, u1 = p1;
            if (c + 4 < R) {
                nIdx = list[c + 4] & 0xFFFFu;
                const float* cb = codebook + (size_t)nIdx * DIM + lane * 8;
                p0 = *(const float4*)cb; p1 = *(const float4*)(cb + 4);
            }
            double s = (double)a0.x * u0.x + (double)a0.y * u0.y
                     + (double)a0.z * u0.z + (double)a0.w * u0.w
                     + (double)a1.x * u1.x + (double)a1.y * u1.y
                     + (double)a1.z * u1.z + (double)a1.w * u1.w;
#pragma unroll
            for (int off = 32; off > 0; off >>= 1) s += __shfl_down(s, off);
            if (lane == 0) {
                float val = (float)s;
                unsigned b = __float_as_uint(val);
                unsigned sk = (b & 0x80000000u) ? ~b : (b | 0x80000000u);
                keys[c] = ((unsigned long long)(~sk) << 32) | uIdx;
            }
        }
    }
    if (tid >= R && tid < RES_CAP) keys[tid] = ~0ULL;
    __syncthreads();

    // bitonic sort 256 u64 ascending (= descending by exact value)
    for (int k = 2; k <= RES_CAP; k <<= 1) {
        for (int j = k >> 1; j > 0; j >>= 1) {
            int ixj = tid ^ j;
            if (ixj > tid) {
                unsigned long long a = keys[tid], b2 = keys[ixj];
                if (((tid & k) == 0) ? (a > b2) : (a < b2)) { keys[tid] = b2; keys[ixj] = a; }
            }
            __syncthreads();
        }
    }

    const unsigned threshInv = (unsigned)(keys[TOPK - 1] >> 32);
    unsigned sk0 = ~(unsigned)(keys[0] >> 32);
    const float vmax = __uint_as_float((sk0 & 0x80000000u) ? (sk0 & 0x7FFFFFFFu) : ~sk0);

    unsigned hi = (unsigned)(keys[tid] >> 32);
    bool sel = (hi <= threshInv);
    unsigned sk = ~hi;
    float val = __uint_as_float((sk & 0x80000000u) ? (sk & 0x7FFFFFFFu) : ~sk);
    float w = sel ? expf(val - vmax) : 0.f;
    wArr[tid] = w;
    redf[tid] = w;
    redu[tid] = sel ? 1u : 0u;
    __syncthreads();
    for (int s = 128; s > 0; s >>= 1) {
        if (tid < s) { redf[tid] += redf[tid + s]; redu[tid] += redu[tid + s]; }
        __syncthreads();
    }
    const float invZ = 1.0f / redf[0];
    const int selCount = (int)redu[0];

    // y_row: single pass, dual accumulators (d=tid and d=tid+256)
    {
        float acc0 = 0.f, acc1 = 0.f;
        const int d0 = tid, d1 = tid + 256;
        for (int i = 0; i < selCount; i++) {
            unsigned idx = (unsigned)(keys[i] & 0xFFFFFFFFu);
            float w2 = wArr[i];
            const float* cb = codebook + (size_t)idx * DIM;
            acc0 += w2 * cb[d0];
            acc1 += w2 * cb[d1];
        }
        y[(size_t)row * DIM + d0] = acc0 * invZ;
        y[(size_t)row * DIM + d1] = acc1 * invZ;
    }
}

// ---------------------------------------------------------------------------
// Exact fallback for flagged rows (expected: ~none). fp64 scan over all VOC.
// ---------------------------------------------------------------------------
__global__ __launch_bounds__(256)
void fallback_row(const unsigned* __restrict__ flags, const float* __restrict__ q2,
                  const float* __restrict__ codebook, const float* __restrict__ trow,
                  const float* __restrict__ sigrow, float* __restrict__ y)
{
    const int row = blockIdx.x;
    if (!flags[row]) return;

    __shared__ float q2s[DIM];
    __shared__ unsigned long long keys[FCAP];
    __shared__ float wArr[FCAP];
    __shared__ float redf[256];
    __shared__ unsigned redu[256];
    __shared__ unsigned s_cnt;

    const int tid = threadIdx.x;
    for (int i = tid; i < DIM; i += 256) q2s[i] = q2[(size_t)row * DIM + i];
    const float sig = sigrow[row];
    float tf = trow[row] - 0.35f * sig;
    unsigned cnt = 0;

    for (int it = 0; it < 16; it++) {
        if (tid == 0) s_cnt = 0;
        __syncthreads();
        for (int i = tid; i < VOC; i += 256) {
            const float* cb = codebook + (size_t)i * DIM;
            double s = 0.0;
            for (int d = 0; d < DIM; d += 4) {
                float4 c4 = *(const float4*)(cb + d);
                s += (double)q2s[d + 0] * (double)c4.x + (double)q2s[d + 1] * (double)c4.y
                   + (double)q2s[d + 2] * (double)c4.z + (double)q2s[d + 3] * (double)c4.w;
            }
            float vv = (float)s;
            if (vv >= tf) {
                unsigned p = atomicAdd(&s_cnt, 1u);
                if (p < FCAP) {
                    unsigned b = __float_as_uint(vv);
                    unsigned sk = (b & 0x80000000u) ? ~b : (b | 0x80000000u);
                    keys[p] = ((unsigned long long)(~sk) << 32) | (unsigned)i;
                }
            }
        }
        __syncthreads();
        cnt = s_cnt;
        if (cnt > FCAP) { tf += 0.15f * sig; continue; }
        if (cnt < TOPK) { tf -= 0.35f * sig; continue; }
        break;
    }
    if (cnt > FCAP) cnt = FCAP;
    for (int i = tid; i < FCAP; i += 256)
        if (i >= (int)cnt) keys[i] = ~0ULL;
    __syncthreads();

    for (int k = 2; k <= FCAP; k <<= 1) {
        for (int j = k >> 1; j > 0; j >>= 1) {
#pragma unroll
            for (int e = 0; e < 4; e++) {
                int i = tid + e * 256;
                int ixj = i ^ j;
                if (ixj > i) {
                    unsigned long long a = keys[i], b = keys[ixj];
                    if (((i & k) == 0) ? (a > b) : (a < b)) { keys[i] = b; keys[ixj] = a; }
                }
            }
            __syncthreads();
        }
    }

    const unsigned threshInv = (unsigned)(keys[TOPK - 1] >> 32);
    unsigned sk0 = ~(unsigned)(keys[0] >> 32);
    const float vmax = __uint_as_float((sk0 & 0x80000000u) ? (sk0 & 0x7FFFFFFFu) : ~sk0);

    float lsum = 0.f; unsigned lcnt = 0;
    for (int i = tid; i < FCAP; i += 256) {
        unsigned hi = (unsigned)(keys[i] >> 32);
        bool sel = (hi <= threshInv);
        unsigned sk = ~hi;
        float vv = __uint_as_float((sk & 0x80000000u) ? (sk & 0x7FFFFFFFu) : ~sk);
        float w = sel ? expf(vv - vmax) : 0.f;
        wArr[i] = w;
        lsum += w; lcnt += sel ? 1u : 0u;
    }
    redf[tid] = lsum; redu[tid] = lcnt;
    __syncthreads();
    for (int s = 128; s > 0; s >>= 1) {
        if (tid < s) { redf[tid] += redf[tid + s]; redu[tid] += redu[tid + s]; }
        __syncthreads();
    }
    const float invZ = 1.f / redf[0];
    const int selCount = (int)redu[0];

    for (int d = tid; d < DIM; d += 256) {
        float acc = 0.f;
        for (int i = 0; i < selCount; i++) {
            unsigned idx = (unsigned)(keys[i] & 0xFFFFFFFFu);
            acc += wArr[i] * codebook[(size_t)idx * DIM + d];
        }
        y[(size_t)row * DIM + d] = acc * invZ;
    }
}

// ---------------------------------------------------------------------------
extern "C" void kernel_launch(void* const* d_in, const int* in_sizes, int n_in,
                              void* d_out, int out_size, void* d_ws, size_t ws_size,
                              hipStream_t stream)
{
    const float* x        = (const float*)d_in[0];
    const float* codebook = (const float*)d_in[1];
    const float* Wq       = (const float*)d_in[2];
    const float* bq       = (const float*)d_in[3];
    const float* Wk       = (const float*)d_in[4];
    // d_in[5] = bk: per-row-constant shift in dots (top-k & softmax invariant)
    const float* Wv       = (const float*)d_in[6];
    const float* bv       = (const float*)d_in[7];
    float* out = (float*)d_out;

    // workspace (~72 MB)
    float* q2   = (float*)d_ws;                       // 4096x512   (8 MB)
    float* Wqk  = q2   + (size_t)BATCH * DIM;         // 512x512    (1 MB)
    float* bqk  = Wqk  + (size_t)DIM * DIM;           // 512 (pad 1024)
    float* y    = bqk  + 1024;                        // 4096x512   (8 MB)
    float* trow = y    + (size_t)BATCH * DIM;         // 4096
    float* sigr = trow + BATCH;                       // 4096
    unsigned* counters = (unsigned*)(sigr + BATCH);   // 4096
    unsigned* flags    = counters + BATCH;            // 4096
    float* cbarsum     = (float*)(flags + BATCH);     // 512
    unsigned* candBuf  = (unsigned*)(cbarsum + 512);  // 4096x512 (8 MB)
    u16* q2h = (u16*)(candBuf + (size_t)BATCH * CAND_CAP);   // 4 MB
    u16* cbh = q2h + (size_t)BATCH * DIM;                    // 32 MB
    u16* yh  = cbh + (size_t)VOC * DIM;                      // 4 MB
    u16* yl  = yh  + (size_t)BATCH * DIM;                    // 4 MB
    u16* wvh = yl  + (size_t)BATCH * DIM;                    // 0.5 MB
    u16* wvl = wvh + (size_t)DIM * DIM;                      // 0.5 MB

    // aliases (no workspace growth):
    //  - x hi/lo pack lives in yh/yl (dead after mfma_out(q2); rewritten by
    //    pack_rows(y) before mfma_out(out))
    //  - Wqk hi/lo pack lives in candBuf (candBuf not needed until mfma_dots)
    u16* xh   = yh;
    u16* xl   = yl;
    u16* wqkh = (u16*)candBuf;
    u16* wqkl = wqkh + (size_t)DIM * DIM;

    dim3 blk(256);

    // Wqk = Wq @ Wk^T (fp64-flush fold); prologue zeroes counters/flags/cbarsum
    gemm64<true, true><<<dim3(DIM / 64, DIM / 64), blk, 0, stream>>>(
        Wq, Wk, nullptr, Wqk, DIM, DIM, DIM, counters, BATCH * 2 + 512);

    // all independent prep in ONE launch: x-pack | Wqk-pack | cb-pack(coal) |
    // Wv-pack | cbar_accum | bias_fold
    fused_prep<<<dim3(3712), blk, 0, stream>>>(
        x, Wqk, codebook, Wv, bq, Wk,
        xh, xl, wqkh, wqkl, cbh, wvh, wvl, cbarsum, bqk);

    // q2 = x @ Wqk + bqk via hi/lo 3-pass MFMA (256 blocks)
    mfma_out<<<dim3(DIM / 64, BATCH / 128), blk, 0, stream>>>(
        xh, xl, wqkh, wqkl, bqk, q2, BATCH);

    // rowstats + q2-pack in one launch
    fused_q2post<<<dim3(2048), blk, 0, stream>>>(q2, cbarsum, trow, sigr, q2h);

    // fused dots GEMM (v13: 2-stage counted-vmcnt pipeline) + candidate append
    mfma_dots<<<dim3(8192), blk, 0, stream>>>(q2h, cbh, trow, candBuf, counters);

    // exact selection + softmax + y = attn @ codebook (prefetched rescue)
    select6<<<dim3(BATCH), blk, 0, stream>>>(
        candBuf, counters, trow, q2, codebook, y, flags);
    fallback_row<<<dim3(BATCH), blk, 0, stream>>>(
        flags, q2, codebook, trow, sigr, y);

    // out = y @ Wv + bv  (hi/lo 3-pass MFMA, 256 blocks)
    pack_rows<<<dim3(BATCH * 64 / 256), blk, 0, stream>>>(y, yh, yl, BATCH, 12);
    mfma_out<<<dim3(DIM / 64, BATCH / 128), blk, 0, stream>>>(
        yh, yl, wvh, wvl, bv, out, BATCH);
}